// Round 25
// baseline (1317.560 us; speedup 1.0000x reference)
//
#include <hip/hip_runtime.h>
#include <cstdint>

#define SS 2048
#define HHd 512
#define FFd 2048
#define TTd 32
#define LLd 6
#define VW 16
#define VC 128

typedef float f32x4 __attribute__((ext_vector_type(4)));
typedef __bf16 bf16x8 __attribute__((ext_vector_type(8)));
typedef short short8v __attribute__((ext_vector_type(8)));
typedef short short4v __attribute__((ext_vector_type(4)));

__device__ __forceinline__ short f2b(float f) {
  unsigned u = __builtin_bit_cast(unsigned, f);
  u += 0x7fffu + ((u >> 16) & 1u);
  return (short)(u >> 16);
}
__device__ __forceinline__ float b2f(short s) {
  unsigned u = ((unsigned)(unsigned short)s) << 16;
  return __builtin_bit_cast(float, u);
}

typedef const __attribute__((address_space(1))) void gv_t;
typedef __attribute__((address_space(3))) void lv_t;
__device__ __forceinline__ void gload16(const void* g, void* l) {
  __builtin_amdgcn_global_load_lds((gv_t*)g, (lv_t*)l, 16, 0, 0);
}

// ------------------------------ GEMM (all-TB, BK=64, swizzled LDS, double-buffered 2-phase) ------------------------------
// C[M,N] = A[M,K] @ B^T. z-batching: A += z*as1; B += (z/zdiv)*bs1 + (z%zdiv)*bs2; C += z*cStr.
// TRBE: when (z % tmod)==tval, write C^T (bf16) to CbT + (z/zdiv)*ctStr instead (LDS-staged coalesced).
// Pipeline: issue L(k+1) into alternate buffer -> MFMA on buf[k] (loads fly under compute) -> barrier.
template<int BMt, int BNt, bool BIAS, bool RELU, bool RESID, bool OUTF, bool OUTB, bool TRBE>
__global__ __launch_bounds__(256) void gemm3(
    const short* __restrict__ A, const short* __restrict__ Bb,
    const float* __restrict__ biasb, const float* __restrict__ resid,
    float* __restrict__ Cfb, short* __restrict__ Cbb,
    int M, int N, int K, int lda, int ldb, int kzS, float scale,
    int zdiv, long as1, long bs1, long bs2, int bb1, int bb2, long cStr,
    short* __restrict__ CbT, long ctStr, int tmod, int tval)
{
  constexpr int MR = BMt / 32, NR = BNt / 32;
  constexpr int WMt = BMt / 2, WNt = BNt / 2;
  constexpr int ACALLS = BMt / 8;
  constexpr int TOT = (BMt + BNt) / 8;
  constexpr int CPW = TOT / 4;
  constexpr int HALF = BMt * 64 + BNt * 64;

  const int z = blockIdx.z;
  const short* Ap = A + (long)z * as1;
  const short* Bp = Bb + (long)(z / zdiv) * bs1 + (long)(z % zdiv) * bs2;
  const float* bias = BIAS ? (biasb + (z / zdiv) * bb1 + (z % zdiv) * bb2) : nullptr;
  const int kz = z * kzS;

  const int m0 = blockIdx.y * BMt;
  const int n0 = blockIdx.x * BNt;

  __shared__ __align__(16) short LDSbuf[2 * HALF];

  const int tid = threadIdx.x;
  const int lane = tid & 63;
  const int w = tid >> 6;

  const short* srcs[CPW];
  int loff[CPW];
  {
    const int rl8 = lane >> 3;
    const int c16 = (lane & 7) ^ rl8;
#pragma unroll
    for (int c = 0; c < CPW; ++c) {
      int q = w * CPW + c;
      if (q < ACALLS) {
        int row = q * 8 + rl8;
        srcs[c] = Ap + (long)(m0 + row) * lda + kz + c16 * 8;
        loff[c] = q * 512;
      } else {
        int row = (q - ACALLS) * 8 + rl8;
        srcs[c] = Bp + (long)(n0 + row) * ldb + kz + c16 * 8;
        loff[c] = BMt * 64 + (q - ACALLS) * 512;
      }
    }
  }

  const int lrow = lane & 15;
  const int slotb = lane >> 4;
  const int wm = (w >> 1) * WMt, wn = (w & 1) * WNt;

  f32x4 acc[MR][NR] = {};

  // prologue: stage tile 0 into buffer 0
#pragma unroll
  for (int c = 0; c < CPW; ++c) gload16(srcs[c], LDSbuf + loff[c]);
#pragma unroll
  for (int c = 0; c < CPW; ++c) srcs[c] += 64;
  __syncthreads();

  const int NIT = K >> 6;
  for (int it = 0; it < NIT; ++it) {
    const int cur = it & 1;
    if (it + 1 < NIT) {
      const int nxt = (cur ^ 1) * HALF;
#pragma unroll
      for (int c = 0; c < CPW; ++c) gload16(srcs[c], LDSbuf + nxt + loff[c]);
#pragma unroll
      for (int c = 0; c < CPW; ++c) srcs[c] += 64;
    }
    const short* As = LDSbuf + cur * HALF;
    const short* Bs = As + BMt * 64;
#pragma unroll
    for (int s = 0; s < 2; ++s) {
      bf16x8 af[MR], bfv[NR];
#pragma unroll
      for (int f = 0; f < MR; ++f) {
        int row = wm + f * 16 + lrow;
        int phys = (slotb + s * 4) ^ (row & 7);
        af[f] = *(const bf16x8*)&As[row * 64 + phys * 8];
      }
#pragma unroll
      for (int f = 0; f < NR; ++f) {
        int row = wn + f * 16 + lrow;
        int phys = (slotb + s * 4) ^ (row & 7);
        bfv[f] = *(const bf16x8*)&Bs[row * 64 + phys * 8];
      }
#pragma unroll
      for (int i = 0; i < MR; ++i)
#pragma unroll
        for (int j = 0; j < NR; ++j)
          acc[i][j] = __builtin_amdgcn_mfma_f32_16x16x32_bf16(af[i], bfv[j], acc[i][j], 0, 0, 0);
    }
    __syncthreads();   // drains L(it+1); frees buf[cur]
  }

  const int crow = (lane >> 4) * 4;
  const int ccol = lane & 15;
  const bool dotr = TRBE && ((z % tmod) == tval);

  if (OUTB) {
    if (dotr) {
      short* Cb = CbT + (long)(z / zdiv) * ctStr;
      constexpr int LDSW = BMt + 8;
      short* Os = LDSbuf;
#pragma unroll
      for (int i = 0; i < MR; ++i) {
#pragma unroll
        for (int j = 0; j < NR; ++j) {
          int lc = wn + j * 16 + ccol;
          float bv = BIAS ? bias[n0 + lc] : 0.f;
#pragma unroll
          for (int r = 0; r < 4; ++r) {
            int lr = wm + i * 16 + crow + r;
            Os[lc * LDSW + lr] = f2b(acc[i][j][r] * scale + bv);
          }
        }
      }
      __syncthreads();
      constexpr int CPR = BMt / 8;
      constexpr int CPT = (BMt * BNt / 8) / 256;
#pragma unroll
      for (int c = 0; c < CPT; ++c) {
        int idx = tid + c * 256;
        int col = idx / CPR;
        int rowc = (idx % CPR) * 8;
        int4 vv = *(const int4*)&Os[col * LDSW + rowc];
        *(int4*)&Cb[(long)(n0 + col) * M + m0 + rowc] = vv;
      }
    } else {
      short* Cb = Cbb + (long)z * cStr;
      constexpr int LDSW = BNt + 8;
      short* Os = LDSbuf;
#pragma unroll
      for (int i = 0; i < MR; ++i) {
#pragma unroll
        for (int j = 0; j < NR; ++j) {
          int lc = wn + j * 16 + ccol;
          float bv = BIAS ? bias[n0 + lc] : 0.f;
#pragma unroll
          for (int r = 0; r < 4; ++r) {
            int lr = wm + i * 16 + crow + r;
            float v = acc[i][j][r] * scale + bv;
            if (RELU) v = v > 0.f ? v : 0.f;
            Os[lr * LDSW + lc] = f2b(v);
          }
        }
      }
      __syncthreads();
      constexpr int CPR = BNt / 8;
      constexpr int CPT = (BMt * BNt / 8) / 256;
#pragma unroll
      for (int c = 0; c < CPT; ++c) {
        int idx = tid + c * 256;
        int row = idx / CPR;
        int col8 = (idx % CPR) * 8;
        int4 vv = *(const int4*)&Os[row * LDSW + col8];
        *(int4*)&Cb[(long)(m0 + row) * N + n0 + col8] = vv;
      }
    }
  } else {
    float* Cf = Cfb + (long)z * cStr;
#pragma unroll
    for (int i = 0; i < MR; ++i) {
#pragma unroll
      for (int j = 0; j < NR; ++j) {
        int gc = n0 + wn + j * 16 + ccol;
        float bv = BIAS ? bias[gc] : 0.f;
#pragma unroll
        for (int r = 0; r < 4; ++r) {
          int gr = m0 + wm + i * 16 + crow + r;
          long off = (long)gr * N + gc;
          float v = acc[i][j][r] * scale + bv;
          if (RESID) v += resid[off];
          if (RELU) v = v > 0.f ? v : 0.f;
          Cf[off] = v;
        }
      }
    }
  }
}

// ============================== Fused attention (q-tile 64, key-split 8, 8 waves, 2-phase) ==============================
#define FSA_SMEM (64 * 512 * 2 + 512 * 64 * 2 + 64 * 64 * 2 + 128 * 4)
__global__ __launch_bounds__(512) void fsa_k(
    const short* __restrict__ Q, const short* __restrict__ Kmat,
    const short* __restrict__ VT, short* __restrict__ Op, float* __restrict__ Zp) {
  extern __shared__ __align__(16) char smem[];
  short* Ks  = (short*)smem;           // [64][512]  (Q stage / K chunk / O stage)
  short* Vts = Ks + 64 * 512;          // [512][64]
  short* Ps  = Vts + 512 * 64;         // [64][64]
  float* Zs  = (float*)(Ps + 64 * 64); // [2][64]
  const float RSQ = 0.04419417382415922f;

  const int z = blockIdx.x;            // key split (0..7)
  const int q0 = blockIdx.y * 64;
  const int key0 = z * 256;
  const int tid = threadIdx.x, lane = tid & 63, w = tid >> 6;
  const int qg = w >> 1;               // 0..3 q-group (16 rows each)
  const int kh = w & 1;
  const int wn = kh * 32, wn2 = kh * 256;
  const int lrow = lane & 15, lgrp = lane >> 4;

  // stage Q (64 rows)
  for (int c = 0; c < 8; ++c) {
    int row = w * 8 + c;
    const short* src = Q + (long)(q0 + row) * HHd + (lane ^ (row & 7)) * 8;
    gload16(src, &Ks[row * 512]);
  }
  __syncthreads();
  bf16x8 qf[16];
#pragma unroll
  for (int st = 0; st < 16; ++st) {
    int row = qg * 16 + lrow;
    int phys = (st * 4 + lgrp) ^ (row & 7);
    qf[st] = *(const bf16x8*)&Ks[row * 512 + phys * 8];
  }
  __syncthreads();

  // prologue: stage K(0)
  for (int c = 0; c < 8; ++c) {
    int row = w * 8 + c;
    const short* src = Kmat + (long)(key0 + row) * HHd + (lane ^ (row & 7)) * 8;
    gload16(src, &Ks[row * 512]);
  }
  __syncthreads();

  f32x4 accO[16] = {};
  float zacc[4] = {};

  for (int kc = 0; kc < 4; ++kc) {
    // issue V(kc) — flies under QK compute
    for (int c = 0; c < 8; ++c) {
      int rb = (w * 8 + c) * 8;
      int vrow = rb + (lane >> 3);
      const short* src = VT + (long)vrow * SS + key0 + kc * 64 + ((lane & 7) ^ (vrow & 7)) * 8;
      gload16(src, &Vts[rb * 64]);
    }
    f32x4 accS0 = {}, accS1 = {};
#pragma unroll
    for (int st = 0; st < 16; ++st) {
      int row0 = wn + lrow;
      int phys0 = (st * 4 + lgrp) ^ (row0 & 7);
      bf16x8 b0 = *(const bf16x8*)&Ks[row0 * 512 + phys0 * 8];
      int row1 = wn + 16 + lrow;
      int phys1 = (st * 4 + lgrp) ^ (row1 & 7);
      bf16x8 b1 = *(const bf16x8*)&Ks[row1 * 512 + phys1 * 8];
      accS0 = __builtin_amdgcn_mfma_f32_16x16x32_bf16(qf[st], b0, accS0, 0, 0, 0);
      accS1 = __builtin_amdgcn_mfma_f32_16x16x32_bf16(qf[st], b1, accS1, 0, 0, 0);
    }
#pragma unroll
    for (int f = 0; f < 2; ++f) {
#pragma unroll
      for (int r = 0; r < 4; ++r) {
        int row = qg * 16 + lgrp * 4 + r;
        int col = wn + f * 16 + lrow;
        float sv = f ? accS1[r] : accS0[r];
        float e = __expf(sv * RSQ);
        zacc[r] += e;
        int slot = col >> 3;
        Ps[row * 64 + ((slot ^ (row & 7)) * 8) + (col & 7)] = f2b(e);
      }
    }
    __syncthreads();   // drains V(kc); P visible; Ks free (QK done)
    // issue K(kc+1) — flies under PV compute
    if (kc < 3) {
      for (int c = 0; c < 8; ++c) {
        int row = w * 8 + c;
        const short* src = Kmat + (long)(key0 + (kc + 1) * 64 + row) * HHd + (lane ^ (row & 7)) * 8;
        gload16(src, &Ks[row * 512]);
      }
    }
#pragma unroll
    for (int kk = 0; kk < 2; ++kk) {
      int prow = qg * 16 + lrow;
      int pphys = (kk * 4 + lgrp) ^ (prow & 7);
      bf16x8 pa = *(const bf16x8*)&Ps[prow * 64 + pphys * 8];
#pragma unroll
      for (int n = 0; n < 16; ++n) {
        int vrow = wn2 + n * 16 + lrow;
        int vphys = (kk * 4 + lgrp) ^ (vrow & 7);
        bf16x8 vb = *(const bf16x8*)&Vts[vrow * 64 + vphys * 8];
        accO[n] = __builtin_amdgcn_mfma_f32_16x16x32_bf16(pa, vb, accO[n], 0, 0, 0);
      }
    }
    __syncthreads();   // drains K(kc+1); Vts/Ps free for next iteration
  }

  // epilogue: stage O as bf16 into Ks (linear [64][512]) + Z shuffles
#pragma unroll
  for (int n = 0; n < 16; ++n) {
#pragma unroll
    for (int r = 0; r < 4; ++r) {
      int row = qg * 16 + lgrp * 4 + r;
      int col = wn2 + n * 16 + lrow;
      Ks[row * 512 + col] = f2b(accO[n][r]);
    }
  }
#pragma unroll
  for (int r = 0; r < 4; ++r) {
    float v = zacc[r];
    v += __shfl_xor(v, 1); v += __shfl_xor(v, 2);
    v += __shfl_xor(v, 4); v += __shfl_xor(v, 8);
    if (lrow == 0) Zs[kh * 64 + qg * 16 + lgrp * 4 + r] = v;
  }
  __syncthreads();
  short* OpZ = Op + (long)z * (long)SS * HHd + (long)q0 * HHd;
#pragma unroll
  for (int c = 0; c < 8; ++c) {
    int idx = tid + c * 512;
    *(int4*)&OpZ[idx * 8] = *(const int4*)&Ks[idx * 8];
  }
  if (tid < 64) Zp[(long)z * SS + q0 + tid] = Zs[tid] + Zs[64 + tid];
}

// ---------------- fused attention tail: (sum8 bf16-O)/Z + bvo + bf16 resid + LayerNorm -> bf16 ----------------
__global__ __launch_bounds__(256) void r4zrln_k(const short* __restrict__ pb,
                                                const float* __restrict__ Zp,
                                                const float* __restrict__ bvo,
                                                const short* __restrict__ resid,
                                                const float* __restrict__ w, const float* __restrict__ b,
                                                short* __restrict__ Yb) {
  const long SH = (long)SS * HHd;
  const int row = blockIdx.x, tid = threadIdx.x;
  long base = (long)row * HHd;
  float zt = 0.f;
#pragma unroll
  for (int sk = 0; sk < 8; ++sk) zt += Zp[(long)sk * SS + row];
  float zi = 1.0f / zt;
  float a0 = 0.f, a1 = 0.f;
#pragma unroll
  for (int sk = 0; sk < 8; ++sk) {
    a0 += b2f(pb[sk * SH + base + tid]);
    a1 += b2f(pb[sk * SH + base + tid + 256]);
  }
  float x0 = a0 * zi + bvo[tid] + b2f(resid[base + tid]);
  float x1 = a1 * zi + bvo[tid + 256] + b2f(resid[base + tid + 256]);
  float s = x0 + x1;
#pragma unroll
  for (int o = 32; o; o >>= 1) s += __shfl_xor(s, o);
  __shared__ float r1[4], r2[4];
  if ((tid & 63) == 0) r1[tid >> 6] = s;
  __syncthreads();
  float mean = (r1[0] + r1[1] + r1[2] + r1[3]) * (1.f / HHd);
  float d0 = x0 - mean, d1 = x1 - mean;
  float q = d0 * d0 + d1 * d1;
#pragma unroll
  for (int o = 32; o; o >>= 1) q += __shfl_xor(q, o);
  if ((tid & 63) == 0) r2[tid >> 6] = q;
  __syncthreads();
  float var = (r2[0] + r2[1] + r2[2] + r2[3]) * (1.f / HHd);
  float rs = rsqrtf(var + 1e-5f);
  float o0 = d0 * rs * w[tid] + b[tid];
  float o1 = d1 * rs * w[tid + 256] + b[tid + 256];
  Yb[base + tid] = f2b(o0); Yb[base + tid + 256] = f2b(o1);
}

// ---------------- split-K=4 bf16 reduce + bias + bf16 resid + LayerNorm -> bf16 (FFN2) ----------------
__global__ __launch_bounds__(256) void r4rln_k(const short* __restrict__ pb,
                                               const float* __restrict__ bias,
                                               const short* __restrict__ resid,
                                               const float* __restrict__ w, const float* __restrict__ b,
                                               short* __restrict__ Yb) {
  const long SH = (long)SS * HHd;
  const int row = blockIdx.x, tid = threadIdx.x;
  long base = (long)row * HHd;
  float x0 = bias[tid] + b2f(resid[base + tid]);
  float x1 = bias[tid + 256] + b2f(resid[base + tid + 256]);
#pragma unroll
  for (int sk = 0; sk < 4; ++sk) {
    x0 += b2f(pb[sk * SH + base + tid]);
    x1 += b2f(pb[sk * SH + base + tid + 256]);
  }
  float s = x0 + x1;
#pragma unroll
  for (int o = 32; o; o >>= 1) s += __shfl_xor(s, o);
  __shared__ float r1[4], r2[4];
  if ((tid & 63) == 0) r1[tid >> 6] = s;
  __syncthreads();
  float mean = (r1[0] + r1[1] + r1[2] + r1[3]) * (1.f / HHd);
  float d0 = x0 - mean, d1 = x1 - mean;
  float q = d0 * d0 + d1 * d1;
#pragma unroll
  for (int o = 32; o; o >>= 1) q += __shfl_xor(q, o);
  if ((tid & 63) == 0) r2[tid >> 6] = q;
  __syncthreads();
  float var = (r2[0] + r2[1] + r2[2] + r2[3]) * (1.f / HHd);
  float rs = rsqrtf(var + 1e-5f);
  float o0 = d0 * rs * w[tid] + b[tid];
  float o1 = d1 * rs * w[tid + 256] + b[tid + 256];
  Yb[base + tid] = f2b(o0); Yb[base + tid + 256] = f2b(o1);
}

// ---------------- LayerNorm over bf16 rows; optional f32 out + bf16 out ----------------
__global__ __launch_bounds__(256) void lnb_k(const short* __restrict__ Xb, const float* __restrict__ w,
                                             const float* __restrict__ b, float* __restrict__ Yf,
                                             short* __restrict__ Yb) {
  const int row = blockIdx.x;
  const int tid = threadIdx.x;
  long base = (long)row * HHd;
  float x0 = b2f(Xb[base + tid]), x1 = b2f(Xb[base + tid + 256]);
  float s = x0 + x1;
#pragma unroll
  for (int o = 32; o; o >>= 1) s += __shfl_xor(s, o);
  __shared__ float r1[4], r2[4];
  if ((tid & 63) == 0) r1[tid >> 6] = s;
  __syncthreads();
  float mean = (r1[0] + r1[1] + r1[2] + r1[3]) * (1.f / HHd);
  float d0 = x0 - mean, d1 = x1 - mean;
  float q = d0 * d0 + d1 * d1;
#pragma unroll
  for (int o = 32; o; o >>= 1) q += __shfl_xor(q, o);
  if ((tid & 63) == 0) r2[tid >> 6] = q;
  __syncthreads();
  float var = (r2[0] + r2[1] + r2[2] + r2[3]) * (1.f / HHd);
  float rs = rsqrtf(var + 1e-5f);
  float o0 = d0 * rs * w[tid] + b[tid];
  float o1 = d1 * rs * w[tid + 256] + b[tid + 256];
  if (Yf) { Yf[base + tid] = o0; Yf[base + tid + 256] = o1; }
  Yb[base + tid] = f2b(o0); Yb[base + tid + 256] = f2b(o1);
}

// ---------------- f32 [K,N] -> bf16 [N,K] transpose-convert (batched z) ----------------
__global__ __launch_bounds__(256) void tconv_k(const float* __restrict__ in, short* __restrict__ out,
                                               int K, int N) {
  __shared__ float t[32][33];
  long zo = (long)blockIdx.z * K * N;
  int n0 = blockIdx.x * 32, k0 = blockIdx.y * 32;
  int tx = threadIdx.x & 31, ty = threadIdx.x >> 5;
#pragma unroll
  for (int i = 0; i < 4; ++i)
    t[ty + i * 8][tx] = in[zo + (long)(k0 + ty + i * 8) * N + n0 + tx];
  __syncthreads();
#pragma unroll
  for (int i = 0; i < 4; ++i)
    out[zo + (long)(n0 + ty + i * 8) * K + k0 + tx] = f2b(t[tx][ty + i * 8]);
}

// ---------------- plain strided f32 -> bf16 convert (batched z) ----------------
__global__ __launch_bounds__(256) void pconv_k(const float* __restrict__ in, short* __restrict__ out,
                                               long inStride, long outStride) {
  long i = ((long)blockIdx.x * 256 + threadIdx.x) * 4;
  const float* ip = in + (long)blockIdx.z * inStride + i;
  short* op = out + (long)blockIdx.z * outStride + i;
  float4 v = *(const float4*)ip;
  short4v o;
  o[0] = f2b(v.x); o[1] = f2b(v.y); o[2] = f2b(v.z); o[3] = f2b(v.w);
  *(short4v*)op = o;
}

// ---------------- bf16 strided copy (batched z) ----------------
__global__ __launch_bounds__(256) void scpy_k(const short* __restrict__ src, short* __restrict__ dst,
                                              long srcStride, long dstStride) {
  long i = ((long)blockIdx.x * 256 + threadIdx.x) * 4;
  *(short4v*)(dst + (long)blockIdx.z * dstStride + i) =
      *(const short4v*)(src + (long)blockIdx.z * srcStride + i);
}

// ---------------- bias slot copy: biasD[l*8+3] <- dab[l*8+4] ----------------
__global__ __launch_bounds__(256) void bcpy_k(const float* __restrict__ src, float* __restrict__ dst) {
  int i = blockIdx.x * 256 + threadIdx.x;  // over L*H
  int l = i >> 9, c = i & 511;
  dst[(l * 8 + 3) * HHd + c] = src[(l * 8 + 4) * HHd + c];
}

// ---------------- bias table copy with zeroed j-slots ----------------
__global__ __launch_bounds__(256) void zbias_k(const float* __restrict__ src, float* __restrict__ dst,
                                               int nj, unsigned jmask, int total) {
  int i = blockIdx.x * 256 + threadIdx.x;
  if (i >= total) return;
  int j = (i >> 9) % nj;
  dst[i] = ((jmask >> j) & 1u) ? 0.f : src[i];
}

// ---------------- bvo partials: row-major streaming (18 combos x 16 m-groups) ----------------
__global__ __launch_bounds__(256) void bvoP_k(const float* __restrict__ eaw, const float* __restrict__ eab,
                                              const float* __restrict__ daw, const float* __restrict__ dab,
                                              float* __restrict__ part) {
  const long HH2 = (long)HHd * HHd;
  const int b = blockIdx.x, mg = blockIdx.y, tid = threadIdx.x;
  const float* Wout; const float* bv;
  if (b < 6) {
    int i = b;
    Wout = eaw + (i * 4 + 3) * HH2; bv = eab + (i * 4 + 2) * HHd;
  } else if (b < 12) {
    int i = b - 6;
    Wout = daw + (i * 8 + 3) * HH2; bv = dab + (i * 8 + 2) * HHd;
  } else {
    int i = b - 12;
    Wout = daw + (i * 8 + 7) * HH2; bv = dab + (i * 8 + 6) * HHd;
  }
  float a0 = 0.f, a1 = 0.f;
#pragma unroll 4
  for (int m = mg * 32; m < mg * 32 + 32; ++m) {
    float bvm = bv[m];
    a0 = fmaf(bvm, Wout[(long)m * HHd + tid], a0);
    a1 = fmaf(bvm, Wout[(long)m * HHd + tid + 256], a1);
  }
  long o = ((long)b * 16 + mg) * HHd;
  part[o + tid] = a0;
  part[o + tid + 256] = a1;
}

// ---------------- bvo reduce: sum 16 partials + bout ----------------
__global__ __launch_bounds__(256) void bvoR_k(const float* __restrict__ part,
                                              const float* __restrict__ eab, const float* __restrict__ dab,
                                              float* __restrict__ bvoAll) {
  const int b = blockIdx.x, tid = threadIdx.x;
  const float* bout;
  if (b < 6) bout = eab + (b * 4 + 3) * HHd;
  else if (b < 12) bout = dab + ((b - 6) * 8 + 3) * HHd;
  else bout = dab + ((b - 12) * 8 + 7) * HHd;
  float s0 = bout[tid], s1 = bout[tid + 256];
#pragma unroll
  for (int mg = 0; mg < 16; ++mg) {
    long o = ((long)b * 16 + mg) * HHd;
    s0 += part[o + tid];
    s1 += part[o + tid + 256];
  }
  bvoAll[(long)b * HHd + tid] = s0;
  bvoAll[(long)b * HHd + tid + 256] = s1;
}

// ------------------------------ embedding gather (bf16 only) ------------------------------
__global__ __launch_bounds__(256) void gather_k(const int* __restrict__ sent, const float* __restrict__ emb,
                                                short* __restrict__ hb, short* __restrict__ yb) {
  long i = (long)blockIdx.x * 256 + threadIdx.x;
  int s = (int)(i >> 9);
  int hcol = (int)(i & 511);
  float v = emb[(long)sent[s] * HHd + hcol];
  short bb = f2b(v);
  hb[i] = bb; yb[i] = bb;
}

// ------------------------------ feats: [SS,HHd] @ [HHd,TTd] + b (f32) ------------------------------
__global__ __launch_bounds__(256) void feats_k(const float* __restrict__ Y, const float* __restrict__ W,
                                               const float* __restrict__ b, float* __restrict__ feats) {
  __shared__ float ys[8 * HHd];
  const int row0 = blockIdx.x * 8;
  for (int i = threadIdx.x; i < 8 * HHd; i += 256) ys[i] = Y[(long)row0 * HHd + i];
  __syncthreads();
  const int n = threadIdx.x & 31, r = threadIdx.x >> 5;
  float acc = b[n];
  const float* yr = &ys[r * HHd];
  for (int k = 0; k < HHd; ++k) acc = fmaf(yr[k], W[k * TTd + n], acc);
  feats[(long)(row0 + r) * TTd + n] = acc;
}

// ============================== Parallel Viterbi (hierarchical max-plus scan) ==============================
__global__ __launch_bounds__(256) void vit_p1(const float* __restrict__ feats,
                                              const float* __restrict__ trans,
                                              float* __restrict__ Mc) {
  __shared__ float trS[1024];
  __shared__ float fS[VW * 32];
  __shared__ float Ga[32 * 33], Gb[32 * 33];
  const int c = blockIdx.x, tid = threadIdx.x;
  for (int i = tid; i < 1024; i += 256) trS[i] = trans[i];
  for (int i = tid; i < VW * 32; i += 256) fS[i] = feats[c * VW * 32 + i];
  __syncthreads();
  for (int i = tid; i < 1024; i += 256) {
    int n = i >> 5, q = i & 31;
    Ga[n * 33 + q] = trS[i] + fS[n];
  }
  __syncthreads();
  float* G = Ga;
  float* Gn = Gb;
  const int q = tid & 31, nb = (tid >> 5) * 4;
  for (int s = 1; s < VW; ++s) {
    float m0 = -3.0e38f, m1 = -3.0e38f, m2 = -3.0e38f, m3 = -3.0e38f;
    for (int pp = 0; pp < 32; ++pp) {
      float g = G[pp * 33 + q];
      m0 = fmaxf(m0, trS[(nb + 0) * 32 + pp] + g);
      m1 = fmaxf(m1, trS[(nb + 1) * 32 + pp] + g);
      m2 = fmaxf(m2, trS[(nb + 2) * 32 + pp] + g);
      m3 = fmaxf(m3, trS[(nb + 3) * 32 + pp] + g);
    }
    Gn[(nb + 0) * 33 + q] = m0 + fS[s * 32 + nb + 0];
    Gn[(nb + 1) * 33 + q] = m1 + fS[s * 32 + nb + 1];
    Gn[(nb + 2) * 33 + q] = m2 + fS[s * 32 + nb + 2];
    Gn[(nb + 3) * 33 + q] = m3 + fS[s * 32 + nb + 3];
    __syncthreads();
    float* t = G; G = Gn; Gn = t;
  }
  for (int i = tid; i < 1024; i += 256) Mc[c * 1024 + i] = G[(i >> 5) * 33 + (i & 31)];
}

__global__ __launch_bounds__(256) void vit_p1b(const float* __restrict__ Mf, float* __restrict__ Mcrs) {
  __shared__ float Ga[32 * 33], Gb[32 * 33], Ms[1024];
  const int c = blockIdx.x, tid = threadIdx.x;
  for (int i = tid; i < 1024; i += 256) Ga[(i >> 5) * 33 + (i & 31)] = Mf[(4 * c) * 1024 + i];
  float* G = Ga;
  float* Gn = Gb;
  const int q = tid & 31, nb = (tid >> 5) * 4;
  for (int j = 1; j < 4; ++j) {
    for (int i = tid; i < 1024; i += 256) Ms[i] = Mf[(4 * c + j) * 1024 + i];
    __syncthreads();
    float m0 = -3.0e38f, m1 = -3.0e38f, m2 = -3.0e38f, m3 = -3.0e38f;
    for (int pp = 0; pp < 32; ++pp) {
      float g = G[pp * 33 + q];
      m0 = fmaxf(m0, Ms[(nb + 0) * 32 + pp] + g);
      m1 = fmaxf(m1, Ms[(nb + 1) * 32 + pp] + g);
      m2 = fmaxf(m2, Ms[(nb + 2) * 32 + pp] + g);
      m3 = fmaxf(m3, Ms[(nb + 3) * 32 + pp] + g);
    }
    Gn[(nb + 0) * 33 + q] = m0;
    Gn[(nb + 1) * 33 + q] = m1;
    Gn[(nb + 2) * 33 + q] = m2;
    Gn[(nb + 3) * 33 + q] = m3;
    __syncthreads();
    float* t = G; G = Gn; Gn = t;
  }
  for (int i = tid; i < 1024; i += 256) Mcrs[c * 1024 + i] = G[(i >> 5) * 33 + (i & 31)];
}

__device__ __forceinline__ float vstep(float fv, int p0, const f32x4& M0, const f32x4& M1,
                                       const f32x4& M2, const f32x4& M3) {
  float mv[16];
#pragma unroll
  for (int j = 0; j < 4; ++j) { mv[j] = M0[j]; mv[4 + j] = M1[j]; mv[8 + j] = M2[j]; mv[12 + j] = M3[j]; }
  float cnd[16];
#pragma unroll
  for (int j = 0; j < 16; ++j) cnd[j] = __shfl(fv, p0 + j) + mv[j];
  float t8[8], t4[4];
#pragma unroll
  for (int j = 0; j < 8; ++j) t8[j] = fmaxf(cnd[2 * j], cnd[2 * j + 1]);
#pragma unroll
  for (int j = 0; j < 4; ++j) t4[j] = fmaxf(t8[2 * j], t8[2 * j + 1]);
  float bv = fmaxf(fmaxf(t4[0], t4[1]), fmaxf(t4[2], t4[3]));
  return fmaxf(bv, __shfl_xor(bv, 32));
}

__global__ __launch_bounds__(64) void vit_p2(const float* __restrict__ Mcrs,
                                             const float* __restrict__ trans,
                                             float* __restrict__ bfvF,
                                             float* __restrict__ term,
                                             float* __restrict__ out) {
  const int lane = threadIdx.x, n = lane & 31, h = lane >> 5, p0 = h << 4;
  float fv = (n == 30) ? 0.f : -10000.f;
  if (lane < 32) bfvF[n] = fv;
  const float* base = Mcrs + n * 32 + p0;
  f32x4 A0, A1, A2, A3, B0, B1, B2, B3, C0, C1, C2, C3;
#define LDM(d0, d1, d2, d3, c) { const float* M = base + (c) * 1024; \
  d0 = *(const f32x4*)M; d1 = *(const f32x4*)(M + 4); d2 = *(const f32x4*)(M + 8); d3 = *(const f32x4*)(M + 12); }
  LDM(A0, A1, A2, A3, 0) LDM(B0, B1, B2, B3, 1) LDM(C0, C1, C2, C3, 2)
#pragma unroll 1
  for (int c = 0; c < 30; c += 3) {
    fv = vstep(fv, p0, A0, A1, A2, A3); if (lane < 32) bfvF[(4 * (c + 1)) * 32 + n] = fv;
    { int cl = (c + 3) & 31; LDM(A0, A1, A2, A3, cl) }
    fv = vstep(fv, p0, B0, B1, B2, B3); if (lane < 32) bfvF[(4 * (c + 2)) * 32 + n] = fv;
    { int cl = (c + 4) & 31; LDM(B0, B1, B2, B3, cl) }
    fv = vstep(fv, p0, C0, C1, C2, C3); if (lane < 32) bfvF[(4 * (c + 3)) * 32 + n] = fv;
    { int cl = (c + 5) & 31; LDM(C0, C1, C2, C3, cl) }
  }
  fv = vstep(fv, p0, A0, A1, A2, A3); if (lane < 32) bfvF[(4 * 31) * 32 + n] = fv;
  fv = vstep(fv, p0, B0, B1, B2, B3); if (lane < 32) bfvF[(4 * 32) * 32 + n] = fv;
#undef LDM
  float v = fv + trans[31 * 32 + n];
  int idx = n;
#pragma unroll
  for (int o = 16; o; o >>= 1) {
    float ov = __shfl_xor(v, o);
    int oi = __shfl_xor(idx, o);
    if (ov > v || (ov == v && oi < idx)) { v = ov; idx = oi; }
  }
  if (lane == 0) { out[0] = v; term[0] = (float)idx; }
}

__global__ __launch_bounds__(64) void vit_p2b(const float* __restrict__ Mf, float* __restrict__ bfvF) {
  const int c = blockIdx.x, lane = threadIdx.x, n = lane & 31, h = lane >> 5, p0 = h << 4;
  float fv = bfvF[(4 * c) * 32 + n];
  const float* base = Mf + (size_t)(4 * c) * 1024 + n * 32 + p0;
#pragma unroll
  for (int j = 0; j < 3; ++j) {
    const float* M = base + j * 1024;
    f32x4 A0 = *(const f32x4*)M, A1 = *(const f32x4*)(M + 4);
    f32x4 A2 = *(const f32x4*)(M + 8), A3 = *(const f32x4*)(M + 12);
    fv = vstep(fv, p0, A0, A1, A2, A3);
    if (lane < 32) bfvF[(4 * c + j + 1) * 32 + n] = fv;
  }
}

__global__ __launch_bounds__(64) void vit_p3(const float* __restrict__ feats,
                                             const float* __restrict__ trans,
                                             const float* __restrict__ bfvF,
                                             unsigned char* __restrict__ bp) {
  const int c = blockIdx.x, lane = threadIdx.x, n = lane & 31, h = lane >> 5, p0 = h << 4;
  float tr[16];
#pragma unroll
  for (int j = 0; j < 16; ++j) tr[j] = trans[n * 32 + p0 + j];
  float fv = bfvF[c * 32 + n];
  float ft[VW];
  for (int s = 0; s < VW; ++s) ft[s] = feats[(c * VW + s) * 32 + n];
  for (int s = 0; s < VW; ++s) {
    float cd[16];
#pragma unroll
    for (int j = 0; j < 16; ++j) cd[j] = __shfl(fv, p0 + j) + tr[j];
    float v8[8]; int i8a[8];
#pragma unroll
    for (int j = 0; j < 8; ++j) {
      bool g = cd[2 * j + 1] > cd[2 * j];
      v8[j] = g ? cd[2 * j + 1] : cd[2 * j];
      i8a[j] = g ? 2 * j + 1 : 2 * j;
    }
    float v4[4]; int i4a[4];
#pragma unroll
    for (int j = 0; j < 4; ++j) {
      bool g = v8[2 * j + 1] > v8[2 * j];
      v4[j] = g ? v8[2 * j + 1] : v8[2 * j];
      i4a[j] = g ? i8a[2 * j + 1] : i8a[2 * j];
    }
    float v2[2]; int i2a[2];
#pragma unroll
    for (int j = 0; j < 2; ++j) {
      bool g = v4[2 * j + 1] > v4[2 * j];
      v2[j] = g ? v4[2 * j + 1] : v4[2 * j];
      i2a[j] = g ? i4a[2 * j + 1] : i4a[2 * j];
    }
    bool g1 = v2[1] > v2[0];
    float bv = g1 ? v2[1] : v2[0];
    int bi = p0 + (g1 ? i2a[1] : i2a[0]);
    float ov = __shfl_xor(bv, 32);
    int oi = __shfl_xor(bi, 32);
    bool takeo = h ? (ov >= bv) : (ov > bv);
    float m = takeo ? ov : bv;
    int mi = takeo ? oi : bi;
    if (!h) bp[(c * VW + s) * 32 + n] = (unsigned char)mi;
    fv = m + ft[s];
  }
}

__global__ __launch_bounds__(VC) void vit_p4(const unsigned char* __restrict__ bp,
                                             const float* __restrict__ term,
                                             float* __restrict__ out) {
  __shared__ unsigned char GsL[VC * 32];
  __shared__ unsigned char bnd[VC];
  const int lane = threadIdx.x;
  unsigned char g[32];
#pragma unroll
  for (int j = 0; j < 32; ++j) g[j] = (unsigned char)j;
  for (int s = VW - 1; s >= 0; --s) {
    const unsigned char* rowp = bp + (lane * VW + s) * 32;
#pragma unroll
    for (int j = 0; j < 32; ++j) g[j] = rowp[g[j]];
  }
#pragma unroll
  for (int j = 0; j < 32; ++j) GsL[lane * 32 + j] = g[j];
  __syncthreads();
  if (lane == 0) {
    bnd[VC - 1] = (unsigned char)(int)term[0];
    for (int cc = VC - 1; cc >= 1; --cc) bnd[cc - 1] = GsL[cc * 32 + bnd[cc]];
  }
  __syncthreads();
  int x = bnd[lane];
  out[1 + lane * VW + VW - 1] = (float)x;
  for (int k = VW - 2; k >= 0; --k) {
    x = bp[(lane * VW + k + 1) * 32 + x];
    out[1 + lane * VW + k] = (float)x;
  }
}

// ------------------------------ host ------------------------------
extern "C" void kernel_launch(void* const* d_in, const int* in_sizes, int n_in,
                              void* d_out, int out_size, void* d_ws, size_t ws_size,
                              hipStream_t stream) {
  (void)in_sizes; (void)n_in; (void)out_size; (void)ws_size;
  const int H = HHd, F = FFd, S = SS, L = LLd;
  const long HH2 = (long)H * H;
  const long SH = (long)S * H;
  const long HF = (long)H * F;

  hipFuncSetAttribute(reinterpret_cast<const void*>(fsa_k),
                      hipFuncAttributeMaxDynamicSharedMemorySize, FSA_SMEM);

  const int*   sent = (const int*)d_in[0];
  const float* embd = (const float*)d_in[1];
  const float* eaw  = (const float*)d_in[2];
  const float* eab  = (const float*)d_in[3];
  const float* ew1  = (const float*)d_in[4];
  const float* eb1  = (const float*)d_in[5];
  const float* ew2  = (const float*)d_in[6];
  const float* eb2  = (const float*)d_in[7];
  const float* elnw = (const float*)d_in[8];
  const float* elnb = (const float*)d_in[9];
  const float* daw  = (const float*)d_in[10];
  const float* dab  = (const float*)d_in[11];
  const float* dw1  = (const float*)d_in[12];
  const float* db1  = (const float*)d_in[13];
  const float* dw2  = (const float*)d_in[14];
  const float* db2  = (const float*)d_in[15];
  const float* dlnw = (const float*)d_in[16];
  const float* dlnb = (const float*)d_in[17];
  const float* enw  = (const float*)d_in[18];
  const float* enb  = (const float*)d_in[19];
  const float* dnw  = (const float*)d_in[20];
  const float* dnb  = (const float*)d_in[21];
  const float* h2tw = (const float*)d_in[22];
  const float* h2tb = (const float*)d_in[23];
  const float* trns = (const float*)d_in[24];

  char* p = (char*)d_ws;
  auto alloc = [&](size_t bytes) -> char* {
    char* r = p;
    p += (bytes + 255) & ~(size_t)255;
    return r;
  };
  short* wEAT = (short*)alloc((size_t)L * 4 * HH2 * 2);
  short* wDAT = (short*)alloc((size_t)L * 8 * HH2 * 2);
  short* wE1T = (short*)alloc((size_t)L * HF * 2);
  short* wE2T = (short*)alloc((size_t)L * HF * 2);
  short* wD1T = (short*)alloc((size_t)L * HF * 2);
  short* wD2T = (short*)alloc((size_t)L * HF * 2);
  short* h_b  = (short*)alloc(SH * 2);
  short* y_b  = (short*)alloc(SH * 2);
  float* tmpf = (float*)alloc(SH * 4);
  short* qkvb = (short*)alloc(4 * SH * 2);           // Q, K, V''-slot, crossQ
  float* scf  = (float*)alloc((size_t)4 * SH * 4);   // partial buffer (8x bf16 splits = 16MB; f32 alias prologue)
  float* Zp   = (float*)alloc((size_t)8 * S * 4);    // per-split Z row sums
  short* ff1b = (short*)alloc((size_t)S * F * 2);
  short* memb = (short*)alloc(SH * 2);
  short* ckvA = (short*)alloc((size_t)2 * L * SH * 2);  // interleaved cross K (even slots; odd unused)
  short* cvT  = (short*)alloc((size_t)L * SH * 2);      // cross V''^T per layer (direct from GEMM)
  float* biasE = (float*)alloc((size_t)L * 4 * H * 4);  // eab with j=2 zeroed
  float* biasD = (float*)alloc((size_t)L * 8 * H * 4);  // dab with j=2,6 zeroed; j=3 <- dab j=4
  float* bvoAll = (float*)alloc((size_t)18 * H * 4);    // folded V/out biases
  float* bvoPart = (float*)alloc((size_t)18 * 16 * H * 4); // bvo partials
  float* ftsf = (float*)alloc((size_t)S * TTd * 4);
  float* McB  = (float*)alloc((size_t)VC * 1024 * 4);
  float* McrsB= (float*)alloc((size_t)(VC / 4) * 1024 * 4);
  float* bfvF = (float*)alloc((size_t)(VC + 1) * 32 * 4);
  float* termB= (float*)alloc(64);
  unsigned char* bpgB = (unsigned char*)alloc((size_t)2048 * 32);

  short* vtb = ff1b;                  // V''^T scratch aliases ff1b (disjoint lifetimes)
  short* sparts = (short*)scf;        // bf16 split partials (8 x SH shorts = 16MB)
  short* wvPe  = (short*)scf;         // plain bf16 Wv copies alias scf (prologue only)
  short* wvPds = wvPe + L * HH2;
  short* wvPdc = wvPds + L * HH2;

  const int ZBIG = 1 << 20;

  // ---- weight conversion ----
  tconv_k<<<dim3(16, 16, L * 4), 256, 0, stream>>>(eaw, wEAT, H, H);
  tconv_k<<<dim3(16, 16, L * 8), 256, 0, stream>>>(daw, wDAT, H, H);
  tconv_k<<<dim3(64, 16, L), 256, 0, stream>>>(ew1, wE1T, H, F);
  tconv_k<<<dim3(16, 64, L), 256, 0, stream>>>(ew2, wE2T, F, H);
  tconv_k<<<dim3(64, 16, L), 256, 0, stream>>>(dw1, wD1T, H, F);
  tconv_k<<<dim3(16, 64, L), 256, 0, stream>>>(dw2, wD2T, F, H);
  // plain bf16 copies of Wv (enc j2, dec-self j2, dec-cross j6)
  pconv_k<<<dim3(256, 1, L), 256, 0, stream>>>(eaw + 2 * HH2, wvPe, 4 * HH2, HH2);
  pconv_k<<<dim3(256, 1, L), 256, 0, stream>>>(daw + 2 * HH2, wvPds, 8 * HH2, HH2);
  pconv_k<<<dim3(256, 1, L), 256, 0, stream>>>(daw + 6 * HH2, wvPdc, 8 * HH2, HH2);
  // compose Wvo^T = Wout^T @ Wv^T into the V-weight slots (in place)
  auto G_cmp = gemm3<128, 64, false, false, false, false, true, false>;
  G_cmp<<<dim3(8, 4, L), 256, 0, stream>>>(
      wEAT + 3 * HH2, wvPe, nullptr, nullptr, nullptr, wEAT + 2 * HH2,
      H, H, H, H, H, 0, 1.f, 1, 4 * HH2, HH2, 0, 0, 0, 4 * HH2,
      nullptr, 0, 1, -1);
  G_cmp<<<dim3(8, 4, L), 256, 0, stream>>>(
      wDAT + 3 * HH2, wvPds, nullptr, nullptr, nullptr, wDAT + 2 * HH2,
      H, H, H, H, H, 0, 1.f, 1, 8 * HH2, HH2, 0, 0, 0, 8 * HH2,
      nullptr, 0, 1, -1);
  G_cmp<<<dim3(8, 4, L), 256, 0, stream>>>(
      wDAT + 7 * HH2, wvPdc, nullptr, nullptr, nullptr, wDAT + 6 * HH2,
      H, H, H, H, H, 0, 1.f, 1, 8 * HH2, HH2, 0, 0, 0, 8 * HH2,
      nullptr, 0, 1, -1);
  // dec-self Wout^T slot (j=3) is free after compose: move crossQ W^T (j=4) into it
  scpy_k<<<dim3(256, 1, L), 256, 0, stream>>>(wDAT + 4 * HH2, wDAT + 3 * HH2, 8 * HH2, 8 * HH2);
  // bias tables with V slots zeroed; folded biases
  zbias_k<<<dim3((L * 4 * H + 255) / 256), 256, 0, stream>>>(eab, biasE, 4, 1u << 2, L * 4 * H);
  zbias_k<<<dim3((L * 8 * H + 255) / 256), 256, 0, stream>>>(dab, biasD, 8, (1u << 2) | (1u << 6), L * 8 * H);
  bcpy_k<<<dim3(L * H / 256), 256, 0, stream>>>(dab, biasD);
  bvoP_k<<<dim3(18, 16), 256, 0, stream>>>(eaw, eab, daw, dab, bvoPart);
  bvoR_k<<<dim3(18), 256, 0, stream>>>(bvoPart, eab, dab, bvoAll);

  gather_k<<<dim3((unsigned)(SH / 256)), 256, 0, stream>>>(sent, embd, h_b, y_b);

  // gemm variants (256x64 fat tiles for the big GEMMs, dbuf pipelined)
  auto G_qkv = gemm3<256, 64, true, false, false, false, true, true>;   // batched proj; z==2 -> V''^T direct
  auto G_spl = gemm3<256, 64, false, false, false, false, true, false>; // split-K partials -> bf16
  auto G_ff1 = gemm3<256, 64, true, true, false, false, true, false>;   // bias+relu -> bf16

  dim3 gQKVe(8, 8, 3), gQKVd(8, 8, 4), gSPL(8, 8, 4), gFF1(32, 8, 1), gFSA(8, 32, 1);

  // ---------------- encoder ----------------
  for (int i = 0; i < L; ++i) {
    G_qkv<<<gQKVe, 256, 0, stream>>>(
        h_b, wEAT + (size_t)i * 4 * HH2, biasE + (size_t)i * 4 * H, nullptr, nullptr, qkvb,
        S, H, H, H, H, 0, 1.f, ZBIG, 0, 0, HH2, 0, H, SH,
        vtb, 0, 3, 2);
    fsa_k<<<gFSA, 512, FSA_SMEM, stream>>>(qkvb, qkvb + SH, vtb, sparts, Zp);
    r4zrln_k<<<dim3(S), 256, 0, stream>>>(sparts, Zp, bvoAll + (size_t)i * H, h_b,
        elnw + (size_t)(i * 2) * H, elnb + (size_t)(i * 2) * H, h_b);
    G_ff1<<<gFF1, 256, 0, stream>>>(
        h_b, wE1T + (size_t)i * HF, eb1 + (size_t)i * F, nullptr, nullptr, ff1b,
        S, F, H, H, H, 0, 1.f, 1, 0, 0, 0, 0, 0, 0,
        nullptr, 0, 1, -1);
    G_spl<<<gSPL, 256, 0, stream>>>(
        ff1b, wE2T + (size_t)i * HF, nullptr, nullptr, nullptr, sparts,
        S, H, F / 4, F, F, F / 4, 1.f, 1, 0, 0, 0, 0, 0, SH,
        nullptr, 0, 1, -1);
    r4rln_k<<<dim3(S), 256, 0, stream>>>(sparts, eb2 + (size_t)i * H, h_b,
        elnw + (size_t)(i * 2 + 1) * H, elnb + (size_t)(i * 2 + 1) * H, h_b);
  }
  lnb_k<<<dim3(S), 256, 0, stream>>>(h_b, enw, enb, nullptr, memb);

  // cross K (j=5, even z) and composed V''^T (j=6, odd z -> direct transposed to cvT)
  G_qkv<<<dim3(8, 8, 2 * L), 256, 0, stream>>>(
      memb, wDAT + 5 * HH2, biasD + 5 * H, nullptr, nullptr, ckvA,
      S, H, H, H, H, 0, 1.f, 2, 0, 8 * HH2, HH2, 8 * H, H, SH,
      cvT, SH, 2, 1);

  // ---------------- decoder ----------------
  for (int i = 0; i < L; ++i) {
    // z=4 batch: Q, K, V''(->vtb transposed), crossQ (slot 3 holds crossQ weights/bias)
    G_qkv<<<gQKVd, 256, 0, stream>>>(
        y_b, wDAT + (size_t)i * 8 * HH2, biasD + (size_t)i * 8 * H, nullptr, nullptr, qkvb,
        S, H, H, H, H, 0, 1.f, ZBIG, 0, 0, HH2, 0, H, SH,
        vtb, 0, 4, 2);
    fsa_k<<<gFSA, 512, FSA_SMEM, stream>>>(qkvb, qkvb + SH, vtb, sparts, Zp);
    r4zrln_k<<<dim3(S), 256, 0, stream>>>(sparts, Zp, bvoAll + (size_t)(6 + i) * H, y_b,
        dlnw + (size_t)(i * 3) * H, dlnb + (size_t)(i * 3) * H, y_b);
    // cross-attn (Q precomputed in batch at slot 3)
    fsa_k<<<gFSA, 512, FSA_SMEM, stream>>>(qkvb + 3 * SH, ckvA + (size_t)(2 * i) * SH,
                                           cvT + (size_t)i * SH, sparts, Zp);
    r4zrln_k<<<dim3(S), 256, 0, stream>>>(sparts, Zp, bvoAll + (size_t)(12 + i) * H, y_b,
        dlnw + (size_t)(i * 3 + 1) * H, dlnb + (size_t)(i * 3 + 1) * H, y_b);
    // FFN
    G_ff1<<<gFF1, 256, 0, stream>>>(
        y_b, wD1T + (size_t)i * HF, db1 + (size_t)i * F, nullptr, nullptr, ff1b,
        S, F, H, H, H, 0, 1.f, 1, 0, 0, 0, 0, 0, 0,
        nullptr, 0, 1, -1);
    G_spl<<<gSPL, 256, 0, stream>>>(
        ff1b, wD2T + (size_t)i * HF, nullptr, nullptr, nullptr, sparts,
        S, H, F / 4, F, F, F / 4, 1.f, 1, 0, 0, 0, 0, 0, SH,
        nullptr, 0, 1, -1);
    r4rln_k<<<dim3(S), 256, 0, stream>>>(sparts, db2 + (size_t)i * H, y_b,
        dlnw + (size_t)(i * 3 + 2) * H, dlnb + (size_t)(i * 3 + 2) * H, y_b);
  }
  // final norm + feats + hierarchical parallel viterbi
  lnb_k<<<dim3(S), 256, 0, stream>>>(y_b, dnw, dnb, tmpf, memb);
  feats_k<<<dim3(S / 8), 256, 0, stream>>>(tmpf, h2tw, h2tb, ftsf);
  float* outF = (float*)d_out;
  vit_p1<<<dim3(VC), 256, 0, stream>>>(ftsf, trns, McB);
  vit_p1b<<<dim3(VC / 4), 256, 0, stream>>>(McB, McrsB);
  vit_p2<<<dim3(1), 64, 0, stream>>>(McrsB, trns, bfvF, termB, outF);
  vit_p2b<<<dim3(VC / 4), 64, 0, stream>>>(McB, bfvF);
  vit_p3<<<dim3(VC), 64, 0, stream>>>(ftsf, trns, bfvF, bpgB);
  vit_p4<<<dim3(1), VC, 0, stream>>>(bpgB, termB, outF);
}

// Round 26
// 1242.952 us; speedup vs baseline: 1.0600x; 1.0600x over previous
//
#include <hip/hip_runtime.h>
#include <cstdint>

#define SS 2048
#define HHd 512
#define FFd 2048
#define TTd 32
#define LLd 6
#define VW 16
#define VC 128

typedef float f32x4 __attribute__((ext_vector_type(4)));
typedef __bf16 bf16x8 __attribute__((ext_vector_type(8)));
typedef short short8v __attribute__((ext_vector_type(8)));
typedef short short4v __attribute__((ext_vector_type(4)));

__device__ __forceinline__ short f2b(float f) {
  unsigned u = __builtin_bit_cast(unsigned, f);
  u += 0x7fffu + ((u >> 16) & 1u);
  return (short)(u >> 16);
}
__device__ __forceinline__ float b2f(short s) {
  unsigned u = ((unsigned)(unsigned short)s) << 16;
  return __builtin_bit_cast(float, u);
}

typedef const __attribute__((address_space(1))) void gv_t;
typedef __attribute__((address_space(3))) void lv_t;
__device__ __forceinline__ void gload16(const void* g, void* l) {
  __builtin_amdgcn_global_load_lds((gv_t*)g, (lv_t*)l, 16, 0, 0);
}

// ------------------------------ GEMM (all-TB, BK=64, swizzled LDS, double-buffered 2-phase) ------------------------------
// C[M,N] = A[M,K] @ B^T. z-batching: A += z*as1; B += (z/zdiv)*bs1 + (z%zdiv)*bs2; C += z*cStr.
// TRBE: when (z % tmod)==tval, write C^T (bf16) to CbT + (z/zdiv)*ctStr instead (LDS-staged coalesced).
// Pipeline: issue L(k+1) into alternate buffer -> MFMA on buf[k] (loads fly under compute) -> barrier.
template<int BMt, int BNt, bool BIAS, bool RELU, bool RESID, bool OUTF, bool OUTB, bool TRBE>
__global__ __launch_bounds__(256) void gemm3(
    const short* __restrict__ A, const short* __restrict__ Bb,
    const float* __restrict__ biasb, const float* __restrict__ resid,
    float* __restrict__ Cfb, short* __restrict__ Cbb,
    int M, int N, int K, int lda, int ldb, int kzS, float scale,
    int zdiv, long as1, long bs1, long bs2, int bb1, int bb2, long cStr,
    short* __restrict__ CbT, long ctStr, int tmod, int tval)
{
  constexpr int MR = BMt / 32, NR = BNt / 32;
  constexpr int WMt = BMt / 2, WNt = BNt / 2;
  constexpr int ACALLS = BMt / 8;
  constexpr int TOT = (BMt + BNt) / 8;
  constexpr int CPW = TOT / 4;
  constexpr int HALF = BMt * 64 + BNt * 64;

  const int z = blockIdx.z;
  const short* Ap = A + (long)z * as1;
  const short* Bp = Bb + (long)(z / zdiv) * bs1 + (long)(z % zdiv) * bs2;
  const float* bias = BIAS ? (biasb + (z / zdiv) * bb1 + (z % zdiv) * bb2) : nullptr;
  const int kz = z * kzS;

  const int m0 = blockIdx.y * BMt;
  const int n0 = blockIdx.x * BNt;

  __shared__ __align__(16) short LDSbuf[2 * HALF];

  const int tid = threadIdx.x;
  const int lane = tid & 63;
  const int w = tid >> 6;

  const short* srcs[CPW];
  int loff[CPW];
  {
    const int rl8 = lane >> 3;
    const int c16 = (lane & 7) ^ rl8;
#pragma unroll
    for (int c = 0; c < CPW; ++c) {
      int q = w * CPW + c;
      if (q < ACALLS) {
        int row = q * 8 + rl8;
        srcs[c] = Ap + (long)(m0 + row) * lda + kz + c16 * 8;
        loff[c] = q * 512;
      } else {
        int row = (q - ACALLS) * 8 + rl8;
        srcs[c] = Bp + (long)(n0 + row) * ldb + kz + c16 * 8;
        loff[c] = BMt * 64 + (q - ACALLS) * 512;
      }
    }
  }

  const int lrow = lane & 15;
  const int slotb = lane >> 4;
  const int wm = (w >> 1) * WMt, wn = (w & 1) * WNt;

  f32x4 acc[MR][NR] = {};

  // prologue: stage tile 0 into buffer 0
#pragma unroll
  for (int c = 0; c < CPW; ++c) gload16(srcs[c], LDSbuf + loff[c]);
#pragma unroll
  for (int c = 0; c < CPW; ++c) srcs[c] += 64;
  __syncthreads();

  const int NIT = K >> 6;
  for (int it = 0; it < NIT; ++it) {
    const int cur = it & 1;
    if (it + 1 < NIT) {
      const int nxt = (cur ^ 1) * HALF;
#pragma unroll
      for (int c = 0; c < CPW; ++c) gload16(srcs[c], LDSbuf + nxt + loff[c]);
#pragma unroll
      for (int c = 0; c < CPW; ++c) srcs[c] += 64;
    }
    const short* As = LDSbuf + cur * HALF;
    const short* Bs = As + BMt * 64;
#pragma unroll
    for (int s = 0; s < 2; ++s) {
      bf16x8 af[MR], bfv[NR];
#pragma unroll
      for (int f = 0; f < MR; ++f) {
        int row = wm + f * 16 + lrow;
        int phys = (slotb + s * 4) ^ (row & 7);
        af[f] = *(const bf16x8*)&As[row * 64 + phys * 8];
      }
#pragma unroll
      for (int f = 0; f < NR; ++f) {
        int row = wn + f * 16 + lrow;
        int phys = (slotb + s * 4) ^ (row & 7);
        bfv[f] = *(const bf16x8*)&Bs[row * 64 + phys * 8];
      }
#pragma unroll
      for (int i = 0; i < MR; ++i)
#pragma unroll
        for (int j = 0; j < NR; ++j)
          acc[i][j] = __builtin_amdgcn_mfma_f32_16x16x32_bf16(af[i], bfv[j], acc[i][j], 0, 0, 0);
    }
    __syncthreads();   // drains L(it+1); frees buf[cur]
  }

  const int crow = (lane >> 4) * 4;
  const int ccol = lane & 15;
  const bool dotr = TRBE && ((z % tmod) == tval);

  if (OUTB) {
    if (dotr) {
      short* Cb = CbT + (long)(z / zdiv) * ctStr;
      constexpr int LDSW = BMt + 8;
      short* Os = LDSbuf;
#pragma unroll
      for (int i = 0; i < MR; ++i) {
#pragma unroll
        for (int j = 0; j < NR; ++j) {
          int lc = wn + j * 16 + ccol;
          float bv = BIAS ? bias[n0 + lc] : 0.f;
#pragma unroll
          for (int r = 0; r < 4; ++r) {
            int lr = wm + i * 16 + crow + r;
            Os[lc * LDSW + lr] = f2b(acc[i][j][r] * scale + bv);
          }
        }
      }
      __syncthreads();
      constexpr int CPR = BMt / 8;
      constexpr int CPT = (BMt * BNt / 8) / 256;
#pragma unroll
      for (int c = 0; c < CPT; ++c) {
        int idx = tid + c * 256;
        int col = idx / CPR;
        int rowc = (idx % CPR) * 8;
        int4 vv = *(const int4*)&Os[col * LDSW + rowc];
        *(int4*)&Cb[(long)(n0 + col) * M + m0 + rowc] = vv;
      }
    } else {
      short* Cb = Cbb + (long)z * cStr;
      constexpr int LDSW = BNt + 8;
      short* Os = LDSbuf;
#pragma unroll
      for (int i = 0; i < MR; ++i) {
#pragma unroll
        for (int j = 0; j < NR; ++j) {
          int lc = wn + j * 16 + ccol;
          float bv = BIAS ? bias[n0 + lc] : 0.f;
#pragma unroll
          for (int r = 0; r < 4; ++r) {
            int lr = wm + i * 16 + crow + r;
            float v = acc[i][j][r] * scale + bv;
            if (RELU) v = v > 0.f ? v : 0.f;
            Os[lr * LDSW + lc] = f2b(v);
          }
        }
      }
      __syncthreads();
      constexpr int CPR = BNt / 8;
      constexpr int CPT = (BMt * BNt / 8) / 256;
#pragma unroll
      for (int c = 0; c < CPT; ++c) {
        int idx = tid + c * 256;
        int row = idx / CPR;
        int col8 = (idx % CPR) * 8;
        int4 vv = *(const int4*)&Os[row * LDSW + col8];
        *(int4*)&Cb[(long)(m0 + row) * N + n0 + col8] = vv;
      }
    }
  } else {
    float* Cf = Cfb + (long)z * cStr;
#pragma unroll
    for (int i = 0; i < MR; ++i) {
#pragma unroll
      for (int j = 0; j < NR; ++j) {
        int gc = n0 + wn + j * 16 + ccol;
        float bv = BIAS ? bias[gc] : 0.f;
#pragma unroll
        for (int r = 0; r < 4; ++r) {
          int gr = m0 + wm + i * 16 + crow + r;
          long off = (long)gr * N + gc;
          float v = acc[i][j][r] * scale + bv;
          if (RESID) v += resid[off];
          if (RELU) v = v > 0.f ? v : 0.f;
          Cf[off] = v;
        }
      }
    }
  }
}

// ============================== Fused attention (q-tile 64, key-split 8, 8 waves, 2-phase) ==============================
#define FSA_SMEM (64 * 512 * 2 + 512 * 64 * 2 + 64 * 64 * 2 + 128 * 4)
__global__ __launch_bounds__(512) void fsa_k(
    const short* __restrict__ Q, const short* __restrict__ Kmat,
    const short* __restrict__ VT, short* __restrict__ Op, float* __restrict__ Zp) {
  extern __shared__ __align__(16) char smem[];
  short* Ks  = (short*)smem;           // [64][512]  (Q stage / K chunk / O stage)
  short* Vts = Ks + 64 * 512;          // [512][64]
  short* Ps  = Vts + 512 * 64;         // [64][64]
  float* Zs  = (float*)(Ps + 64 * 64); // [2][64]
  const float RSQ = 0.04419417382415922f;

  const int z = blockIdx.x;            // key split (0..7)
  const int q0 = blockIdx.y * 64;
  const int key0 = z * 256;
  const int tid = threadIdx.x, lane = tid & 63, w = tid >> 6;
  const int qg = w >> 1;               // 0..3 q-group (16 rows each)
  const int kh = w & 1;
  const int wn = kh * 32, wn2 = kh * 256;
  const int lrow = lane & 15, lgrp = lane >> 4;

  // stage Q (64 rows)
  for (int c = 0; c < 8; ++c) {
    int row = w * 8 + c;
    const short* src = Q + (long)(q0 + row) * HHd + (lane ^ (row & 7)) * 8;
    gload16(src, &Ks[row * 512]);
  }
  __syncthreads();
  bf16x8 qf[16];
#pragma unroll
  for (int st = 0; st < 16; ++st) {
    int row = qg * 16 + lrow;
    int phys = (st * 4 + lgrp) ^ (row & 7);
    qf[st] = *(const bf16x8*)&Ks[row * 512 + phys * 8];
  }
  __syncthreads();

  // prologue: stage K(0)
  for (int c = 0; c < 8; ++c) {
    int row = w * 8 + c;
    const short* src = Kmat + (long)(key0 + row) * HHd + (lane ^ (row & 7)) * 8;
    gload16(src, &Ks[row * 512]);
  }
  __syncthreads();

  f32x4 accO[16] = {};
  float zacc[4] = {};

  for (int kc = 0; kc < 4; ++kc) {
    // issue V(kc) — flies under QK compute
    for (int c = 0; c < 8; ++c) {
      int rb = (w * 8 + c) * 8;
      int vrow = rb + (lane >> 3);
      const short* src = VT + (long)vrow * SS + key0 + kc * 64 + ((lane & 7) ^ (vrow & 7)) * 8;
      gload16(src, &Vts[rb * 64]);
    }
    f32x4 accS0 = {}, accS1 = {};
#pragma unroll
    for (int st = 0; st < 16; ++st) {
      int row0 = wn + lrow;
      int phys0 = (st * 4 + lgrp) ^ (row0 & 7);
      bf16x8 b0 = *(const bf16x8*)&Ks[row0 * 512 + phys0 * 8];
      int row1 = wn + 16 + lrow;
      int phys1 = (st * 4 + lgrp) ^ (row1 & 7);
      bf16x8 b1 = *(const bf16x8*)&Ks[row1 * 512 + phys1 * 8];
      accS0 = __builtin_amdgcn_mfma_f32_16x16x32_bf16(qf[st], b0, accS0, 0, 0, 0);
      accS1 = __builtin_amdgcn_mfma_f32_16x16x32_bf16(qf[st], b1, accS1, 0, 0, 0);
    }
#pragma unroll
    for (int f = 0; f < 2; ++f) {
#pragma unroll
      for (int r = 0; r < 4; ++r) {
        int row = qg * 16 + lgrp * 4 + r;
        int col = wn + f * 16 + lrow;
        float sv = f ? accS1[r] : accS0[r];
        float e = __expf(sv * RSQ);
        zacc[r] += e;
        int slot = col >> 3;
        Ps[row * 64 + ((slot ^ (row & 7)) * 8) + (col & 7)] = f2b(e);
      }
    }
    __syncthreads();   // drains V(kc); P visible; Ks free (QK done)
    // issue K(kc+1) — flies under PV compute
    if (kc < 3) {
      for (int c = 0; c < 8; ++c) {
        int row = w * 8 + c;
        const short* src = Kmat + (long)(key0 + (kc + 1) * 64 + row) * HHd + (lane ^ (row & 7)) * 8;
        gload16(src, &Ks[row * 512]);
      }
    }
#pragma unroll
    for (int kk = 0; kk < 2; ++kk) {
      int prow = qg * 16 + lrow;
      int pphys = (kk * 4 + lgrp) ^ (prow & 7);
      bf16x8 pa = *(const bf16x8*)&Ps[prow * 64 + pphys * 8];
#pragma unroll
      for (int n = 0; n < 16; ++n) {
        int vrow = wn2 + n * 16 + lrow;
        int vphys = (kk * 4 + lgrp) ^ (vrow & 7);
        bf16x8 vb = *(const bf16x8*)&Vts[vrow * 64 + vphys * 8];
        accO[n] = __builtin_amdgcn_mfma_f32_16x16x32_bf16(pa, vb, accO[n], 0, 0, 0);
      }
    }
    __syncthreads();   // drains K(kc+1); Vts/Ps free for next iteration
  }

  // epilogue: stage O as bf16 into Ks (linear [64][512]) + Z shuffles
#pragma unroll
  for (int n = 0; n < 16; ++n) {
#pragma unroll
    for (int r = 0; r < 4; ++r) {
      int row = qg * 16 + lgrp * 4 + r;
      int col = wn2 + n * 16 + lrow;
      Ks[row * 512 + col] = f2b(accO[n][r]);
    }
  }
#pragma unroll
  for (int r = 0; r < 4; ++r) {
    float v = zacc[r];
    v += __shfl_xor(v, 1); v += __shfl_xor(v, 2);
    v += __shfl_xor(v, 4); v += __shfl_xor(v, 8);
    if (lrow == 0) Zs[kh * 64 + qg * 16 + lgrp * 4 + r] = v;
  }
  __syncthreads();
  short* OpZ = Op + (long)z * (long)SS * HHd + (long)q0 * HHd;
#pragma unroll
  for (int c = 0; c < 8; ++c) {
    int idx = tid + c * 512;
    *(int4*)&OpZ[idx * 8] = *(const int4*)&Ks[idx * 8];
  }
  if (tid < 64) Zp[(long)z * SS + q0 + tid] = Zs[tid] + Zs[64 + tid];
}

// ---------------- fused attention tail: (sum8 bf16-O)/Z + bvo + bf16 resid + LayerNorm -> bf16 ----------------
__global__ __launch_bounds__(256) void r4zrln_k(const short* __restrict__ pb,
                                                const float* __restrict__ Zp,
                                                const float* __restrict__ bvo,
                                                const short* __restrict__ resid,
                                                const float* __restrict__ w, const float* __restrict__ b,
                                                short* __restrict__ Yb) {
  const long SH = (long)SS * HHd;
  const int row = blockIdx.x, tid = threadIdx.x;
  long base = (long)row * HHd;
  float zt = 0.f;
#pragma unroll
  for (int sk = 0; sk < 8; ++sk) zt += Zp[(long)sk * SS + row];
  float zi = 1.0f / zt;
  float a0 = 0.f, a1 = 0.f;
#pragma unroll
  for (int sk = 0; sk < 8; ++sk) {
    a0 += b2f(pb[sk * SH + base + tid]);
    a1 += b2f(pb[sk * SH + base + tid + 256]);
  }
  float x0 = a0 * zi + bvo[tid] + b2f(resid[base + tid]);
  float x1 = a1 * zi + bvo[tid + 256] + b2f(resid[base + tid + 256]);
  float s = x0 + x1;
#pragma unroll
  for (int o = 32; o; o >>= 1) s += __shfl_xor(s, o);
  __shared__ float r1[4], r2[4];
  if ((tid & 63) == 0) r1[tid >> 6] = s;
  __syncthreads();
  float mean = (r1[0] + r1[1] + r1[2] + r1[3]) * (1.f / HHd);
  float d0 = x0 - mean, d1 = x1 - mean;
  float q = d0 * d0 + d1 * d1;
#pragma unroll
  for (int o = 32; o; o >>= 1) q += __shfl_xor(q, o);
  if ((tid & 63) == 0) r2[tid >> 6] = q;
  __syncthreads();
  float var = (r2[0] + r2[1] + r2[2] + r2[3]) * (1.f / HHd);
  float rs = rsqrtf(var + 1e-5f);
  float o0 = d0 * rs * w[tid] + b[tid];
  float o1 = d1 * rs * w[tid + 256] + b[tid + 256];
  Yb[base + tid] = f2b(o0); Yb[base + tid + 256] = f2b(o1);
}

// ---------------- split-K=4 bf16 reduce + bias + bf16 resid + LayerNorm -> bf16 (FFN2) ----------------
__global__ __launch_bounds__(256) void r4rln_k(const short* __restrict__ pb,
                                               const float* __restrict__ bias,
                                               const short* __restrict__ resid,
                                               const float* __restrict__ w, const float* __restrict__ b,
                                               short* __restrict__ Yb) {
  const long SH = (long)SS * HHd;
  const int row = blockIdx.x, tid = threadIdx.x;
  long base = (long)row * HHd;
  float x0 = bias[tid] + b2f(resid[base + tid]);
  float x1 = bias[tid + 256] + b2f(resid[base + tid + 256]);
#pragma unroll
  for (int sk = 0; sk < 4; ++sk) {
    x0 += b2f(pb[sk * SH + base + tid]);
    x1 += b2f(pb[sk * SH + base + tid + 256]);
  }
  float s = x0 + x1;
#pragma unroll
  for (int o = 32; o; o >>= 1) s += __shfl_xor(s, o);
  __shared__ float r1[4], r2[4];
  if ((tid & 63) == 0) r1[tid >> 6] = s;
  __syncthreads();
  float mean = (r1[0] + r1[1] + r1[2] + r1[3]) * (1.f / HHd);
  float d0 = x0 - mean, d1 = x1 - mean;
  float q = d0 * d0 + d1 * d1;
#pragma unroll
  for (int o = 32; o; o >>= 1) q += __shfl_xor(q, o);
  if ((tid & 63) == 0) r2[tid >> 6] = q;
  __syncthreads();
  float var = (r2[0] + r2[1] + r2[2] + r2[3]) * (1.f / HHd);
  float rs = rsqrtf(var + 1e-5f);
  float o0 = d0 * rs * w[tid] + b[tid];
  float o1 = d1 * rs * w[tid + 256] + b[tid + 256];
  Yb[base + tid] = f2b(o0); Yb[base + tid + 256] = f2b(o1);
}

// ---------------- LayerNorm over bf16 rows; optional f32 out + bf16 out ----------------
__global__ __launch_bounds__(256) void lnb_k(const short* __restrict__ Xb, const float* __restrict__ w,
                                             const float* __restrict__ b, float* __restrict__ Yf,
                                             short* __restrict__ Yb) {
  const int row = blockIdx.x;
  const int tid = threadIdx.x;
  long base = (long)row * HHd;
  float x0 = b2f(Xb[base + tid]), x1 = b2f(Xb[base + tid + 256]);
  float s = x0 + x1;
#pragma unroll
  for (int o = 32; o; o >>= 1) s += __shfl_xor(s, o);
  __shared__ float r1[4], r2[4];
  if ((tid & 63) == 0) r1[tid >> 6] = s;
  __syncthreads();
  float mean = (r1[0] + r1[1] + r1[2] + r1[3]) * (1.f / HHd);
  float d0 = x0 - mean, d1 = x1 - mean;
  float q = d0 * d0 + d1 * d1;
#pragma unroll
  for (int o = 32; o; o >>= 1) q += __shfl_xor(q, o);
  if ((tid & 63) == 0) r2[tid >> 6] = q;
  __syncthreads();
  float var = (r2[0] + r2[1] + r2[2] + r2[3]) * (1.f / HHd);
  float rs = rsqrtf(var + 1e-5f);
  float o0 = d0 * rs * w[tid] + b[tid];
  float o1 = d1 * rs * w[tid + 256] + b[tid + 256];
  if (Yf) { Yf[base + tid] = o0; Yf[base + tid + 256] = o1; }
  Yb[base + tid] = f2b(o0); Yb[base + tid + 256] = f2b(o1);
}

// ---------------- f32 [K,N] -> bf16 [N,K] transpose-convert (batched z) ----------------
__global__ __launch_bounds__(256) void tconv_k(const float* __restrict__ in, short* __restrict__ out,
                                               int K, int N) {
  __shared__ float t[32][33];
  long zo = (long)blockIdx.z * K * N;
  int n0 = blockIdx.x * 32, k0 = blockIdx.y * 32;
  int tx = threadIdx.x & 31, ty = threadIdx.x >> 5;
#pragma unroll
  for (int i = 0; i < 4; ++i)
    t[ty + i * 8][tx] = in[zo + (long)(k0 + ty + i * 8) * N + n0 + tx];
  __syncthreads();
#pragma unroll
  for (int i = 0; i < 4; ++i)
    out[zo + (long)(n0 + ty + i * 8) * K + k0 + tx] = f2b(t[tx][ty + i * 8]);
}

// ---------------- plain strided f32 -> bf16 convert (batched z) ----------------
__global__ __launch_bounds__(256) void pconv_k(const float* __restrict__ in, short* __restrict__ out,
                                               long inStride, long outStride) {
  long i = ((long)blockIdx.x * 256 + threadIdx.x) * 4;
  const float* ip = in + (long)blockIdx.z * inStride + i;
  short* op = out + (long)blockIdx.z * outStride + i;
  float4 v = *(const float4*)ip;
  short4v o;
  o[0] = f2b(v.x); o[1] = f2b(v.y); o[2] = f2b(v.z); o[3] = f2b(v.w);
  *(short4v*)op = o;
}

// ---------------- bf16 strided copy (batched z) ----------------
__global__ __launch_bounds__(256) void scpy_k(const short* __restrict__ src, short* __restrict__ dst,
                                              long srcStride, long dstStride) {
  long i = ((long)blockIdx.x * 256 + threadIdx.x) * 4;
  *(short4v*)(dst + (long)blockIdx.z * dstStride + i) =
      *(const short4v*)(src + (long)blockIdx.z * srcStride + i);
}

// ---------------- bias slot copy: biasD[l*8+3] <- dab[l*8+4] ----------------
__global__ __launch_bounds__(256) void bcpy_k(const float* __restrict__ src, float* __restrict__ dst) {
  int i = blockIdx.x * 256 + threadIdx.x;  // over L*H
  int l = i >> 9, c = i & 511;
  dst[(l * 8 + 3) * HHd + c] = src[(l * 8 + 4) * HHd + c];
}

// ---------------- bias table copy with zeroed j-slots ----------------
__global__ __launch_bounds__(256) void zbias_k(const float* __restrict__ src, float* __restrict__ dst,
                                               int nj, unsigned jmask, int total) {
  int i = blockIdx.x * 256 + threadIdx.x;
  if (i >= total) return;
  int j = (i >> 9) % nj;
  dst[i] = ((jmask >> j) & 1u) ? 0.f : src[i];
}

// ---------------- bvo partials: row-major streaming (18 combos x 16 m-groups) ----------------
__global__ __launch_bounds__(256) void bvoP_k(const float* __restrict__ eaw, const float* __restrict__ eab,
                                              const float* __restrict__ daw, const float* __restrict__ dab,
                                              float* __restrict__ part) {
  const long HH2 = (long)HHd * HHd;
  const int b = blockIdx.x, mg = blockIdx.y, tid = threadIdx.x;
  const float* Wout; const float* bv;
  if (b < 6) {
    int i = b;
    Wout = eaw + (i * 4 + 3) * HH2; bv = eab + (i * 4 + 2) * HHd;
  } else if (b < 12) {
    int i = b - 6;
    Wout = daw + (i * 8 + 3) * HH2; bv = dab + (i * 8 + 2) * HHd;
  } else {
    int i = b - 12;
    Wout = daw + (i * 8 + 7) * HH2; bv = dab + (i * 8 + 6) * HHd;
  }
  float a0 = 0.f, a1 = 0.f;
#pragma unroll 4
  for (int m = mg * 32; m < mg * 32 + 32; ++m) {
    float bvm = bv[m];
    a0 = fmaf(bvm, Wout[(long)m * HHd + tid], a0);
    a1 = fmaf(bvm, Wout[(long)m * HHd + tid + 256], a1);
  }
  long o = ((long)b * 16 + mg) * HHd;
  part[o + tid] = a0;
  part[o + tid + 256] = a1;
}

// ---------------- bvo reduce: sum 16 partials + bout ----------------
__global__ __launch_bounds__(256) void bvoR_k(const float* __restrict__ part,
                                              const float* __restrict__ eab, const float* __restrict__ dab,
                                              float* __restrict__ bvoAll) {
  const int b = blockIdx.x, tid = threadIdx.x;
  const float* bout;
  if (b < 6) bout = eab + (b * 4 + 3) * HHd;
  else if (b < 12) bout = dab + ((b - 6) * 8 + 3) * HHd;
  else bout = dab + ((b - 12) * 8 + 7) * HHd;
  float s0 = bout[tid], s1 = bout[tid + 256];
#pragma unroll
  for (int mg = 0; mg < 16; ++mg) {
    long o = ((long)b * 16 + mg) * HHd;
    s0 += part[o + tid];
    s1 += part[o + tid + 256];
  }
  bvoAll[(long)b * HHd + tid] = s0;
  bvoAll[(long)b * HHd + tid + 256] = s1;
}

// ------------------------------ embedding gather (bf16 only) ------------------------------
__global__ __launch_bounds__(256) void gather_k(const int* __restrict__ sent, const float* __restrict__ emb,
                                                short* __restrict__ hb, short* __restrict__ yb) {
  long i = (long)blockIdx.x * 256 + threadIdx.x;
  int s = (int)(i >> 9);
  int hcol = (int)(i & 511);
  float v = emb[(long)sent[s] * HHd + hcol];
  short bb = f2b(v);
  hb[i] = bb; yb[i] = bb;
}

// ------------------------------ feats: [SS,HHd] @ [HHd,TTd] + b (f32) ------------------------------
__global__ __launch_bounds__(256) void feats_k(const float* __restrict__ Y, const float* __restrict__ W,
                                               const float* __restrict__ b, float* __restrict__ feats) {
  __shared__ float ys[8 * HHd];
  const int row0 = blockIdx.x * 8;
  for (int i = threadIdx.x; i < 8 * HHd; i += 256) ys[i] = Y[(long)row0 * HHd + i];
  __syncthreads();
  const int n = threadIdx.x & 31, r = threadIdx.x >> 5;
  float acc = b[n];
  const float* yr = &ys[r * HHd];
  for (int k = 0; k < HHd; ++k) acc = fmaf(yr[k], W[k * TTd + n], acc);
  feats[(long)(row0 + r) * TTd + n] = acc;
}

// ============================== Parallel Viterbi (hierarchical max-plus scan) ==============================
__global__ __launch_bounds__(256) void vit_p1(const float* __restrict__ feats,
                                              const float* __restrict__ trans,
                                              float* __restrict__ Mc) {
  __shared__ float trS[1024];
  __shared__ float fS[VW * 32];
  __shared__ float Ga[32 * 33], Gb[32 * 33];
  const int c = blockIdx.x, tid = threadIdx.x;
  for (int i = tid; i < 1024; i += 256) trS[i] = trans[i];
  for (int i = tid; i < VW * 32; i += 256) fS[i] = feats[c * VW * 32 + i];
  __syncthreads();
  for (int i = tid; i < 1024; i += 256) {
    int n = i >> 5, q = i & 31;
    Ga[n * 33 + q] = trS[i] + fS[n];
  }
  __syncthreads();
  float* G = Ga;
  float* Gn = Gb;
  const int q = tid & 31, nb = (tid >> 5) * 4;
  for (int s = 1; s < VW; ++s) {
    float m0 = -3.0e38f, m1 = -3.0e38f, m2 = -3.0e38f, m3 = -3.0e38f;
    for (int pp = 0; pp < 32; ++pp) {
      float g = G[pp * 33 + q];
      m0 = fmaxf(m0, trS[(nb + 0) * 32 + pp] + g);
      m1 = fmaxf(m1, trS[(nb + 1) * 32 + pp] + g);
      m2 = fmaxf(m2, trS[(nb + 2) * 32 + pp] + g);
      m3 = fmaxf(m3, trS[(nb + 3) * 32 + pp] + g);
    }
    Gn[(nb + 0) * 33 + q] = m0 + fS[s * 32 + nb + 0];
    Gn[(nb + 1) * 33 + q] = m1 + fS[s * 32 + nb + 1];
    Gn[(nb + 2) * 33 + q] = m2 + fS[s * 32 + nb + 2];
    Gn[(nb + 3) * 33 + q] = m3 + fS[s * 32 + nb + 3];
    __syncthreads();
    float* t = G; G = Gn; Gn = t;
  }
  for (int i = tid; i < 1024; i += 256) Mc[c * 1024 + i] = G[(i >> 5) * 33 + (i & 31)];
}

__global__ __launch_bounds__(256) void vit_p1b(const float* __restrict__ Mf, float* __restrict__ Mcrs) {
  __shared__ float Ga[32 * 33], Gb[32 * 33], Ms[1024];
  const int c = blockIdx.x, tid = threadIdx.x;
  for (int i = tid; i < 1024; i += 256) Ga[(i >> 5) * 33 + (i & 31)] = Mf[(4 * c) * 1024 + i];
  float* G = Ga;
  float* Gn = Gb;
  const int q = tid & 31, nb = (tid >> 5) * 4;
  for (int j = 1; j < 4; ++j) {
    for (int i = tid; i < 1024; i += 256) Ms[i] = Mf[(4 * c + j) * 1024 + i];
    __syncthreads();
    float m0 = -3.0e38f, m1 = -3.0e38f, m2 = -3.0e38f, m3 = -3.0e38f;
    for (int pp = 0; pp < 32; ++pp) {
      float g = G[pp * 33 + q];
      m0 = fmaxf(m0, Ms[(nb + 0) * 32 + pp] + g);
      m1 = fmaxf(m1, Ms[(nb + 1) * 32 + pp] + g);
      m2 = fmaxf(m2, Ms[(nb + 2) * 32 + pp] + g);
      m3 = fmaxf(m3, Ms[(nb + 3) * 32 + pp] + g);
    }
    Gn[(nb + 0) * 33 + q] = m0;
    Gn[(nb + 1) * 33 + q] = m1;
    Gn[(nb + 2) * 33 + q] = m2;
    Gn[(nb + 3) * 33 + q] = m3;
    __syncthreads();
    float* t = G; G = Gn; Gn = t;
  }
  for (int i = tid; i < 1024; i += 256) Mcrs[c * 1024 + i] = G[(i >> 5) * 33 + (i & 31)];
}

__device__ __forceinline__ float vstep(float fv, int p0, const f32x4& M0, const f32x4& M1,
                                       const f32x4& M2, const f32x4& M3) {
  float mv[16];
#pragma unroll
  for (int j = 0; j < 4; ++j) { mv[j] = M0[j]; mv[4 + j] = M1[j]; mv[8 + j] = M2[j]; mv[12 + j] = M3[j]; }
  float cnd[16];
#pragma unroll
  for (int j = 0; j < 16; ++j) cnd[j] = __shfl(fv, p0 + j) + mv[j];
  float t8[8], t4[4];
#pragma unroll
  for (int j = 0; j < 8; ++j) t8[j] = fmaxf(cnd[2 * j], cnd[2 * j + 1]);
#pragma unroll
  for (int j = 0; j < 4; ++j) t4[j] = fmaxf(t8[2 * j], t8[2 * j + 1]);
  float bv = fmaxf(fmaxf(t4[0], t4[1]), fmaxf(t4[2], t4[3]));
  return fmaxf(bv, __shfl_xor(bv, 32));
}

__global__ __launch_bounds__(64) void vit_p2(const float* __restrict__ Mcrs,
                                             const float* __restrict__ trans,
                                             float* __restrict__ bfvF,
                                             float* __restrict__ term,
                                             float* __restrict__ out) {
  const int lane = threadIdx.x, n = lane & 31, h = lane >> 5, p0 = h << 4;
  float fv = (n == 30) ? 0.f : -10000.f;
  if (lane < 32) bfvF[n] = fv;
  const float* base = Mcrs + n * 32 + p0;
  f32x4 A0, A1, A2, A3, B0, B1, B2, B3, C0, C1, C2, C3;
#define LDM(d0, d1, d2, d3, c) { const float* M = base + (c) * 1024; \
  d0 = *(const f32x4*)M; d1 = *(const f32x4*)(M + 4); d2 = *(const f32x4*)(M + 8); d3 = *(const f32x4*)(M + 12); }
  LDM(A0, A1, A2, A3, 0) LDM(B0, B1, B2, B3, 1) LDM(C0, C1, C2, C3, 2)
#pragma unroll 1
  for (int c = 0; c < 30; c += 3) {
    fv = vstep(fv, p0, A0, A1, A2, A3); if (lane < 32) bfvF[(4 * (c + 1)) * 32 + n] = fv;
    { int cl = (c + 3) & 31; LDM(A0, A1, A2, A3, cl) }
    fv = vstep(fv, p0, B0, B1, B2, B3); if (lane < 32) bfvF[(4 * (c + 2)) * 32 + n] = fv;
    { int cl = (c + 4) & 31; LDM(B0, B1, B2, B3, cl) }
    fv = vstep(fv, p0, C0, C1, C2, C3); if (lane < 32) bfvF[(4 * (c + 3)) * 32 + n] = fv;
    { int cl = (c + 5) & 31; LDM(C0, C1, C2, C3, cl) }
  }
  fv = vstep(fv, p0, A0, A1, A2, A3); if (lane < 32) bfvF[(4 * 31) * 32 + n] = fv;
  fv = vstep(fv, p0, B0, B1, B2, B3); if (lane < 32) bfvF[(4 * 32) * 32 + n] = fv;
#undef LDM
  float v = fv + trans[31 * 32 + n];
  int idx = n;
#pragma unroll
  for (int o = 16; o; o >>= 1) {
    float ov = __shfl_xor(v, o);
    int oi = __shfl_xor(idx, o);
    if (ov > v || (ov == v && oi < idx)) { v = ov; idx = oi; }
  }
  if (lane == 0) { out[0] = v; term[0] = (float)idx; }
}

__global__ __launch_bounds__(64) void vit_p2b(const float* __restrict__ Mf, float* __restrict__ bfvF) {
  const int c = blockIdx.x, lane = threadIdx.x, n = lane & 31, h = lane >> 5, p0 = h << 4;
  float fv = bfvF[(4 * c) * 32 + n];
  const float* base = Mf + (size_t)(4 * c) * 1024 + n * 32 + p0;
#pragma unroll
  for (int j = 0; j < 3; ++j) {
    const float* M = base + j * 1024;
    f32x4 A0 = *(const f32x4*)M, A1 = *(const f32x4*)(M + 4);
    f32x4 A2 = *(const f32x4*)(M + 8), A3 = *(const f32x4*)(M + 12);
    fv = vstep(fv, p0, A0, A1, A2, A3);
    if (lane < 32) bfvF[(4 * c + j + 1) * 32 + n] = fv;
  }
}

__global__ __launch_bounds__(64) void vit_p3(const float* __restrict__ feats,
                                             const float* __restrict__ trans,
                                             const float* __restrict__ bfvF,
                                             unsigned char* __restrict__ bp) {
  const int c = blockIdx.x, lane = threadIdx.x, n = lane & 31, h = lane >> 5, p0 = h << 4;
  float tr[16];
#pragma unroll
  for (int j = 0; j < 16; ++j) tr[j] = trans[n * 32 + p0 + j];
  float fv = bfvF[c * 32 + n];
  float ft[VW];
  for (int s = 0; s < VW; ++s) ft[s] = feats[(c * VW + s) * 32 + n];
  for (int s = 0; s < VW; ++s) {
    float cd[16];
#pragma unroll
    for (int j = 0; j < 16; ++j) cd[j] = __shfl(fv, p0 + j) + tr[j];
    float v8[8]; int i8a[8];
#pragma unroll
    for (int j = 0; j < 8; ++j) {
      bool g = cd[2 * j + 1] > cd[2 * j];
      v8[j] = g ? cd[2 * j + 1] : cd[2 * j];
      i8a[j] = g ? 2 * j + 1 : 2 * j;
    }
    float v4[4]; int i4a[4];
#pragma unroll
    for (int j = 0; j < 4; ++j) {
      bool g = v8[2 * j + 1] > v8[2 * j];
      v4[j] = g ? v8[2 * j + 1] : v8[2 * j];
      i4a[j] = g ? i8a[2 * j + 1] : i8a[2 * j];
    }
    float v2[2]; int i2a[2];
#pragma unroll
    for (int j = 0; j < 2; ++j) {
      bool g = v4[2 * j + 1] > v4[2 * j];
      v2[j] = g ? v4[2 * j + 1] : v4[2 * j];
      i2a[j] = g ? i4a[2 * j + 1] : i4a[2 * j];
    }
    bool g1 = v2[1] > v2[0];
    float bv = g1 ? v2[1] : v2[0];
    int bi = p0 + (g1 ? i2a[1] : i2a[0]);
    float ov = __shfl_xor(bv, 32);
    int oi = __shfl_xor(bi, 32);
    bool takeo = h ? (ov >= bv) : (ov > bv);
    float m = takeo ? ov : bv;
    int mi = takeo ? oi : bi;
    if (!h) bp[(c * VW + s) * 32 + n] = (unsigned char)mi;
    fv = m + ft[s];
  }
}

__global__ __launch_bounds__(VC) void vit_p4(const unsigned char* __restrict__ bp,
                                             const float* __restrict__ term,
                                             float* __restrict__ out) {
  __shared__ unsigned char GsL[VC * 32];
  __shared__ unsigned char bnd[VC];
  const int lane = threadIdx.x;
  unsigned char g[32];
#pragma unroll
  for (int j = 0; j < 32; ++j) g[j] = (unsigned char)j;
  for (int s = VW - 1; s >= 0; --s) {
    const unsigned char* rowp = bp + (lane * VW + s) * 32;
#pragma unroll
    for (int j = 0; j < 32; ++j) g[j] = rowp[g[j]];
  }
#pragma unroll
  for (int j = 0; j < 32; ++j) GsL[lane * 32 + j] = g[j];
  __syncthreads();
  if (lane == 0) {
    bnd[VC - 1] = (unsigned char)(int)term[0];
    for (int cc = VC - 1; cc >= 1; --cc) bnd[cc - 1] = GsL[cc * 32 + bnd[cc]];
  }
  __syncthreads();
  int x = bnd[lane];
  out[1 + lane * VW + VW - 1] = (float)x;
  for (int k = VW - 2; k >= 0; --k) {
    x = bp[(lane * VW + k + 1) * 32 + x];
    out[1 + lane * VW + k] = (float)x;
  }
}

// ------------------------------ host ------------------------------
extern "C" void kernel_launch(void* const* d_in, const int* in_sizes, int n_in,
                              void* d_out, int out_size, void* d_ws, size_t ws_size,
                              hipStream_t stream) {
  (void)in_sizes; (void)n_in; (void)out_size; (void)ws_size;
  const int H = HHd, F = FFd, S = SS, L = LLd;
  const long HH2 = (long)H * H;
  const long SH = (long)S * H;
  const long HF = (long)H * F;

  hipFuncSetAttribute(reinterpret_cast<const void*>(fsa_k),
                      hipFuncAttributeMaxDynamicSharedMemorySize, FSA_SMEM);

  const int*   sent = (const int*)d_in[0];
  const float* embd = (const float*)d_in[1];
  const float* eaw  = (const float*)d_in[2];
  const float* eab  = (const float*)d_in[3];
  const float* ew1  = (const float*)d_in[4];
  const float* eb1  = (const float*)d_in[5];
  const float* ew2  = (const float*)d_in[6];
  const float* eb2  = (const float*)d_in[7];
  const float* elnw = (const float*)d_in[8];
  const float* elnb = (const float*)d_in[9];
  const float* daw  = (const float*)d_in[10];
  const float* dab  = (const float*)d_in[11];
  const float* dw1  = (const float*)d_in[12];
  const float* db1  = (const float*)d_in[13];
  const float* dw2  = (const float*)d_in[14];
  const float* db2  = (const float*)d_in[15];
  const float* dlnw = (const float*)d_in[16];
  const float* dlnb = (const float*)d_in[17];
  const float* enw  = (const float*)d_in[18];
  const float* enb  = (const float*)d_in[19];
  const float* dnw  = (const float*)d_in[20];
  const float* dnb  = (const float*)d_in[21];
  const float* h2tw = (const float*)d_in[22];
  const float* h2tb = (const float*)d_in[23];
  const float* trns = (const float*)d_in[24];

  char* p = (char*)d_ws;
  auto alloc = [&](size_t bytes) -> char* {
    char* r = p;
    p += (bytes + 255) & ~(size_t)255;
    return r;
  };
  short* wEAT = (short*)alloc((size_t)L * 4 * HH2 * 2);
  short* wDAT = (short*)alloc((size_t)L * 8 * HH2 * 2);
  short* wE1T = (short*)alloc((size_t)L * HF * 2);
  short* wE2T = (short*)alloc((size_t)L * HF * 2);
  short* wD1T = (short*)alloc((size_t)L * HF * 2);
  short* wD2T = (short*)alloc((size_t)L * HF * 2);
  short* h_b  = (short*)alloc(SH * 2);
  short* y_b  = (short*)alloc(SH * 2);
  float* tmpf = (float*)alloc(SH * 4);
  short* qkvb = (short*)alloc(4 * SH * 2);           // Q, K, V''-slot, crossQ
  float* scf  = (float*)alloc((size_t)4 * SH * 4);   // partial buffer (8x bf16 splits = 16MB; f32 alias prologue)
  float* Zp   = (float*)alloc((size_t)8 * S * 4);    // per-split Z row sums
  short* ff1b = (short*)alloc((size_t)S * F * 2);
  short* memb = (short*)alloc(SH * 2);
  short* ckvA = (short*)alloc((size_t)2 * L * SH * 2);  // interleaved cross K (even slots; odd unused)
  short* cvT  = (short*)alloc((size_t)L * SH * 2);      // cross V''^T per layer (direct from GEMM)
  float* biasE = (float*)alloc((size_t)L * 4 * H * 4);  // eab with j=2 zeroed
  float* biasD = (float*)alloc((size_t)L * 8 * H * 4);  // dab with j=2,6 zeroed; j=3 <- dab j=4
  float* bvoAll = (float*)alloc((size_t)18 * H * 4);    // folded V/out biases
  float* bvoPart = (float*)alloc((size_t)18 * 16 * H * 4); // bvo partials
  float* ftsf = (float*)alloc((size_t)S * TTd * 4);
  float* McB  = (float*)alloc((size_t)VC * 1024 * 4);
  float* McrsB= (float*)alloc((size_t)(VC / 4) * 1024 * 4);
  float* bfvF = (float*)alloc((size_t)(VC + 1) * 32 * 4);
  float* termB= (float*)alloc(64);
  unsigned char* bpgB = (unsigned char*)alloc((size_t)2048 * 32);

  short* vtb = ff1b;                  // V''^T scratch aliases ff1b (disjoint lifetimes)
  short* sparts = (short*)scf;        // bf16 split partials (8 x SH shorts = 16MB)
  short* wvPe  = (short*)scf;         // plain bf16 Wv copies alias scf (prologue only)
  short* wvPds = wvPe + L * HH2;
  short* wvPdc = wvPds + L * HH2;

  const int ZBIG = 1 << 20;

  // ---- weight conversion ----
  tconv_k<<<dim3(16, 16, L * 4), 256, 0, stream>>>(eaw, wEAT, H, H);
  tconv_k<<<dim3(16, 16, L * 8), 256, 0, stream>>>(daw, wDAT, H, H);
  tconv_k<<<dim3(64, 16, L), 256, 0, stream>>>(ew1, wE1T, H, F);
  tconv_k<<<dim3(16, 64, L), 256, 0, stream>>>(ew2, wE2T, F, H);
  tconv_k<<<dim3(64, 16, L), 256, 0, stream>>>(dw1, wD1T, H, F);
  tconv_k<<<dim3(16, 64, L), 256, 0, stream>>>(dw2, wD2T, F, H);
  // plain bf16 copies of Wv (enc j2, dec-self j2, dec-cross j6)
  pconv_k<<<dim3(256, 1, L), 256, 0, stream>>>(eaw + 2 * HH2, wvPe, 4 * HH2, HH2);
  pconv_k<<<dim3(256, 1, L), 256, 0, stream>>>(daw + 2 * HH2, wvPds, 8 * HH2, HH2);
  pconv_k<<<dim3(256, 1, L), 256, 0, stream>>>(daw + 6 * HH2, wvPdc, 8 * HH2, HH2);
  // compose Wvo^T = Wout^T @ Wv^T into the V-weight slots (in place)
  auto G_cmp = gemm3<128, 64, false, false, false, false, true, false>;
  G_cmp<<<dim3(8, 4, L), 256, 0, stream>>>(
      wEAT + 3 * HH2, wvPe, nullptr, nullptr, nullptr, wEAT + 2 * HH2,
      H, H, H, H, H, 0, 1.f, 1, 4 * HH2, HH2, 0, 0, 0, 4 * HH2,
      nullptr, 0, 1, -1);
  G_cmp<<<dim3(8, 4, L), 256, 0, stream>>>(
      wDAT + 3 * HH2, wvPds, nullptr, nullptr, nullptr, wDAT + 2 * HH2,
      H, H, H, H, H, 0, 1.f, 1, 8 * HH2, HH2, 0, 0, 0, 8 * HH2,
      nullptr, 0, 1, -1);
  G_cmp<<<dim3(8, 4, L), 256, 0, stream>>>(
      wDAT + 7 * HH2, wvPdc, nullptr, nullptr, nullptr, wDAT + 6 * HH2,
      H, H, H, H, H, 0, 1.f, 1, 8 * HH2, HH2, 0, 0, 0, 8 * HH2,
      nullptr, 0, 1, -1);
  // dec-self Wout^T slot (j=3) is free after compose: move crossQ W^T (j=4) into it
  scpy_k<<<dim3(256, 1, L), 256, 0, stream>>>(wDAT + 4 * HH2, wDAT + 3 * HH2, 8 * HH2, 8 * HH2);
  // bias tables with V slots zeroed; folded biases
  zbias_k<<<dim3((L * 4 * H + 255) / 256), 256, 0, stream>>>(eab, biasE, 4, 1u << 2, L * 4 * H);
  zbias_k<<<dim3((L * 8 * H + 255) / 256), 256, 0, stream>>>(dab, biasD, 8, (1u << 2) | (1u << 6), L * 8 * H);
  bcpy_k<<<dim3(L * H / 256), 256, 0, stream>>>(dab, biasD);
  bvoP_k<<<dim3(18, 16), 256, 0, stream>>>(eaw, eab, daw, dab, bvoPart);
  bvoR_k<<<dim3(18), 256, 0, stream>>>(bvoPart, eab, dab, bvoAll);

  gather_k<<<dim3((unsigned)(SH / 256)), 256, 0, stream>>>(sent, embd, h_b, y_b);

  // gemm variants
  auto G_qkv = gemm3<128, 64, true, false, false, false, true, true>;   // batched proj; z==2 -> V''^T direct
  auto G_spl = gemm3<128, 64, false, false, false, false, true, false>; // split-K partials -> bf16
  auto G_ff1 = gemm3<128, 64, true, true, false, false, true, false>;   // bias+relu -> bf16

  dim3 gQKVe(8, 16, 3), gQKVd(8, 16, 4), gSPL(8, 16, 4), gFF1(32, 16, 1), gFSA(8, 32, 1);

  // ---------------- encoder ----------------
  for (int i = 0; i < L; ++i) {
    G_qkv<<<gQKVe, 256, 0, stream>>>(
        h_b, wEAT + (size_t)i * 4 * HH2, biasE + (size_t)i * 4 * H, nullptr, nullptr, qkvb,
        S, H, H, H, H, 0, 1.f, ZBIG, 0, 0, HH2, 0, H, SH,
        vtb, 0, 3, 2);
    fsa_k<<<gFSA, 512, FSA_SMEM, stream>>>(qkvb, qkvb + SH, vtb, sparts, Zp);
    r4zrln_k<<<dim3(S), 256, 0, stream>>>(sparts, Zp, bvoAll + (size_t)i * H, h_b,
        elnw + (size_t)(i * 2) * H, elnb + (size_t)(i * 2) * H, h_b);
    G_ff1<<<gFF1, 256, 0, stream>>>(
        h_b, wE1T + (size_t)i * HF, eb1 + (size_t)i * F, nullptr, nullptr, ff1b,
        S, F, H, H, H, 0, 1.f, 1, 0, 0, 0, 0, 0, 0,
        nullptr, 0, 1, -1);
    G_spl<<<gSPL, 256, 0, stream>>>(
        ff1b, wE2T + (size_t)i * HF, nullptr, nullptr, nullptr, sparts,
        S, H, F / 4, F, F, F / 4, 1.f, 1, 0, 0, 0, 0, 0, SH,
        nullptr, 0, 1, -1);
    r4rln_k<<<dim3(S), 256, 0, stream>>>(sparts, eb2 + (size_t)i * H, h_b,
        elnw + (size_t)(i * 2 + 1) * H, elnb + (size_t)(i * 2 + 1) * H, h_b);
  }
  lnb_k<<<dim3(S), 256, 0, stream>>>(h_b, enw, enb, nullptr, memb);

  // cross K (j=5, even z) and composed V''^T (j=6, odd z -> direct transposed to cvT)
  G_qkv<<<dim3(8, 16, 2 * L), 256, 0, stream>>>(
      memb, wDAT + 5 * HH2, biasD + 5 * H, nullptr, nullptr, ckvA,
      S, H, H, H, H, 0, 1.f, 2, 0, 8 * HH2, HH2, 8 * H, H, SH,
      cvT, SH, 2, 1);

  // ---------------- decoder ----------------
  for (int i = 0; i < L; ++i) {
    // z=4 batch: Q, K, V''(->vtb transposed), crossQ (slot 3 holds crossQ weights/bias)
    G_qkv<<<gQKVd, 256, 0, stream>>>(
        y_b, wDAT + (size_t)i * 8 * HH2, biasD + (size_t)i * 8 * H, nullptr, nullptr, qkvb,
        S, H, H, H, H, 0, 1.f, ZBIG, 0, 0, HH2, 0, H, SH,
        vtb, 0, 4, 2);
    fsa_k<<<gFSA, 512, FSA_SMEM, stream>>>(qkvb, qkvb + SH, vtb, sparts, Zp);
    r4zrln_k<<<dim3(S), 256, 0, stream>>>(sparts, Zp, bvoAll + (size_t)(6 + i) * H, y_b,
        dlnw + (size_t)(i * 3) * H, dlnb + (size_t)(i * 3) * H, y_b);
    // cross-attn (Q precomputed in batch at slot 3)
    fsa_k<<<gFSA, 512, FSA_SMEM, stream>>>(qkvb + 3 * SH, ckvA + (size_t)(2 * i) * SH,
                                           cvT + (size_t)i * SH, sparts, Zp);
    r4zrln_k<<<dim3(S), 256, 0, stream>>>(sparts, Zp, bvoAll + (size_t)(12 + i) * H, y_b,
        dlnw + (size_t)(i * 3 + 1) * H, dlnb + (size_t)(i * 3 + 1) * H, y_b);
    // FFN
    G_ff1<<<gFF1, 256, 0, stream>>>(
        y_b, wD1T + (size_t)i * HF, db1 + (size_t)i * F, nullptr, nullptr, ff1b,
        S, F, H, H, H, 0, 1.f, 1, 0, 0, 0, 0, 0, 0,
        nullptr, 0, 1, -1);
    G_spl<<<gSPL, 256, 0, stream>>>(
        ff1b, wD2T + (size_t)i * HF, nullptr, nullptr, nullptr, sparts,
        S, H, F / 4, F, F, F / 4, 1.f, 1, 0, 0, 0, 0, 0, SH,
        nullptr, 0, 1, -1);
    r4rln_k<<<dim3(S), 256, 0, stream>>>(sparts, db2 + (size_t)i * H, y_b,
        dlnw + (size_t)(i * 3 + 2) * H, dlnb + (size_t)(i * 3 + 2) * H, y_b);
  }
  // final norm + feats + hierarchical parallel viterbi
  lnb_k<<<dim3(S), 256, 0, stream>>>(y_b, dnw, dnb, tmpf, memb);
  feats_k<<<dim3(S / 8), 256, 0, stream>>>(tmpf, h2tw, h2tb, ftsf);
  float* outF = (float*)d_out;
  vit_p1<<<dim3(VC), 256, 0, stream>>>(ftsf, trns, McB);
  vit_p1b<<<dim3(VC / 4), 256, 0, stream>>>(McB, McrsB);
  vit_p2<<<dim3(1), 64, 0, stream>>>(McrsB, trns, bfvF, termB, outF);
  vit_p2b<<<dim3(VC / 4), 64, 0, stream>>>(McB, bfvF);
  vit_p3<<<dim3(VC), 64, 0, stream>>>(ftsf, trns, bfvF, bpgB);
  vit_p4<<<dim3(1), VC, 0, stream>>>(bpgB, termB, outF);
}

// Round 27
// 1213.796 us; speedup vs baseline: 1.0855x; 1.0240x over previous
//
#include <hip/hip_runtime.h>
#include <cstdint>

#define SS 2048
#define HHd 512
#define FFd 2048
#define TTd 32
#define LLd 6
#define VW 16
#define VC 128

typedef float f32x4 __attribute__((ext_vector_type(4)));
typedef __bf16 bf16x8 __attribute__((ext_vector_type(8)));
typedef short short8v __attribute__((ext_vector_type(8)));
typedef short short4v __attribute__((ext_vector_type(4)));

__device__ __forceinline__ short f2b(float f) {
  unsigned u = __builtin_bit_cast(unsigned, f);
  u += 0x7fffu + ((u >> 16) & 1u);
  return (short)(u >> 16);
}
__device__ __forceinline__ float b2f(short s) {
  unsigned u = ((unsigned)(unsigned short)s) << 16;
  return __builtin_bit_cast(float, u);
}

typedef const __attribute__((address_space(1))) void gv_t;
typedef __attribute__((address_space(3))) void lv_t;
__device__ __forceinline__ void gload16(const void* g, void* l) {
  __builtin_amdgcn_global_load_lds((gv_t*)g, (lv_t*)l, 16, 0, 0);
}

// ------------------------------ GEMM (all-TB, BK=64, swizzled LDS, double-buffered 2-phase) ------------------------------
// C[M,N] = A[M,K] @ B^T. z-batching: A += z*as1; B += (z/zdiv)*bs1 + (z%zdiv)*bs2; C += z*cStr.
// TRBE: when (z % tmod)==tval, write C^T (bf16) to CbT + (z/zdiv)*ctStr instead (LDS-staged coalesced).
// Pipeline: issue L(k+1) into alternate buffer -> MFMA on buf[k] (loads fly under compute) -> barrier.
template<int BMt, int BNt, bool BIAS, bool RELU, bool RESID, bool OUTF, bool OUTB, bool TRBE>
__global__ __launch_bounds__(256) void gemm3(
    const short* __restrict__ A, const short* __restrict__ Bb,
    const float* __restrict__ biasb, const float* __restrict__ resid,
    float* __restrict__ Cfb, short* __restrict__ Cbb,
    int M, int N, int K, int lda, int ldb, int kzS, float scale,
    int zdiv, long as1, long bs1, long bs2, int bb1, int bb2, long cStr,
    short* __restrict__ CbT, long ctStr, int tmod, int tval)
{
  constexpr int MR = BMt / 32, NR = BNt / 32;
  constexpr int WMt = BMt / 2, WNt = BNt / 2;
  constexpr int ACALLS = BMt / 8;
  constexpr int TOT = (BMt + BNt) / 8;
  constexpr int CPW = TOT / 4;
  constexpr int HALF = BMt * 64 + BNt * 64;

  const int z = blockIdx.z;
  const short* Ap = A + (long)z * as1;
  const short* Bp = Bb + (long)(z / zdiv) * bs1 + (long)(z % zdiv) * bs2;
  const float* bias = BIAS ? (biasb + (z / zdiv) * bb1 + (z % zdiv) * bb2) : nullptr;
  const int kz = z * kzS;

  const int m0 = blockIdx.y * BMt;
  const int n0 = blockIdx.x * BNt;

  __shared__ __align__(16) short LDSbuf[2 * HALF];

  const int tid = threadIdx.x;
  const int lane = tid & 63;
  const int w = tid >> 6;

  const short* srcs[CPW];
  int loff[CPW];
  {
    const int rl8 = lane >> 3;
    const int c16 = (lane & 7) ^ rl8;
#pragma unroll
    for (int c = 0; c < CPW; ++c) {
      int q = w * CPW + c;
      if (q < ACALLS) {
        int row = q * 8 + rl8;
        srcs[c] = Ap + (long)(m0 + row) * lda + kz + c16 * 8;
        loff[c] = q * 512;
      } else {
        int row = (q - ACALLS) * 8 + rl8;
        srcs[c] = Bp + (long)(n0 + row) * ldb + kz + c16 * 8;
        loff[c] = BMt * 64 + (q - ACALLS) * 512;
      }
    }
  }

  const int lrow = lane & 15;
  const int slotb = lane >> 4;
  const int wm = (w >> 1) * WMt, wn = (w & 1) * WNt;

  f32x4 acc[MR][NR] = {};

  // prologue: stage tile 0 into buffer 0
#pragma unroll
  for (int c = 0; c < CPW; ++c) gload16(srcs[c], LDSbuf + loff[c]);
#pragma unroll
  for (int c = 0; c < CPW; ++c) srcs[c] += 64;
  __syncthreads();

  const int NIT = K >> 6;
  for (int it = 0; it < NIT; ++it) {
    const int cur = it & 1;
    if (it + 1 < NIT) {
      const int nxt = (cur ^ 1) * HALF;
#pragma unroll
      for (int c = 0; c < CPW; ++c) gload16(srcs[c], LDSbuf + nxt + loff[c]);
#pragma unroll
      for (int c = 0; c < CPW; ++c) srcs[c] += 64;
    }
    const short* As = LDSbuf + cur * HALF;
    const short* Bs = As + BMt * 64;
#pragma unroll
    for (int s = 0; s < 2; ++s) {
      bf16x8 af[MR], bfv[NR];
#pragma unroll
      for (int f = 0; f < MR; ++f) {
        int row = wm + f * 16 + lrow;
        int phys = (slotb + s * 4) ^ (row & 7);
        af[f] = *(const bf16x8*)&As[row * 64 + phys * 8];
      }
#pragma unroll
      for (int f = 0; f < NR; ++f) {
        int row = wn + f * 16 + lrow;
        int phys = (slotb + s * 4) ^ (row & 7);
        bfv[f] = *(const bf16x8*)&Bs[row * 64 + phys * 8];
      }
#pragma unroll
      for (int i = 0; i < MR; ++i)
#pragma unroll
        for (int j = 0; j < NR; ++j)
          acc[i][j] = __builtin_amdgcn_mfma_f32_16x16x32_bf16(af[i], bfv[j], acc[i][j], 0, 0, 0);
    }
    __syncthreads();   // drains L(it+1); frees buf[cur]
  }

  const int crow = (lane >> 4) * 4;
  const int ccol = lane & 15;
  const bool dotr = TRBE && ((z % tmod) == tval);

  if (OUTB) {
    if (dotr) {
      short* Cb = CbT + (long)(z / zdiv) * ctStr;
      constexpr int LDSW = BMt + 8;
      short* Os = LDSbuf;
#pragma unroll
      for (int i = 0; i < MR; ++i) {
#pragma unroll
        for (int j = 0; j < NR; ++j) {
          int lc = wn + j * 16 + ccol;
          float bv = BIAS ? bias[n0 + lc] : 0.f;
#pragma unroll
          for (int r = 0; r < 4; ++r) {
            int lr = wm + i * 16 + crow + r;
            Os[lc * LDSW + lr] = f2b(acc[i][j][r] * scale + bv);
          }
        }
      }
      __syncthreads();
      constexpr int CPR = BMt / 8;
      constexpr int CPT = (BMt * BNt / 8) / 256;
#pragma unroll
      for (int c = 0; c < CPT; ++c) {
        int idx = tid + c * 256;
        int col = idx / CPR;
        int rowc = (idx % CPR) * 8;
        int4 vv = *(const int4*)&Os[col * LDSW + rowc];
        *(int4*)&Cb[(long)(n0 + col) * M + m0 + rowc] = vv;
      }
    } else {
      short* Cb = Cbb + (long)z * cStr;
      constexpr int LDSW = BNt + 8;
      short* Os = LDSbuf;
#pragma unroll
      for (int i = 0; i < MR; ++i) {
#pragma unroll
        for (int j = 0; j < NR; ++j) {
          int lc = wn + j * 16 + ccol;
          float bv = BIAS ? bias[n0 + lc] : 0.f;
#pragma unroll
          for (int r = 0; r < 4; ++r) {
            int lr = wm + i * 16 + crow + r;
            float v = acc[i][j][r] * scale + bv;
            if (RELU) v = v > 0.f ? v : 0.f;
            Os[lr * LDSW + lc] = f2b(v);
          }
        }
      }
      __syncthreads();
      constexpr int CPR = BNt / 8;
      constexpr int CPT = (BMt * BNt / 8) / 256;
#pragma unroll
      for (int c = 0; c < CPT; ++c) {
        int idx = tid + c * 256;
        int row = idx / CPR;
        int col8 = (idx % CPR) * 8;
        int4 vv = *(const int4*)&Os[row * LDSW + col8];
        *(int4*)&Cb[(long)(m0 + row) * N + n0 + col8] = vv;
      }
    }
  } else {
    float* Cf = Cfb + (long)z * cStr;
#pragma unroll
    for (int i = 0; i < MR; ++i) {
#pragma unroll
      for (int j = 0; j < NR; ++j) {
        int gc = n0 + wn + j * 16 + ccol;
        float bv = BIAS ? bias[gc] : 0.f;
#pragma unroll
        for (int r = 0; r < 4; ++r) {
          int gr = m0 + wm + i * 16 + crow + r;
          long off = (long)gr * N + gc;
          float v = acc[i][j][r] * scale + bv;
          if (RESID) v += resid[off];
          if (RELU) v = v > 0.f ? v : 0.f;
          Cf[off] = v;
        }
      }
    }
  }
}

// ============================== Fused attention (q-tile 64, key-split 8, 8 waves, 2-phase) ==============================
// blockIdx.z selects pointer set 0/1 (dual-issue: decoder self + cross attention in one launch).
#define FSA_SMEM (64 * 512 * 2 + 512 * 64 * 2 + 64 * 64 * 2 + 128 * 4)
__global__ __launch_bounds__(512) void fsa_k(
    const short* __restrict__ Q0, const short* __restrict__ K0,
    const short* __restrict__ V0, short* __restrict__ O0, float* __restrict__ Zp0,
    const short* __restrict__ Q1, const short* __restrict__ K1,
    const short* __restrict__ V1, short* __restrict__ O1, float* __restrict__ Zp1) {
  extern __shared__ __align__(16) char smem[];
  short* Ks  = (short*)smem;           // [64][512]  (Q stage / K chunk / O stage)
  short* Vts = Ks + 64 * 512;          // [512][64]
  short* Ps  = Vts + 512 * 64;         // [64][64]
  float* Zs  = (float*)(Ps + 64 * 64); // [2][64]
  const float RSQ = 0.04419417382415922f;

  const int sel = blockIdx.z;
  const short* Q   = sel ? Q1 : Q0;
  const short* Kmat= sel ? K1 : K0;
  const short* VT  = sel ? V1 : V0;
  short* Op        = sel ? O1 : O0;
  float* Zp        = sel ? Zp1 : Zp0;

  const int z = blockIdx.x;            // key split (0..7)
  const int q0 = blockIdx.y * 64;
  const int key0 = z * 256;
  const int tid = threadIdx.x, lane = tid & 63, w = tid >> 6;
  const int qg = w >> 1;               // 0..3 q-group (16 rows each)
  const int kh = w & 1;
  const int wn = kh * 32, wn2 = kh * 256;
  const int lrow = lane & 15, lgrp = lane >> 4;

  // stage Q (64 rows)
  for (int c = 0; c < 8; ++c) {
    int row = w * 8 + c;
    const short* src = Q + (long)(q0 + row) * HHd + (lane ^ (row & 7)) * 8;
    gload16(src, &Ks[row * 512]);
  }
  __syncthreads();
  bf16x8 qf[16];
#pragma unroll
  for (int st = 0; st < 16; ++st) {
    int row = qg * 16 + lrow;
    int phys = (st * 4 + lgrp) ^ (row & 7);
    qf[st] = *(const bf16x8*)&Ks[row * 512 + phys * 8];
  }
  __syncthreads();

  // prologue: stage K(0)
  for (int c = 0; c < 8; ++c) {
    int row = w * 8 + c;
    const short* src = Kmat + (long)(key0 + row) * HHd + (lane ^ (row & 7)) * 8;
    gload16(src, &Ks[row * 512]);
  }
  __syncthreads();

  f32x4 accO[16] = {};
  float zacc[4] = {};

  for (int kc = 0; kc < 4; ++kc) {
    // issue V(kc) — flies under QK compute
    for (int c = 0; c < 8; ++c) {
      int rb = (w * 8 + c) * 8;
      int vrow = rb + (lane >> 3);
      const short* src = VT + (long)vrow * SS + key0 + kc * 64 + ((lane & 7) ^ (vrow & 7)) * 8;
      gload16(src, &Vts[rb * 64]);
    }
    f32x4 accS0 = {}, accS1 = {};
#pragma unroll
    for (int st = 0; st < 16; ++st) {
      int row0 = wn + lrow;
      int phys0 = (st * 4 + lgrp) ^ (row0 & 7);
      bf16x8 b0 = *(const bf16x8*)&Ks[row0 * 512 + phys0 * 8];
      int row1 = wn + 16 + lrow;
      int phys1 = (st * 4 + lgrp) ^ (row1 & 7);
      bf16x8 b1 = *(const bf16x8*)&Ks[row1 * 512 + phys1 * 8];
      accS0 = __builtin_amdgcn_mfma_f32_16x16x32_bf16(qf[st], b0, accS0, 0, 0, 0);
      accS1 = __builtin_amdgcn_mfma_f32_16x16x32_bf16(qf[st], b1, accS1, 0, 0, 0);
    }
#pragma unroll
    for (int f = 0; f < 2; ++f) {
#pragma unroll
      for (int r = 0; r < 4; ++r) {
        int row = qg * 16 + lgrp * 4 + r;
        int col = wn + f * 16 + lrow;
        float sv = f ? accS1[r] : accS0[r];
        float e = __expf(sv * RSQ);
        zacc[r] += e;
        int slot = col >> 3;
        Ps[row * 64 + ((slot ^ (row & 7)) * 8) + (col & 7)] = f2b(e);
      }
    }
    __syncthreads();   // drains V(kc); P visible; Ks free (QK done)
    // issue K(kc+1) — flies under PV compute
    if (kc < 3) {
      for (int c = 0; c < 8; ++c) {
        int row = w * 8 + c;
        const short* src = Kmat + (long)(key0 + (kc + 1) * 64 + row) * HHd + (lane ^ (row & 7)) * 8;
        gload16(src, &Ks[row * 512]);
      }
    }
#pragma unroll
    for (int kk = 0; kk < 2; ++kk) {
      int prow = qg * 16 + lrow;
      int pphys = (kk * 4 + lgrp) ^ (prow & 7);
      bf16x8 pa = *(const bf16x8*)&Ps[prow * 64 + pphys * 8];
#pragma unroll
      for (int n = 0; n < 16; ++n) {
        int vrow = wn2 + n * 16 + lrow;
        int vphys = (kk * 4 + lgrp) ^ (vrow & 7);
        bf16x8 vb = *(const bf16x8*)&Vts[vrow * 64 + vphys * 8];
        accO[n] = __builtin_amdgcn_mfma_f32_16x16x32_bf16(pa, vb, accO[n], 0, 0, 0);
      }
    }
    __syncthreads();   // drains K(kc+1); Vts/Ps free for next iteration
  }

  // epilogue: stage O as bf16 into Ks (linear [64][512]) + Z shuffles
#pragma unroll
  for (int n = 0; n < 16; ++n) {
#pragma unroll
    for (int r = 0; r < 4; ++r) {
      int row = qg * 16 + lgrp * 4 + r;
      int col = wn2 + n * 16 + lrow;
      Ks[row * 512 + col] = f2b(accO[n][r]);
    }
  }
#pragma unroll
  for (int r = 0; r < 4; ++r) {
    float v = zacc[r];
    v += __shfl_xor(v, 1); v += __shfl_xor(v, 2);
    v += __shfl_xor(v, 4); v += __shfl_xor(v, 8);
    if (lrow == 0) Zs[kh * 64 + qg * 16 + lgrp * 4 + r] = v;
  }
  __syncthreads();
  short* OpZ = Op + (long)z * (long)SS * HHd + (long)q0 * HHd;
#pragma unroll
  for (int c = 0; c < 8; ++c) {
    int idx = tid + c * 512;
    *(int4*)&OpZ[idx * 8] = *(const int4*)&Ks[idx * 8];
  }
  if (tid < 64) Zp[(long)z * SS + q0 + tid] = Zs[tid] + Zs[64 + tid];
}

// ---------------- fused attention tail: (sum8 bf16-O)/Z + bvo + bf16 resid + LayerNorm -> bf16 ----------------
__global__ __launch_bounds__(256) void r4zrln_k(const short* __restrict__ pb,
                                                const float* __restrict__ Zp,
                                                const float* __restrict__ bvo,
                                                const short* __restrict__ resid,
                                                const float* __restrict__ w, const float* __restrict__ b,
                                                short* __restrict__ Yb) {
  const long SH = (long)SS * HHd;
  const int row = blockIdx.x, tid = threadIdx.x;
  long base = (long)row * HHd;
  float zt = 0.f;
#pragma unroll
  for (int sk = 0; sk < 8; ++sk) zt += Zp[(long)sk * SS + row];
  float zi = 1.0f / zt;
  float a0 = 0.f, a1 = 0.f;
#pragma unroll
  for (int sk = 0; sk < 8; ++sk) {
    a0 += b2f(pb[sk * SH + base + tid]);
    a1 += b2f(pb[sk * SH + base + tid + 256]);
  }
  float x0 = a0 * zi + bvo[tid] + b2f(resid[base + tid]);
  float x1 = a1 * zi + bvo[tid + 256] + b2f(resid[base + tid + 256]);
  float s = x0 + x1;
#pragma unroll
  for (int o = 32; o; o >>= 1) s += __shfl_xor(s, o);
  __shared__ float r1[4], r2[4];
  if ((tid & 63) == 0) r1[tid >> 6] = s;
  __syncthreads();
  float mean = (r1[0] + r1[1] + r1[2] + r1[3]) * (1.f / HHd);
  float d0 = x0 - mean, d1 = x1 - mean;
  float q = d0 * d0 + d1 * d1;
#pragma unroll
  for (int o = 32; o; o >>= 1) q += __shfl_xor(q, o);
  if ((tid & 63) == 0) r2[tid >> 6] = q;
  __syncthreads();
  float var = (r2[0] + r2[1] + r2[2] + r2[3]) * (1.f / HHd);
  float rs = rsqrtf(var + 1e-5f);
  float o0 = d0 * rs * w[tid] + b[tid];
  float o1 = d1 * rs * w[tid + 256] + b[tid + 256];
  Yb[base + tid] = f2b(o0); Yb[base + tid + 256] = f2b(o1);
}

// ---------------- split-K=4 bf16 reduce + bias + bf16 resid + LayerNorm -> bf16 (FFN2) ----------------
__global__ __launch_bounds__(256) void r4rln_k(const short* __restrict__ pb,
                                               const float* __restrict__ bias,
                                               const short* __restrict__ resid,
                                               const float* __restrict__ w, const float* __restrict__ b,
                                               short* __restrict__ Yb) {
  const long SH = (long)SS * HHd;
  const int row = blockIdx.x, tid = threadIdx.x;
  long base = (long)row * HHd;
  float x0 = bias[tid] + b2f(resid[base + tid]);
  float x1 = bias[tid + 256] + b2f(resid[base + tid + 256]);
#pragma unroll
  for (int sk = 0; sk < 4; ++sk) {
    x0 += b2f(pb[sk * SH + base + tid]);
    x1 += b2f(pb[sk * SH + base + tid + 256]);
  }
  float s = x0 + x1;
#pragma unroll
  for (int o = 32; o; o >>= 1) s += __shfl_xor(s, o);
  __shared__ float r1[4], r2[4];
  if ((tid & 63) == 0) r1[tid >> 6] = s;
  __syncthreads();
  float mean = (r1[0] + r1[1] + r1[2] + r1[3]) * (1.f / HHd);
  float d0 = x0 - mean, d1 = x1 - mean;
  float q = d0 * d0 + d1 * d1;
#pragma unroll
  for (int o = 32; o; o >>= 1) q += __shfl_xor(q, o);
  if ((tid & 63) == 0) r2[tid >> 6] = q;
  __syncthreads();
  float var = (r2[0] + r2[1] + r2[2] + r2[3]) * (1.f / HHd);
  float rs = rsqrtf(var + 1e-5f);
  float o0 = d0 * rs * w[tid] + b[tid];
  float o1 = d1 * rs * w[tid + 256] + b[tid + 256];
  Yb[base + tid] = f2b(o0); Yb[base + tid + 256] = f2b(o1);
}

// ---------------- LayerNorm over bf16 rows; optional f32 out + bf16 out ----------------
__global__ __launch_bounds__(256) void lnb_k(const short* __restrict__ Xb, const float* __restrict__ w,
                                             const float* __restrict__ b, float* __restrict__ Yf,
                                             short* __restrict__ Yb) {
  const int row = blockIdx.x;
  const int tid = threadIdx.x;
  long base = (long)row * HHd;
  float x0 = b2f(Xb[base + tid]), x1 = b2f(Xb[base + tid + 256]);
  float s = x0 + x1;
#pragma unroll
  for (int o = 32; o; o >>= 1) s += __shfl_xor(s, o);
  __shared__ float r1[4], r2[4];
  if ((tid & 63) == 0) r1[tid >> 6] = s;
  __syncthreads();
  float mean = (r1[0] + r1[1] + r1[2] + r1[3]) * (1.f / HHd);
  float d0 = x0 - mean, d1 = x1 - mean;
  float q = d0 * d0 + d1 * d1;
#pragma unroll
  for (int o = 32; o; o >>= 1) q += __shfl_xor(q, o);
  if ((tid & 63) == 0) r2[tid >> 6] = q;
  __syncthreads();
  float var = (r2[0] + r2[1] + r2[2] + r2[3]) * (1.f / HHd);
  float rs = rsqrtf(var + 1e-5f);
  float o0 = d0 * rs * w[tid] + b[tid];
  float o1 = d1 * rs * w[tid + 256] + b[tid + 256];
  if (Yf) { Yf[base + tid] = o0; Yf[base + tid + 256] = o1; }
  Yb[base + tid] = f2b(o0); Yb[base + tid + 256] = f2b(o1);
}

// ---------------- f32 [K,N] -> bf16 [N,K] transpose-convert (batched z) ----------------
__global__ __launch_bounds__(256) void tconv_k(const float* __restrict__ in, short* __restrict__ out,
                                               int K, int N) {
  __shared__ float t[32][33];
  long zo = (long)blockIdx.z * K * N;
  int n0 = blockIdx.x * 32, k0 = blockIdx.y * 32;
  int tx = threadIdx.x & 31, ty = threadIdx.x >> 5;
#pragma unroll
  for (int i = 0; i < 4; ++i)
    t[ty + i * 8][tx] = in[zo + (long)(k0 + ty + i * 8) * N + n0 + tx];
  __syncthreads();
#pragma unroll
  for (int i = 0; i < 4; ++i)
    out[zo + (long)(n0 + ty + i * 8) * K + k0 + tx] = f2b(t[tx][ty + i * 8]);
}

// ---------------- plain strided f32 -> bf16 convert (batched z) ----------------
__global__ __launch_bounds__(256) void pconv_k(const float* __restrict__ in, short* __restrict__ out,
                                               long inStride, long outStride) {
  long i = ((long)blockIdx.x * 256 + threadIdx.x) * 4;
  const float* ip = in + (long)blockIdx.z * inStride + i;
  short* op = out + (long)blockIdx.z * outStride + i;
  float4 v = *(const float4*)ip;
  short4v o;
  o[0] = f2b(v.x); o[1] = f2b(v.y); o[2] = f2b(v.z); o[3] = f2b(v.w);
  *(short4v*)op = o;
}

// ---------------- bf16 strided copy (batched z) ----------------
__global__ __launch_bounds__(256) void scpy_k(const short* __restrict__ src, short* __restrict__ dst,
                                              long srcStride, long dstStride) {
  long i = ((long)blockIdx.x * 256 + threadIdx.x) * 4;
  *(short4v*)(dst + (long)blockIdx.z * dstStride + i) =
      *(const short4v*)(src + (long)blockIdx.z * srcStride + i);
}

// ---------------- bias slot copy: biasD[l*8+3] <- dab[l*8+4] ----------------
__global__ __launch_bounds__(256) void bcpy_k(const float* __restrict__ src, float* __restrict__ dst) {
  int i = blockIdx.x * 256 + threadIdx.x;  // over L*H
  int l = i >> 9, c = i & 511;
  dst[(l * 8 + 3) * HHd + c] = src[(l * 8 + 4) * HHd + c];
}

// ---------------- bias table copy with zeroed j-slots ----------------
__global__ __launch_bounds__(256) void zbias_k(const float* __restrict__ src, float* __restrict__ dst,
                                               int nj, unsigned jmask, int total) {
  int i = blockIdx.x * 256 + threadIdx.x;
  if (i >= total) return;
  int j = (i >> 9) % nj;
  dst[i] = ((jmask >> j) & 1u) ? 0.f : src[i];
}

// ---------------- bvo partials: row-major streaming (18 combos x 16 m-groups) ----------------
__global__ __launch_bounds__(256) void bvoP_k(const float* __restrict__ eaw, const float* __restrict__ eab,
                                              const float* __restrict__ daw, const float* __restrict__ dab,
                                              float* __restrict__ part) {
  const long HH2 = (long)HHd * HHd;
  const int b = blockIdx.x, mg = blockIdx.y, tid = threadIdx.x;
  const float* Wout; const float* bv;
  if (b < 6) {
    int i = b;
    Wout = eaw + (i * 4 + 3) * HH2; bv = eab + (i * 4 + 2) * HHd;
  } else if (b < 12) {
    int i = b - 6;
    Wout = daw + (i * 8 + 3) * HH2; bv = dab + (i * 8 + 2) * HHd;
  } else {
    int i = b - 12;
    Wout = daw + (i * 8 + 7) * HH2; bv = dab + (i * 8 + 6) * HHd;
  }
  float a0 = 0.f, a1 = 0.f;
#pragma unroll 4
  for (int m = mg * 32; m < mg * 32 + 32; ++m) {
    float bvm = bv[m];
    a0 = fmaf(bvm, Wout[(long)m * HHd + tid], a0);
    a1 = fmaf(bvm, Wout[(long)m * HHd + tid + 256], a1);
  }
  long o = ((long)b * 16 + mg) * HHd;
  part[o + tid] = a0;
  part[o + tid + 256] = a1;
}

// ---------------- bvo reduce: sum 16 partials + bout ----------------
__global__ __launch_bounds__(256) void bvoR_k(const float* __restrict__ part,
                                              const float* __restrict__ eab, const float* __restrict__ dab,
                                              float* __restrict__ bvoAll) {
  const int b = blockIdx.x, tid = threadIdx.x;
  const float* bout;
  if (b < 6) bout = eab + (b * 4 + 3) * HHd;
  else if (b < 12) bout = dab + ((b - 6) * 8 + 3) * HHd;
  else bout = dab + ((b - 12) * 8 + 7) * HHd;
  float s0 = bout[tid], s1 = bout[tid + 256];
#pragma unroll
  for (int mg = 0; mg < 16; ++mg) {
    long o = ((long)b * 16 + mg) * HHd;
    s0 += part[o + tid];
    s1 += part[o + tid + 256];
  }
  bvoAll[(long)b * HHd + tid] = s0;
  bvoAll[(long)b * HHd + tid + 256] = s1;
}

// ------------------------------ embedding gather (bf16 only) ------------------------------
__global__ __launch_bounds__(256) void gather_k(const int* __restrict__ sent, const float* __restrict__ emb,
                                                short* __restrict__ hb, short* __restrict__ yb) {
  long i = (long)blockIdx.x * 256 + threadIdx.x;
  int s = (int)(i >> 9);
  int hcol = (int)(i & 511);
  float v = emb[(long)sent[s] * HHd + hcol];
  short bb = f2b(v);
  hb[i] = bb; yb[i] = bb;
}

// ------------------------------ feats: [SS,HHd] @ [HHd,TTd] + b (f32) ------------------------------
__global__ __launch_bounds__(256) void feats_k(const float* __restrict__ Y, const float* __restrict__ W,
                                               const float* __restrict__ b, float* __restrict__ feats) {
  __shared__ float ys[8 * HHd];
  const int row0 = blockIdx.x * 8;
  for (int i = threadIdx.x; i < 8 * HHd; i += 256) ys[i] = Y[(long)row0 * HHd + i];
  __syncthreads();
  const int n = threadIdx.x & 31, r = threadIdx.x >> 5;
  float acc = b[n];
  const float* yr = &ys[r * HHd];
  for (int k = 0; k < HHd; ++k) acc = fmaf(yr[k], W[k * TTd + n], acc);
  feats[(long)(row0 + r) * TTd + n] = acc;
}

// ============================== Parallel Viterbi (hierarchical max-plus scan) ==============================
__global__ __launch_bounds__(256) void vit_p1(const float* __restrict__ feats,
                                              const float* __restrict__ trans,
                                              float* __restrict__ Mc) {
  __shared__ float trS[1024];
  __shared__ float fS[VW * 32];
  __shared__ float Ga[32 * 33], Gb[32 * 33];
  const int c = blockIdx.x, tid = threadIdx.x;
  for (int i = tid; i < 1024; i += 256) trS[i] = trans[i];
  for (int i = tid; i < VW * 32; i += 256) fS[i] = feats[c * VW * 32 + i];
  __syncthreads();
  for (int i = tid; i < 1024; i += 256) {
    int n = i >> 5, q = i & 31;
    Ga[n * 33 + q] = trS[i] + fS[n];
  }
  __syncthreads();
  float* G = Ga;
  float* Gn = Gb;
  const int q = tid & 31, nb = (tid >> 5) * 4;
  for (int s = 1; s < VW; ++s) {
    float m0 = -3.0e38f, m1 = -3.0e38f, m2 = -3.0e38f, m3 = -3.0e38f;
    for (int pp = 0; pp < 32; ++pp) {
      float g = G[pp * 33 + q];
      m0 = fmaxf(m0, trS[(nb + 0) * 32 + pp] + g);
      m1 = fmaxf(m1, trS[(nb + 1) * 32 + pp] + g);
      m2 = fmaxf(m2, trS[(nb + 2) * 32 + pp] + g);
      m3 = fmaxf(m3, trS[(nb + 3) * 32 + pp] + g);
    }
    Gn[(nb + 0) * 33 + q] = m0 + fS[s * 32 + nb + 0];
    Gn[(nb + 1) * 33 + q] = m1 + fS[s * 32 + nb + 1];
    Gn[(nb + 2) * 33 + q] = m2 + fS[s * 32 + nb + 2];
    Gn[(nb + 3) * 33 + q] = m3 + fS[s * 32 + nb + 3];
    __syncthreads();
    float* t = G; G = Gn; Gn = t;
  }
  for (int i = tid; i < 1024; i += 256) Mc[c * 1024 + i] = G[(i >> 5) * 33 + (i & 31)];
}

__global__ __launch_bounds__(256) void vit_p1b(const float* __restrict__ Mf, float* __restrict__ Mcrs) {
  __shared__ float Ga[32 * 33], Gb[32 * 33], Ms[1024];
  const int c = blockIdx.x, tid = threadIdx.x;
  for (int i = tid; i < 1024; i += 256) Ga[(i >> 5) * 33 + (i & 31)] = Mf[(4 * c) * 1024 + i];
  float* G = Ga;
  float* Gn = Gb;
  const int q = tid & 31, nb = (tid >> 5) * 4;
  for (int j = 1; j < 4; ++j) {
    for (int i = tid; i < 1024; i += 256) Ms[i] = Mf[(4 * c + j) * 1024 + i];
    __syncthreads();
    float m0 = -3.0e38f, m1 = -3.0e38f, m2 = -3.0e38f, m3 = -3.0e38f;
    for (int pp = 0; pp < 32; ++pp) {
      float g = G[pp * 33 + q];
      m0 = fmaxf(m0, Ms[(nb + 0) * 32 + pp] + g);
      m1 = fmaxf(m1, Ms[(nb + 1) * 32 + pp] + g);
      m2 = fmaxf(m2, Ms[(nb + 2) * 32 + pp] + g);
      m3 = fmaxf(m3, Ms[(nb + 3) * 32 + pp] + g);
    }
    Gn[(nb + 0) * 33 + q] = m0;
    Gn[(nb + 1) * 33 + q] = m1;
    Gn[(nb + 2) * 33 + q] = m2;
    Gn[(nb + 3) * 33 + q] = m3;
    __syncthreads();
    float* t = G; G = Gn; Gn = t;
  }
  for (int i = tid; i < 1024; i += 256) Mcrs[c * 1024 + i] = G[(i >> 5) * 33 + (i & 31)];
}

__device__ __forceinline__ float vstep(float fv, int p0, const f32x4& M0, const f32x4& M1,
                                       const f32x4& M2, const f32x4& M3) {
  float mv[16];
#pragma unroll
  for (int j = 0; j < 4; ++j) { mv[j] = M0[j]; mv[4 + j] = M1[j]; mv[8 + j] = M2[j]; mv[12 + j] = M3[j]; }
  float cnd[16];
#pragma unroll
  for (int j = 0; j < 16; ++j) cnd[j] = __shfl(fv, p0 + j) + mv[j];
  float t8[8], t4[4];
#pragma unroll
  for (int j = 0; j < 8; ++j) t8[j] = fmaxf(cnd[2 * j], cnd[2 * j + 1]);
#pragma unroll
  for (int j = 0; j < 4; ++j) t4[j] = fmaxf(t8[2 * j], t8[2 * j + 1]);
  float bv = fmaxf(fmaxf(t4[0], t4[1]), fmaxf(t4[2], t4[3]));
  return fmaxf(bv, __shfl_xor(bv, 32));
}

__global__ __launch_bounds__(64) void vit_p2(const float* __restrict__ Mcrs,
                                             const float* __restrict__ trans,
                                             float* __restrict__ bfvF,
                                             float* __restrict__ term,
                                             float* __restrict__ out) {
  const int lane = threadIdx.x, n = lane & 31, h = lane >> 5, p0 = h << 4;
  float fv = (n == 30) ? 0.f : -10000.f;
  if (lane < 32) bfvF[n] = fv;
  const float* base = Mcrs + n * 32 + p0;
  f32x4 A0, A1, A2, A3, B0, B1, B2, B3, C0, C1, C2, C3;
#define LDM(d0, d1, d2, d3, c) { const float* M = base + (c) * 1024; \
  d0 = *(const f32x4*)M; d1 = *(const f32x4*)(M + 4); d2 = *(const f32x4*)(M + 8); d3 = *(const f32x4*)(M + 12); }
  LDM(A0, A1, A2, A3, 0) LDM(B0, B1, B2, B3, 1) LDM(C0, C1, C2, C3, 2)
#pragma unroll 1
  for (int c = 0; c < 30; c += 3) {
    fv = vstep(fv, p0, A0, A1, A2, A3); if (lane < 32) bfvF[(4 * (c + 1)) * 32 + n] = fv;
    { int cl = (c + 3) & 31; LDM(A0, A1, A2, A3, cl) }
    fv = vstep(fv, p0, B0, B1, B2, B3); if (lane < 32) bfvF[(4 * (c + 2)) * 32 + n] = fv;
    { int cl = (c + 4) & 31; LDM(B0, B1, B2, B3, cl) }
    fv = vstep(fv, p0, C0, C1, C2, C3); if (lane < 32) bfvF[(4 * (c + 3)) * 32 + n] = fv;
    { int cl = (c + 5) & 31; LDM(C0, C1, C2, C3, cl) }
  }
  fv = vstep(fv, p0, A0, A1, A2, A3); if (lane < 32) bfvF[(4 * 31) * 32 + n] = fv;
  fv = vstep(fv, p0, B0, B1, B2, B3); if (lane < 32) bfvF[(4 * 32) * 32 + n] = fv;
#undef LDM
  float v = fv + trans[31 * 32 + n];
  int idx = n;
#pragma unroll
  for (int o = 16; o; o >>= 1) {
    float ov = __shfl_xor(v, o);
    int oi = __shfl_xor(idx, o);
    if (ov > v || (ov == v && oi < idx)) { v = ov; idx = oi; }
  }
  if (lane == 0) { out[0] = v; term[0] = (float)idx; }
}

__global__ __launch_bounds__(64) void vit_p2b(const float* __restrict__ Mf, float* __restrict__ bfvF) {
  const int c = blockIdx.x, lane = threadIdx.x, n = lane & 31, h = lane >> 5, p0 = h << 4;
  float fv = bfvF[(4 * c) * 32 + n];
  const float* base = Mf + (size_t)(4 * c) * 1024 + n * 32 + p0;
#pragma unroll
  for (int j = 0; j < 3; ++j) {
    const float* M = base + j * 1024;
    f32x4 A0 = *(const f32x4*)M, A1 = *(const f32x4*)(M + 4);
    f32x4 A2 = *(const f32x4*)(M + 8), A3 = *(const f32x4*)(M + 12);
    fv = vstep(fv, p0, A0, A1, A2, A3);
    if (lane < 32) bfvF[(4 * c + j + 1) * 32 + n] = fv;
  }
}

__global__ __launch_bounds__(64) void vit_p3(const float* __restrict__ feats,
                                             const float* __restrict__ trans,
                                             const float* __restrict__ bfvF,
                                             unsigned char* __restrict__ bp) {
  const int c = blockIdx.x, lane = threadIdx.x, n = lane & 31, h = lane >> 5, p0 = h << 4;
  float tr[16];
#pragma unroll
  for (int j = 0; j < 16; ++j) tr[j] = trans[n * 32 + p0 + j];
  float fv = bfvF[c * 32 + n];
  float ft[VW];
  for (int s = 0; s < VW; ++s) ft[s] = feats[(c * VW + s) * 32 + n];
  for (int s = 0; s < VW; ++s) {
    float cd[16];
#pragma unroll
    for (int j = 0; j < 16; ++j) cd[j] = __shfl(fv, p0 + j) + tr[j];
    float v8[8]; int i8a[8];
#pragma unroll
    for (int j = 0; j < 8; ++j) {
      bool g = cd[2 * j + 1] > cd[2 * j];
      v8[j] = g ? cd[2 * j + 1] : cd[2 * j];
      i8a[j] = g ? 2 * j + 1 : 2 * j;
    }
    float v4[4]; int i4a[4];
#pragma unroll
    for (int j = 0; j < 4; ++j) {
      bool g = v8[2 * j + 1] > v8[2 * j];
      v4[j] = g ? v8[2 * j + 1] : v8[2 * j];
      i4a[j] = g ? i8a[2 * j + 1] : i8a[2 * j];
    }
    float v2[2]; int i2a[2];
#pragma unroll
    for (int j = 0; j < 2; ++j) {
      bool g = v4[2 * j + 1] > v4[2 * j];
      v2[j] = g ? v4[2 * j + 1] : v4[2 * j];
      i2a[j] = g ? i4a[2 * j + 1] : i4a[2 * j];
    }
    bool g1 = v2[1] > v2[0];
    float bv = g1 ? v2[1] : v2[0];
    int bi = p0 + (g1 ? i2a[1] : i2a[0]);
    float ov = __shfl_xor(bv, 32);
    int oi = __shfl_xor(bi, 32);
    bool takeo = h ? (ov >= bv) : (ov > bv);
    float m = takeo ? ov : bv;
    int mi = takeo ? oi : bi;
    if (!h) bp[(c * VW + s) * 32 + n] = (unsigned char)mi;
    fv = m + ft[s];
  }
}

__global__ __launch_bounds__(VC) void vit_p4(const unsigned char* __restrict__ bp,
                                             const float* __restrict__ term,
                                             float* __restrict__ out) {
  __shared__ unsigned char GsL[VC * 32];
  __shared__ unsigned char bnd[VC];
  const int lane = threadIdx.x;
  unsigned char g[32];
#pragma unroll
  for (int j = 0; j < 32; ++j) g[j] = (unsigned char)j;
  for (int s = VW - 1; s >= 0; --s) {
    const unsigned char* rowp = bp + (lane * VW + s) * 32;
#pragma unroll
    for (int j = 0; j < 32; ++j) g[j] = rowp[g[j]];
  }
#pragma unroll
  for (int j = 0; j < 32; ++j) GsL[lane * 32 + j] = g[j];
  __syncthreads();
  if (lane == 0) {
    bnd[VC - 1] = (unsigned char)(int)term[0];
    for (int cc = VC - 1; cc >= 1; --cc) bnd[cc - 1] = GsL[cc * 32 + bnd[cc]];
  }
  __syncthreads();
  int x = bnd[lane];
  out[1 + lane * VW + VW - 1] = (float)x;
  for (int k = VW - 2; k >= 0; --k) {
    x = bp[(lane * VW + k + 1) * 32 + x];
    out[1 + lane * VW + k] = (float)x;
  }
}

// ------------------------------ host ------------------------------
extern "C" void kernel_launch(void* const* d_in, const int* in_sizes, int n_in,
                              void* d_out, int out_size, void* d_ws, size_t ws_size,
                              hipStream_t stream) {
  (void)in_sizes; (void)n_in; (void)out_size; (void)ws_size;
  const int H = HHd, F = FFd, S = SS, L = LLd;
  const long HH2 = (long)H * H;
  const long SH = (long)S * H;
  const long HF = (long)H * F;

  hipFuncSetAttribute(reinterpret_cast<const void*>(fsa_k),
                      hipFuncAttributeMaxDynamicSharedMemorySize, FSA_SMEM);

  const int*   sent = (const int*)d_in[0];
  const float* embd = (const float*)d_in[1];
  const float* eaw  = (const float*)d_in[2];
  const float* eab  = (const float*)d_in[3];
  const float* ew1  = (const float*)d_in[4];
  const float* eb1  = (const float*)d_in[5];
  const float* ew2  = (const float*)d_in[6];
  const float* eb2  = (const float*)d_in[7];
  const float* elnw = (const float*)d_in[8];
  const float* elnb = (const float*)d_in[9];
  const float* daw  = (const float*)d_in[10];
  const float* dab  = (const float*)d_in[11];
  const float* dw1  = (const float*)d_in[12];
  const float* db1  = (const float*)d_in[13];
  const float* dw2  = (const float*)d_in[14];
  const float* db2  = (const float*)d_in[15];
  const float* dlnw = (const float*)d_in[16];
  const float* dlnb = (const float*)d_in[17];
  const float* enw  = (const float*)d_in[18];
  const float* enb  = (const float*)d_in[19];
  const float* dnw  = (const float*)d_in[20];
  const float* dnb  = (const float*)d_in[21];
  const float* h2tw = (const float*)d_in[22];
  const float* h2tb = (const float*)d_in[23];
  const float* trns = (const float*)d_in[24];

  char* p = (char*)d_ws;
  auto alloc = [&](size_t bytes) -> char* {
    char* r = p;
    p += (bytes + 255) & ~(size_t)255;
    return r;
  };
  short* wEAT = (short*)alloc((size_t)L * 4 * HH2 * 2);
  short* wDAT = (short*)alloc((size_t)L * 8 * HH2 * 2);
  short* wE1T = (short*)alloc((size_t)L * HF * 2);
  short* wE2T = (short*)alloc((size_t)L * HF * 2);
  short* wD1T = (short*)alloc((size_t)L * HF * 2);
  short* wD2T = (short*)alloc((size_t)L * HF * 2);
  short* h_b  = (short*)alloc(SH * 2);
  short* y_b  = (short*)alloc(SH * 2);
  float* tmpf = (float*)alloc(SH * 4);
  short* qkvb = (short*)alloc(4 * SH * 2);           // Q, K, V''-slot, crossQ
  float* scf  = (float*)alloc((size_t)8 * SH * 4);   // partial buffer (16x bf16 splits = 32MB; f32 alias prologue)
  float* Zp   = (float*)alloc((size_t)16 * S * 4);   // per-split Z row sums (self 8 + cross 8)
  short* ff1b = (short*)alloc((size_t)S * F * 2);
  short* memb = (short*)alloc(SH * 2);
  short* ckvA = (short*)alloc((size_t)2 * L * SH * 2);  // interleaved cross K (even slots; odd unused)
  short* cvT  = (short*)alloc((size_t)L * SH * 2);      // cross V''^T per layer (direct from GEMM)
  float* biasE = (float*)alloc((size_t)L * 4 * H * 4);  // eab with j=2 zeroed
  float* biasD = (float*)alloc((size_t)L * 8 * H * 4);  // dab with j=2,6 zeroed; j=3 <- dab j=4
  float* bvoAll = (float*)alloc((size_t)18 * H * 4);    // folded V/out biases
  float* bvoPart = (float*)alloc((size_t)18 * 16 * H * 4); // bvo partials
  float* ftsf = (float*)alloc((size_t)S * TTd * 4);
  float* McB  = (float*)alloc((size_t)VC * 1024 * 4);
  float* McrsB= (float*)alloc((size_t)(VC / 4) * 1024 * 4);
  float* bfvF = (float*)alloc((size_t)(VC + 1) * 32 * 4);
  float* termB= (float*)alloc(64);
  unsigned char* bpgB = (unsigned char*)alloc((size_t)2048 * 32);

  short* vtb = ff1b;                  // V''^T scratch aliases ff1b (disjoint lifetimes)
  short* sparts = (short*)scf;        // bf16 split partials (self: 8 x SH shorts)
  short* sparts2 = sparts + 8 * SH;   // bf16 split partials (cross: 8 x SH shorts)
  float* Zp2 = Zp + 8 * S;
  short* wvPe  = (short*)scf;         // plain bf16 Wv copies alias scf (prologue only)
  short* wvPds = wvPe + L * HH2;
  short* wvPdc = wvPds + L * HH2;

  const int ZBIG = 1 << 20;

  // ---- weight conversion ----
  tconv_k<<<dim3(16, 16, L * 4), 256, 0, stream>>>(eaw, wEAT, H, H);
  tconv_k<<<dim3(16, 16, L * 8), 256, 0, stream>>>(daw, wDAT, H, H);
  tconv_k<<<dim3(64, 16, L), 256, 0, stream>>>(ew1, wE1T, H, F);
  tconv_k<<<dim3(16, 64, L), 256, 0, stream>>>(ew2, wE2T, F, H);
  tconv_k<<<dim3(64, 16, L), 256, 0, stream>>>(dw1, wD1T, H, F);
  tconv_k<<<dim3(16, 64, L), 256, 0, stream>>>(dw2, wD2T, F, H);
  // plain bf16 copies of Wv (enc j2, dec-self j2, dec-cross j6)
  pconv_k<<<dim3(256, 1, L), 256, 0, stream>>>(eaw + 2 * HH2, wvPe, 4 * HH2, HH2);
  pconv_k<<<dim3(256, 1, L), 256, 0, stream>>>(daw + 2 * HH2, wvPds, 8 * HH2, HH2);
  pconv_k<<<dim3(256, 1, L), 256, 0, stream>>>(daw + 6 * HH2, wvPdc, 8 * HH2, HH2);
  // compose Wvo^T = Wout^T @ Wv^T into the V-weight slots (in place)
  auto G_cmp = gemm3<128, 64, false, false, false, false, true, false>;
  G_cmp<<<dim3(8, 4, L), 256, 0, stream>>>(
      wEAT + 3 * HH2, wvPe, nullptr, nullptr, nullptr, wEAT + 2 * HH2,
      H, H, H, H, H, 0, 1.f, 1, 4 * HH2, HH2, 0, 0, 0, 4 * HH2,
      nullptr, 0, 1, -1);
  G_cmp<<<dim3(8, 4, L), 256, 0, stream>>>(
      wDAT + 3 * HH2, wvPds, nullptr, nullptr, nullptr, wDAT + 2 * HH2,
      H, H, H, H, H, 0, 1.f, 1, 8 * HH2, HH2, 0, 0, 0, 8 * HH2,
      nullptr, 0, 1, -1);
  G_cmp<<<dim3(8, 4, L), 256, 0, stream>>>(
      wDAT + 7 * HH2, wvPdc, nullptr, nullptr, nullptr, wDAT + 6 * HH2,
      H, H, H, H, H, 0, 1.f, 1, 8 * HH2, HH2, 0, 0, 0, 8 * HH2,
      nullptr, 0, 1, -1);
  // dec-self Wout^T slot (j=3) is free after compose: move crossQ W^T (j=4) into it
  scpy_k<<<dim3(256, 1, L), 256, 0, stream>>>(wDAT + 4 * HH2, wDAT + 3 * HH2, 8 * HH2, 8 * HH2);
  // bias tables with V slots zeroed; folded biases
  zbias_k<<<dim3((L * 4 * H + 255) / 256), 256, 0, stream>>>(eab, biasE, 4, 1u << 2, L * 4 * H);
  zbias_k<<<dim3((L * 8 * H + 255) / 256), 256, 0, stream>>>(dab, biasD, 8, (1u << 2) | (1u << 6), L * 8 * H);
  bcpy_k<<<dim3(L * H / 256), 256, 0, stream>>>(dab, biasD);
  bvoP_k<<<dim3(18, 16), 256, 0, stream>>>(eaw, eab, daw, dab, bvoPart);
  bvoR_k<<<dim3(18), 256, 0, stream>>>(bvoPart, eab, dab, bvoAll);

  gather_k<<<dim3((unsigned)(SH / 256)), 256, 0, stream>>>(sent, embd, h_b, y_b);

  // gemm variants
  auto G_qkv = gemm3<128, 64, true, false, false, false, true, true>;   // batched proj; z==2 -> V''^T direct
  auto G_spl = gemm3<128, 64, false, false, false, false, true, false>; // split-K partials -> bf16
  auto G_ff1 = gemm3<128, 64, true, true, false, false, true, false>;   // bias+relu -> bf16

  dim3 gQKVe(8, 16, 3), gQKVd(8, 16, 4), gSPL(8, 16, 4), gFF1(32, 16, 1);
  dim3 gFSA(8, 32, 1), gFSA2(8, 32, 2);

  // ---------------- encoder ----------------
  for (int i = 0; i < L; ++i) {
    G_qkv<<<gQKVe, 256, 0, stream>>>(
        h_b, wEAT + (size_t)i * 4 * HH2, biasE + (size_t)i * 4 * H, nullptr, nullptr, qkvb,
        S, H, H, H, H, 0, 1.f, ZBIG, 0, 0, HH2, 0, H, SH,
        vtb, 0, 3, 2);
    fsa_k<<<gFSA, 512, FSA_SMEM, stream>>>(qkvb, qkvb + SH, vtb, sparts, Zp,
                                           qkvb, qkvb + SH, vtb, sparts, Zp);
    r4zrln_k<<<dim3(S), 256, 0, stream>>>(sparts, Zp, bvoAll + (size_t)i * H, h_b,
        elnw + (size_t)(i * 2) * H, elnb + (size_t)(i * 2) * H, h_b);
    G_ff1<<<gFF1, 256, 0, stream>>>(
        h_b, wE1T + (size_t)i * HF, eb1 + (size_t)i * F, nullptr, nullptr, ff1b,
        S, F, H, H, H, 0, 1.f, 1, 0, 0, 0, 0, 0, 0,
        nullptr, 0, 1, -1);
    G_spl<<<gSPL, 256, 0, stream>>>(
        ff1b, wE2T + (size_t)i * HF, nullptr, nullptr, nullptr, sparts,
        S, H, F / 4, F, F, F / 4, 1.f, 1, 0, 0, 0, 0, 0, SH,
        nullptr, 0, 1, -1);
    r4rln_k<<<dim3(S), 256, 0, stream>>>(sparts, eb2 + (size_t)i * H, h_b,
        elnw + (size_t)(i * 2 + 1) * H, elnb + (size_t)(i * 2 + 1) * H, h_b);
  }
  lnb_k<<<dim3(S), 256, 0, stream>>>(h_b, enw, enb, nullptr, memb);

  // cross K (j=5, even z) and composed V''^T (j=6, odd z -> direct transposed to cvT)
  G_qkv<<<dim3(8, 16, 2 * L), 256, 0, stream>>>(
      memb, wDAT + 5 * HH2, biasD + 5 * H, nullptr, nullptr, ckvA,
      S, H, H, H, H, 0, 1.f, 2, 0, 8 * HH2, HH2, 8 * H, H, SH,
      cvT, SH, 2, 1);

  // ---------------- decoder ----------------
  for (int i = 0; i < L; ++i) {
    // z=4 batch: Q, K, V''(->vtb transposed), crossQ (slot 3 holds crossQ weights/bias)
    G_qkv<<<gQKVd, 256, 0, stream>>>(
        y_b, wDAT + (size_t)i * 8 * HH2, biasD + (size_t)i * 8 * H, nullptr, nullptr, qkvb,
        S, H, H, H, H, 0, 1.f, ZBIG, 0, 0, HH2, 0, H, SH,
        vtb, 0, 4, 2);
    // dual-issue: self attention (set 0) + cross attention (set 1) in one launch
    fsa_k<<<gFSA2, 512, FSA_SMEM, stream>>>(
        qkvb, qkvb + SH, vtb, sparts, Zp,
        qkvb + 3 * SH, ckvA + (size_t)(2 * i) * SH, cvT + (size_t)i * SH, sparts2, Zp2);
    r4zrln_k<<<dim3(S), 256, 0, stream>>>(sparts, Zp, bvoAll + (size_t)(6 + i) * H, y_b,
        dlnw + (size_t)(i * 3) * H, dlnb + (size_t)(i * 3) * H, y_b);
    r4zrln_k<<<dim3(S), 256, 0, stream>>>(sparts2, Zp2, bvoAll + (size_t)(12 + i) * H, y_b,
        dlnw + (size_t)(i * 3 + 1) * H, dlnb + (size_t)(i * 3 + 1) * H, y_b);
    // FFN
    G_ff1<<<gFF1, 256, 0, stream>>>(
        y_b, wD1T + (size_t)i * HF, db1 + (size_t)i * F, nullptr, nullptr, ff1b,
        S, F, H, H, H, 0, 1.f, 1, 0, 0, 0, 0, 0, 0,
        nullptr, 0, 1, -1);
    G_spl<<<gSPL, 256, 0, stream>>>(
        ff1b, wD2T + (size_t)i * HF, nullptr, nullptr, nullptr, sparts,
        S, H, F / 4, F, F, F / 4, 1.f, 1, 0, 0, 0, 0, 0, SH,
        nullptr, 0, 1, -1);
    r4rln_k<<<dim3(S), 256, 0, stream>>>(sparts, db2 + (size_t)i * H, y_b,
        dlnw + (size_t)(i * 3 + 2) * H, dlnb + (size_t)(i * 3 + 2) * H, y_b);
  }
  // final norm + feats + hierarchical parallel viterbi
  lnb_k<<<dim3(S), 256, 0, stream>>>(y_b, dnw, dnb, tmpf, memb);
  feats_k<<<dim3(S / 8), 256, 0, stream>>>(tmpf, h2tw, h2tb, ftsf);
  float* outF = (float*)d_out;
  vit_p1<<<dim3(VC), 256, 0, stream>>>(ftsf, trns, McB);
  vit_p1b<<<dim3(VC / 4), 256, 0, stream>>>(McB, McrsB);
  vit_p2<<<dim3(1), 64, 0, stream>>>(McrsB, trns, bfvF, termB, outF);
  vit_p2b<<<dim3(VC / 4), 64, 0, stream>>>(McB, bfvF);
  vit_p3<<<dim3(VC), 64, 0, stream>>>(ftsf, trns, bfvF, bpgB);
  vit_p4<<<dim3(1), VC, 0, stream>>>(bpgB, termB, outF);
}

// Round 28
// 1186.095 us; speedup vs baseline: 1.1108x; 1.0234x over previous
//
#include <hip/hip_runtime.h>
#include <cstdint>

#define SS 2048
#define HHd 512
#define FFd 2048
#define TTd 32
#define LLd 6
#define VW 16
#define VC 128

typedef float f32x4 __attribute__((ext_vector_type(4)));
typedef __bf16 bf16x8 __attribute__((ext_vector_type(8)));
typedef short short8v __attribute__((ext_vector_type(8)));
typedef short short4v __attribute__((ext_vector_type(4)));

__device__ __forceinline__ short f2b(float f) {
  unsigned u = __builtin_bit_cast(unsigned, f);
  u += 0x7fffu + ((u >> 16) & 1u);
  return (short)(u >> 16);
}
__device__ __forceinline__ float b2f(short s) {
  unsigned u = ((unsigned)(unsigned short)s) << 16;
  return __builtin_bit_cast(float, u);
}

typedef const __attribute__((address_space(1))) void gv_t;
typedef __attribute__((address_space(3))) void lv_t;
__device__ __forceinline__ void gload16(const void* g, void* l) {
  __builtin_amdgcn_global_load_lds((gv_t*)g, (lv_t*)l, 16, 0, 0);
}

// ------------------------------ GEMM (all-TB, BK=64, swizzled LDS, double-buffered 2-phase) ------------------------------
template<int BMt, int BNt, bool BIAS, bool RELU, bool RESID, bool OUTF, bool OUTB, bool TRBE>
__global__ __launch_bounds__(256) void gemm3(
    const short* __restrict__ A, const short* __restrict__ Bb,
    const float* __restrict__ biasb, const float* __restrict__ resid,
    float* __restrict__ Cfb, short* __restrict__ Cbb,
    int M, int N, int K, int lda, int ldb, int kzS, float scale,
    int zdiv, long as1, long bs1, long bs2, int bb1, int bb2, long cStr,
    short* __restrict__ CbT, long ctStr, int tmod, int tval)
{
  constexpr int MR = BMt / 32, NR = BNt / 32;
  constexpr int WMt = BMt / 2, WNt = BNt / 2;
  constexpr int ACALLS = BMt / 8;
  constexpr int TOT = (BMt + BNt) / 8;
  constexpr int CPW = TOT / 4;
  constexpr int HALF = BMt * 64 + BNt * 64;

  const int z = blockIdx.z;
  const short* Ap = A + (long)z * as1;
  const short* Bp = Bb + (long)(z / zdiv) * bs1 + (long)(z % zdiv) * bs2;
  const float* bias = BIAS ? (biasb + (z / zdiv) * bb1 + (z % zdiv) * bb2) : nullptr;
  const int kz = z * kzS;

  const int m0 = blockIdx.y * BMt;
  const int n0 = blockIdx.x * BNt;

  __shared__ __align__(16) short LDSbuf[2 * HALF];

  const int tid = threadIdx.x;
  const int lane = tid & 63;
  const int w = tid >> 6;

  const short* srcs[CPW];
  int loff[CPW];
  {
    const int rl8 = lane >> 3;
    const int c16 = (lane & 7) ^ rl8;
#pragma unroll
    for (int c = 0; c < CPW; ++c) {
      int q = w * CPW + c;
      if (q < ACALLS) {
        int row = q * 8 + rl8;
        srcs[c] = Ap + (long)(m0 + row) * lda + kz + c16 * 8;
        loff[c] = q * 512;
      } else {
        int row = (q - ACALLS) * 8 + rl8;
        srcs[c] = Bp + (long)(n0 + row) * ldb + kz + c16 * 8;
        loff[c] = BMt * 64 + (q - ACALLS) * 512;
      }
    }
  }

  const int lrow = lane & 15;
  const int slotb = lane >> 4;
  const int wm = (w >> 1) * WMt, wn = (w & 1) * WNt;

  f32x4 acc[MR][NR] = {};

  // prologue: stage tile 0 into buffer 0
#pragma unroll
  for (int c = 0; c < CPW; ++c) gload16(srcs[c], LDSbuf + loff[c]);
#pragma unroll
  for (int c = 0; c < CPW; ++c) srcs[c] += 64;
  __syncthreads();

  const int NIT = K >> 6;
  for (int it = 0; it < NIT; ++it) {
    const int cur = it & 1;
    if (it + 1 < NIT) {
      const int nxt = (cur ^ 1) * HALF;
#pragma unroll
      for (int c = 0; c < CPW; ++c) gload16(srcs[c], LDSbuf + nxt + loff[c]);
#pragma unroll
      for (int c = 0; c < CPW; ++c) srcs[c] += 64;
    }
    const short* As = LDSbuf + cur * HALF;
    const short* Bs = As + BMt * 64;
#pragma unroll
    for (int s = 0; s < 2; ++s) {
      bf16x8 af[MR], bfv[NR];
#pragma unroll
      for (int f = 0; f < MR; ++f) {
        int row = wm + f * 16 + lrow;
        int phys = (slotb + s * 4) ^ (row & 7);
        af[f] = *(const bf16x8*)&As[row * 64 + phys * 8];
      }
#pragma unroll
      for (int f = 0; f < NR; ++f) {
        int row = wn + f * 16 + lrow;
        int phys = (slotb + s * 4) ^ (row & 7);
        bfv[f] = *(const bf16x8*)&Bs[row * 64 + phys * 8];
      }
#pragma unroll
      for (int i = 0; i < MR; ++i)
#pragma unroll
        for (int j = 0; j < NR; ++j)
          acc[i][j] = __builtin_amdgcn_mfma_f32_16x16x32_bf16(af[i], bfv[j], acc[i][j], 0, 0, 0);
    }
    __syncthreads();   // drains L(it+1); frees buf[cur]
  }

  const int crow = (lane >> 4) * 4;
  const int ccol = lane & 15;
  const bool dotr = TRBE && ((z % tmod) == tval);

  if (OUTB) {
    if (dotr) {
      short* Cb = CbT + (long)(z / zdiv) * ctStr;
      constexpr int LDSW = BMt + 8;
      short* Os = LDSbuf;
#pragma unroll
      for (int i = 0; i < MR; ++i) {
#pragma unroll
        for (int j = 0; j < NR; ++j) {
          int lc = wn + j * 16 + ccol;
          float bv = BIAS ? bias[n0 + lc] : 0.f;
#pragma unroll
          for (int r = 0; r < 4; ++r) {
            int lr = wm + i * 16 + crow + r;
            Os[lc * LDSW + lr] = f2b(acc[i][j][r] * scale + bv);
          }
        }
      }
      __syncthreads();
      constexpr int CPR = BMt / 8;
      constexpr int CPT = (BMt * BNt / 8) / 256;
#pragma unroll
      for (int c = 0; c < CPT; ++c) {
        int idx = tid + c * 256;
        int col = idx / CPR;
        int rowc = (idx % CPR) * 8;
        int4 vv = *(const int4*)&Os[col * LDSW + rowc];
        *(int4*)&Cb[(long)(n0 + col) * M + m0 + rowc] = vv;
      }
    } else {
      short* Cb = Cbb + (long)z * cStr;
      constexpr int LDSW = BNt + 8;
      short* Os = LDSbuf;
#pragma unroll
      for (int i = 0; i < MR; ++i) {
#pragma unroll
        for (int j = 0; j < NR; ++j) {
          int lc = wn + j * 16 + ccol;
          float bv = BIAS ? bias[n0 + lc] : 0.f;
#pragma unroll
          for (int r = 0; r < 4; ++r) {
            int lr = wm + i * 16 + crow + r;
            float v = acc[i][j][r] * scale + bv;
            if (RELU) v = v > 0.f ? v : 0.f;
            Os[lr * LDSW + lc] = f2b(v);
          }
        }
      }
      __syncthreads();
      constexpr int CPR = BNt / 8;
      constexpr int CPT = (BMt * BNt / 8) / 256;
#pragma unroll
      for (int c = 0; c < CPT; ++c) {
        int idx = tid + c * 256;
        int row = idx / CPR;
        int col8 = (idx % CPR) * 8;
        int4 vv = *(const int4*)&Os[row * LDSW + col8];
        *(int4*)&Cb[(long)(m0 + row) * N + n0 + col8] = vv;
      }
    }
  } else {
    float* Cf = Cfb + (long)z * cStr;
#pragma unroll
    for (int i = 0; i < MR; ++i) {
#pragma unroll
      for (int j = 0; j < NR; ++j) {
        int gc = n0 + wn + j * 16 + ccol;
        float bv = BIAS ? bias[gc] : 0.f;
#pragma unroll
        for (int r = 0; r < 4; ++r) {
          int gr = m0 + wm + i * 16 + crow + r;
          long off = (long)gr * N + gc;
          float v = acc[i][j][r] * scale + bv;
          if (RESID) v += resid[off];
          if (RELU) v = v > 0.f ? v : 0.f;
          Cf[off] = v;
        }
      }
    }
  }
}

// ============================== Fused attention (q-tile 64, key-split 8, 8 waves, 2-phase) ==============================
// blockIdx.z selects pointer set 0/1 (dual-issue: decoder self + cross attention in one launch).
#define FSA_SMEM (64 * 512 * 2 + 512 * 64 * 2 + 64 * 64 * 2 + 128 * 4)
__global__ __launch_bounds__(512) void fsa_k(
    const short* __restrict__ Q0, const short* __restrict__ K0,
    const short* __restrict__ V0, short* __restrict__ O0, float* __restrict__ Zp0,
    const short* __restrict__ Q1, const short* __restrict__ K1,
    const short* __restrict__ V1, short* __restrict__ O1, float* __restrict__ Zp1) {
  extern __shared__ __align__(16) char smem[];
  short* Ks  = (short*)smem;           // [64][512]  (Q stage / K chunk / O stage)
  short* Vts = Ks + 64 * 512;          // [512][64]
  short* Ps  = Vts + 512 * 64;         // [64][64]
  float* Zs  = (float*)(Ps + 64 * 64); // [2][64]
  const float RSQ = 0.04419417382415922f;

  const int sel = blockIdx.z;
  const short* Q   = sel ? Q1 : Q0;
  const short* Kmat= sel ? K1 : K0;
  const short* VT  = sel ? V1 : V0;
  short* Op        = sel ? O1 : O0;
  float* Zp        = sel ? Zp1 : Zp0;

  const int z = blockIdx.x;            // key split (0..7)
  const int q0 = blockIdx.y * 64;
  const int key0 = z * 256;
  const int tid = threadIdx.x, lane = tid & 63, w = tid >> 6;
  const int qg = w >> 1;               // 0..3 q-group (16 rows each)
  const int kh = w & 1;
  const int wn = kh * 32, wn2 = kh * 256;
  const int lrow = lane & 15, lgrp = lane >> 4;

  // stage Q (64 rows)
  for (int c = 0; c < 8; ++c) {
    int row = w * 8 + c;
    const short* src = Q + (long)(q0 + row) * HHd + (lane ^ (row & 7)) * 8;
    gload16(src, &Ks[row * 512]);
  }
  __syncthreads();
  bf16x8 qf[16];
#pragma unroll
  for (int st = 0; st < 16; ++st) {
    int row = qg * 16 + lrow;
    int phys = (st * 4 + lgrp) ^ (row & 7);
    qf[st] = *(const bf16x8*)&Ks[row * 512 + phys * 8];
  }
  __syncthreads();

  // prologue: stage K(0)
  for (int c = 0; c < 8; ++c) {
    int row = w * 8 + c;
    const short* src = Kmat + (long)(key0 + row) * HHd + (lane ^ (row & 7)) * 8;
    gload16(src, &Ks[row * 512]);
  }
  __syncthreads();

  f32x4 accO[16] = {};
  float zacc[4] = {};

  for (int kc = 0; kc < 4; ++kc) {
    // issue V(kc) — flies under QK compute
    for (int c = 0; c < 8; ++c) {
      int rb = (w * 8 + c) * 8;
      int vrow = rb + (lane >> 3);
      const short* src = VT + (long)vrow * SS + key0 + kc * 64 + ((lane & 7) ^ (vrow & 7)) * 8;
      gload16(src, &Vts[rb * 64]);
    }
    f32x4 accS0 = {}, accS1 = {};
#pragma unroll
    for (int st = 0; st < 16; ++st) {
      int row0 = wn + lrow;
      int phys0 = (st * 4 + lgrp) ^ (row0 & 7);
      bf16x8 b0 = *(const bf16x8*)&Ks[row0 * 512 + phys0 * 8];
      int row1 = wn + 16 + lrow;
      int phys1 = (st * 4 + lgrp) ^ (row1 & 7);
      bf16x8 b1 = *(const bf16x8*)&Ks[row1 * 512 + phys1 * 8];
      accS0 = __builtin_amdgcn_mfma_f32_16x16x32_bf16(qf[st], b0, accS0, 0, 0, 0);
      accS1 = __builtin_amdgcn_mfma_f32_16x16x32_bf16(qf[st], b1, accS1, 0, 0, 0);
    }
#pragma unroll
    for (int f = 0; f < 2; ++f) {
#pragma unroll
      for (int r = 0; r < 4; ++r) {
        int row = qg * 16 + lgrp * 4 + r;
        int col = wn + f * 16 + lrow;
        float sv = f ? accS1[r] : accS0[r];
        float e = __expf(sv * RSQ);
        zacc[r] += e;
        int slot = col >> 3;
        Ps[row * 64 + ((slot ^ (row & 7)) * 8) + (col & 7)] = f2b(e);
      }
    }
    __syncthreads();   // drains V(kc); P visible; Ks free (QK done)
    // issue K(kc+1) — flies under PV compute
    if (kc < 3) {
      for (int c = 0; c < 8; ++c) {
        int row = w * 8 + c;
        const short* src = Kmat + (long)(key0 + (kc + 1) * 64 + row) * HHd + (lane ^ (row & 7)) * 8;
        gload16(src, &Ks[row * 512]);
      }
    }
#pragma unroll
    for (int kk = 0; kk < 2; ++kk) {
      int prow = qg * 16 + lrow;
      int pphys = (kk * 4 + lgrp) ^ (prow & 7);
      bf16x8 pa = *(const bf16x8*)&Ps[prow * 64 + pphys * 8];
#pragma unroll
      for (int n = 0; n < 16; ++n) {
        int vrow = wn2 + n * 16 + lrow;
        int vphys = (kk * 4 + lgrp) ^ (vrow & 7);
        bf16x8 vb = *(const bf16x8*)&Vts[vrow * 64 + vphys * 8];
        accO[n] = __builtin_amdgcn_mfma_f32_16x16x32_bf16(pa, vb, accO[n], 0, 0, 0);
      }
    }
    __syncthreads();   // drains K(kc+1); Vts/Ps free for next iteration
  }

  // epilogue: stage O as bf16 into Ks (linear [64][512]) + Z shuffles
#pragma unroll
  for (int n = 0; n < 16; ++n) {
#pragma unroll
    for (int r = 0; r < 4; ++r) {
      int row = qg * 16 + lgrp * 4 + r;
      int col = wn2 + n * 16 + lrow;
      Ks[row * 512 + col] = f2b(accO[n][r]);
    }
  }
#pragma unroll
  for (int r = 0; r < 4; ++r) {
    float v = zacc[r];
    v += __shfl_xor(v, 1); v += __shfl_xor(v, 2);
    v += __shfl_xor(v, 4); v += __shfl_xor(v, 8);
    if (lrow == 0) Zs[kh * 64 + qg * 16 + lgrp * 4 + r] = v;
  }
  __syncthreads();
  short* OpZ = Op + (long)z * (long)SS * HHd + (long)q0 * HHd;
#pragma unroll
  for (int c = 0; c < 8; ++c) {
    int idx = tid + c * 512;
    *(int4*)&OpZ[idx * 8] = *(const int4*)&Ks[idx * 8];
  }
  if (tid < 64) Zp[(long)z * SS + q0 + tid] = Zs[tid] + Zs[64 + tid];
}

// ---------------- fused attention tail: (sum8 bf16-O)/Z + bvo + bf16 resid + LayerNorm -> bf16 ----------------
__global__ __launch_bounds__(256) void r4zrln_k(const short* __restrict__ pb,
                                                const float* __restrict__ Zp,
                                                const float* __restrict__ bvo,
                                                const short* __restrict__ resid,
                                                const float* __restrict__ w, const float* __restrict__ b,
                                                short* __restrict__ Yb) {
  const long SH = (long)SS * HHd;
  const int row = blockIdx.x, tid = threadIdx.x;
  long base = (long)row * HHd;
  float zt = 0.f;
#pragma unroll
  for (int sk = 0; sk < 8; ++sk) zt += Zp[(long)sk * SS + row];
  float zi = 1.0f / zt;
  float a0 = 0.f, a1 = 0.f;
#pragma unroll
  for (int sk = 0; sk < 8; ++sk) {
    a0 += b2f(pb[sk * SH + base + tid]);
    a1 += b2f(pb[sk * SH + base + tid + 256]);
  }
  float x0 = a0 * zi + bvo[tid] + b2f(resid[base + tid]);
  float x1 = a1 * zi + bvo[tid + 256] + b2f(resid[base + tid + 256]);
  float s = x0 + x1;
#pragma unroll
  for (int o = 32; o; o >>= 1) s += __shfl_xor(s, o);
  __shared__ float r1[4], r2[4];
  if ((tid & 63) == 0) r1[tid >> 6] = s;
  __syncthreads();
  float mean = (r1[0] + r1[1] + r1[2] + r1[3]) * (1.f / HHd);
  float d0 = x0 - mean, d1 = x1 - mean;
  float q = d0 * d0 + d1 * d1;
#pragma unroll
  for (int o = 32; o; o >>= 1) q += __shfl_xor(q, o);
  if ((tid & 63) == 0) r2[tid >> 6] = q;
  __syncthreads();
  float var = (r2[0] + r2[1] + r2[2] + r2[3]) * (1.f / HHd);
  float rs = rsqrtf(var + 1e-5f);
  float o0 = d0 * rs * w[tid] + b[tid];
  float o1 = d1 * rs * w[tid + 256] + b[tid + 256];
  Yb[base + tid] = f2b(o0); Yb[base + tid + 256] = f2b(o1);
}

// ---------------- fused decoder double-tail: self-attn tail then cross-attn tail, y1 kept in registers ----------------
__global__ __launch_bounds__(256) void r4zrln2_k(
    const short* __restrict__ pbA, const float* __restrict__ ZpA, const float* __restrict__ bvoA,
    const short* __restrict__ pbB, const float* __restrict__ ZpB, const float* __restrict__ bvoB,
    const float* __restrict__ w1, const float* __restrict__ b1,
    const float* __restrict__ w2, const float* __restrict__ b2,
    short* __restrict__ Yb) {
  const long SH = (long)SS * HHd;
  const int row = blockIdx.x, tid = threadIdx.x;
  long base = (long)row * HHd;
  __shared__ float r1[4], r2[4], r3[4], r4[4];

  // ---- stage A: self-attention tail ----
  float zt = 0.f;
#pragma unroll
  for (int sk = 0; sk < 8; ++sk) zt += ZpA[(long)sk * SS + row];
  float zi = 1.0f / zt;
  float a0 = 0.f, a1 = 0.f;
#pragma unroll
  for (int sk = 0; sk < 8; ++sk) {
    a0 += b2f(pbA[sk * SH + base + tid]);
    a1 += b2f(pbA[sk * SH + base + tid + 256]);
  }
  float x0 = a0 * zi + bvoA[tid] + b2f(Yb[base + tid]);
  float x1 = a1 * zi + bvoA[tid + 256] + b2f(Yb[base + tid + 256]);
  float s = x0 + x1;
#pragma unroll
  for (int o = 32; o; o >>= 1) s += __shfl_xor(s, o);
  if ((tid & 63) == 0) r1[tid >> 6] = s;
  __syncthreads();
  float mean = (r1[0] + r1[1] + r1[2] + r1[3]) * (1.f / HHd);
  float d0 = x0 - mean, d1 = x1 - mean;
  float q = d0 * d0 + d1 * d1;
#pragma unroll
  for (int o = 32; o; o >>= 1) q += __shfl_xor(q, o);
  if ((tid & 63) == 0) r2[tid >> 6] = q;
  __syncthreads();
  float var = (r2[0] + r2[1] + r2[2] + r2[3]) * (1.f / HHd);
  float rs = rsqrtf(var + 1e-5f);
  // bf16-round y1 to match the previous store/reload numerics
  float y10 = b2f(f2b(d0 * rs * w1[tid] + b1[tid]));
  float y11 = b2f(f2b(d1 * rs * w1[tid + 256] + b1[tid + 256]));

  // ---- stage B: cross-attention tail (resid = y1 in registers) ----
  float zt2 = 0.f;
#pragma unroll
  for (int sk = 0; sk < 8; ++sk) zt2 += ZpB[(long)sk * SS + row];
  float zi2 = 1.0f / zt2;
  float c0 = 0.f, c1 = 0.f;
#pragma unroll
  for (int sk = 0; sk < 8; ++sk) {
    c0 += b2f(pbB[sk * SH + base + tid]);
    c1 += b2f(pbB[sk * SH + base + tid + 256]);
  }
  float u0 = c0 * zi2 + bvoB[tid] + y10;
  float u1 = c1 * zi2 + bvoB[tid + 256] + y11;
  float s2 = u0 + u1;
#pragma unroll
  for (int o = 32; o; o >>= 1) s2 += __shfl_xor(s2, o);
  if ((tid & 63) == 0) r3[tid >> 6] = s2;
  __syncthreads();
  float mean2 = (r3[0] + r3[1] + r3[2] + r3[3]) * (1.f / HHd);
  float e0 = u0 - mean2, e1 = u1 - mean2;
  float q2 = e0 * e0 + e1 * e1;
#pragma unroll
  for (int o = 32; o; o >>= 1) q2 += __shfl_xor(q2, o);
  if ((tid & 63) == 0) r4[tid >> 6] = q2;
  __syncthreads();
  float var2 = (r4[0] + r4[1] + r4[2] + r4[3]) * (1.f / HHd);
  float rs2 = rsqrtf(var2 + 1e-5f);
  float o0 = e0 * rs2 * w2[tid] + b2[tid];
  float o1 = e1 * rs2 * w2[tid + 256] + b2[tid + 256];
  Yb[base + tid] = f2b(o0); Yb[base + tid + 256] = f2b(o1);
}

// ---------------- split-K=4 bf16 reduce + bias + bf16 resid + LayerNorm -> bf16 (FFN2) ----------------
__global__ __launch_bounds__(256) void r4rln_k(const short* __restrict__ pb,
                                               const float* __restrict__ bias,
                                               const short* __restrict__ resid,
                                               const float* __restrict__ w, const float* __restrict__ b,
                                               short* __restrict__ Yb) {
  const long SH = (long)SS * HHd;
  const int row = blockIdx.x, tid = threadIdx.x;
  long base = (long)row * HHd;
  float x0 = bias[tid] + b2f(resid[base + tid]);
  float x1 = bias[tid + 256] + b2f(resid[base + tid + 256]);
#pragma unroll
  for (int sk = 0; sk < 4; ++sk) {
    x0 += b2f(pb[sk * SH + base + tid]);
    x1 += b2f(pb[sk * SH + base + tid + 256]);
  }
  float s = x0 + x1;
#pragma unroll
  for (int o = 32; o; o >>= 1) s += __shfl_xor(s, o);
  __shared__ float r1[4], r2[4];
  if ((tid & 63) == 0) r1[tid >> 6] = s;
  __syncthreads();
  float mean = (r1[0] + r1[1] + r1[2] + r1[3]) * (1.f / HHd);
  float d0 = x0 - mean, d1 = x1 - mean;
  float q = d0 * d0 + d1 * d1;
#pragma unroll
  for (int o = 32; o; o >>= 1) q += __shfl_xor(q, o);
  if ((tid & 63) == 0) r2[tid >> 6] = q;
  __syncthreads();
  float var = (r2[0] + r2[1] + r2[2] + r2[3]) * (1.f / HHd);
  float rs = rsqrtf(var + 1e-5f);
  float o0 = d0 * rs * w[tid] + b[tid];
  float o1 = d1 * rs * w[tid + 256] + b[tid + 256];
  Yb[base + tid] = f2b(o0); Yb[base + tid + 256] = f2b(o1);
}

// ---------------- LayerNorm over bf16 rows; optional f32 out + bf16 out ----------------
__global__ __launch_bounds__(256) void lnb_k(const short* __restrict__ Xb, const float* __restrict__ w,
                                             const float* __restrict__ b, float* __restrict__ Yf,
                                             short* __restrict__ Yb) {
  const int row = blockIdx.x;
  const int tid = threadIdx.x;
  long base = (long)row * HHd;
  float x0 = b2f(Xb[base + tid]), x1 = b2f(Xb[base + tid + 256]);
  float s = x0 + x1;
#pragma unroll
  for (int o = 32; o; o >>= 1) s += __shfl_xor(s, o);
  __shared__ float r1[4], r2[4];
  if ((tid & 63) == 0) r1[tid >> 6] = s;
  __syncthreads();
  float mean = (r1[0] + r1[1] + r1[2] + r1[3]) * (1.f / HHd);
  float d0 = x0 - mean, d1 = x1 - mean;
  float q = d0 * d0 + d1 * d1;
#pragma unroll
  for (int o = 32; o; o >>= 1) q += __shfl_xor(q, o);
  if ((tid & 63) == 0) r2[tid >> 6] = q;
  __syncthreads();
  float var = (r2[0] + r2[1] + r2[2] + r2[3]) * (1.f / HHd);
  float rs = rsqrtf(var + 1e-5f);
  float o0 = d0 * rs * w[tid] + b[tid];
  float o1 = d1 * rs * w[tid + 256] + b[tid + 256];
  if (Yf) { Yf[base + tid] = o0; Yf[base + tid + 256] = o1; }
  Yb[base + tid] = f2b(o0); Yb[base + tid + 256] = f2b(o1);
}

// ---------------- dual f32 [K,N] -> bf16 [N,K] transpose-convert (z-range select) ----------------
__global__ __launch_bounds__(256) void tconv2_k(const float* __restrict__ in0, short* __restrict__ out0,
                                                const float* __restrict__ in1, short* __restrict__ out1,
                                                int K, int N, int split) {
  __shared__ float t[32][33];
  int zz = blockIdx.z;
  const float* in = (zz < split) ? in0 : in1;
  short* out = (zz < split) ? out0 : out1;
  int zi = (zz < split) ? zz : zz - split;
  long zo = (long)zi * K * N;
  int n0 = blockIdx.x * 32, k0 = blockIdx.y * 32;
  int tx = threadIdx.x & 31, ty = threadIdx.x >> 5;
#pragma unroll
  for (int i = 0; i < 4; ++i)
    t[ty + i * 8][tx] = in[zo + (long)(k0 + ty + i * 8) * N + n0 + tx];
  __syncthreads();
#pragma unroll
  for (int i = 0; i < 4; ++i)
    out[zo + (long)(n0 + ty + i * 8) * K + k0 + tx] = f2b(t[tx][ty + i * 8]);
}

// ---------------- triple strided f32 -> bf16 convert (z/L selects pair) ----------------
__global__ __launch_bounds__(256) void pconv3_k(const float* __restrict__ inA, short* __restrict__ outA,
                                                long strideA,
                                                const float* __restrict__ inB, short* __restrict__ outB,
                                                long strideB,
                                                const float* __restrict__ inC, short* __restrict__ outC,
                                                long strideC, long outStride) {
  int zz = blockIdx.z;
  int grp = zz / LLd, zi = zz % LLd;
  const float* in = grp == 0 ? inA : (grp == 1 ? inB : inC);
  short* out = grp == 0 ? outA : (grp == 1 ? outB : outC);
  long inStride = grp == 0 ? strideA : (grp == 1 ? strideB : strideC);
  long i = ((long)blockIdx.x * 256 + threadIdx.x) * 4;
  const float* ip = in + (long)zi * inStride + i;
  short* op = out + (long)zi * outStride + i;
  float4 v = *(const float4*)ip;
  short4v o;
  o[0] = f2b(v.x); o[1] = f2b(v.y); o[2] = f2b(v.z); o[3] = f2b(v.w);
  *(short4v*)op = o;
}

// ---------------- bf16 strided copy (batched z) ----------------
__global__ __launch_bounds__(256) void scpy_k(const short* __restrict__ src, short* __restrict__ dst,
                                              long srcStride, long dstStride) {
  long i = ((long)blockIdx.x * 256 + threadIdx.x) * 4;
  *(short4v*)(dst + (long)blockIdx.z * dstStride + i) =
      *(const short4v*)(src + (long)blockIdx.z * srcStride + i);
}

// ---------------- bias slot copy: biasD[l*8+3] <- dab[l*8+4] ----------------
__global__ __launch_bounds__(256) void bcpy_k(const float* __restrict__ src, float* __restrict__ dst) {
  int i = blockIdx.x * 256 + threadIdx.x;  // over L*H
  int l = i >> 9, c = i & 511;
  dst[(l * 8 + 3) * HHd + c] = src[(l * 8 + 4) * HHd + c];
}

// ---------------- bias table copy with zeroed j-slots ----------------
__global__ __launch_bounds__(256) void zbias_k(const float* __restrict__ src, float* __restrict__ dst,
                                               int nj, unsigned jmask, int total) {
  int i = blockIdx.x * 256 + threadIdx.x;
  if (i >= total) return;
  int j = (i >> 9) % nj;
  dst[i] = ((jmask >> j) & 1u) ? 0.f : src[i];
}

// ---------------- bvo partials: row-major streaming (18 combos x 16 m-groups) ----------------
__global__ __launch_bounds__(256) void bvoP_k(const float* __restrict__ eaw, const float* __restrict__ eab,
                                              const float* __restrict__ daw, const float* __restrict__ dab,
                                              float* __restrict__ part) {
  const long HH2 = (long)HHd * HHd;
  const int b = blockIdx.x, mg = blockIdx.y, tid = threadIdx.x;
  const float* Wout; const float* bv;
  if (b < 6) {
    int i = b;
    Wout = eaw + (i * 4 + 3) * HH2; bv = eab + (i * 4 + 2) * HHd;
  } else if (b < 12) {
    int i = b - 6;
    Wout = daw + (i * 8 + 3) * HH2; bv = dab + (i * 8 + 2) * HHd;
  } else {
    int i = b - 12;
    Wout = daw + (i * 8 + 7) * HH2; bv = dab + (i * 8 + 6) * HHd;
  }
  float a0 = 0.f, a1 = 0.f;
#pragma unroll 4
  for (int m = mg * 32; m < mg * 32 + 32; ++m) {
    float bvm = bv[m];
    a0 = fmaf(bvm, Wout[(long)m * HHd + tid], a0);
    a1 = fmaf(bvm, Wout[(long)m * HHd + tid + 256], a1);
  }
  long o = ((long)b * 16 + mg) * HHd;
  part[o + tid] = a0;
  part[o + tid + 256] = a1;
}

// ---------------- bvo reduce: sum 16 partials + bout ----------------
__global__ __launch_bounds__(256) void bvoR_k(const float* __restrict__ part,
                                              const float* __restrict__ eab, const float* __restrict__ dab,
                                              float* __restrict__ bvoAll) {
  const int b = blockIdx.x, tid = threadIdx.x;
  const float* bout;
  if (b < 6) bout = eab + (b * 4 + 3) * HHd;
  else if (b < 12) bout = dab + ((b - 6) * 8 + 3) * HHd;
  else bout = dab + ((b - 12) * 8 + 7) * HHd;
  float s0 = bout[tid], s1 = bout[tid + 256];
#pragma unroll
  for (int mg = 0; mg < 16; ++mg) {
    long o = ((long)b * 16 + mg) * HHd;
    s0 += part[o + tid];
    s1 += part[o + tid + 256];
  }
  bvoAll[(long)b * HHd + tid] = s0;
  bvoAll[(long)b * HHd + tid + 256] = s1;
}

// ------------------------------ embedding gather (bf16 only) ------------------------------
__global__ __launch_bounds__(256) void gather_k(const int* __restrict__ sent, const float* __restrict__ emb,
                                                short* __restrict__ hb, short* __restrict__ yb) {
  long i = (long)blockIdx.x * 256 + threadIdx.x;
  int s = (int)(i >> 9);
  int hcol = (int)(i & 511);
  float v = emb[(long)sent[s] * HHd + hcol];
  short bb = f2b(v);
  hb[i] = bb; yb[i] = bb;
}

// ------------------------------ fused final LN + feats: LN(y_b) @ [HHd,TTd] + b (f32) ------------------------------
__global__ __launch_bounds__(256) void featsln_k(const short* __restrict__ Yb,
                                                 const float* __restrict__ w, const float* __restrict__ b,
                                                 const float* __restrict__ W, const float* __restrict__ bias,
                                                 float* __restrict__ feats) {
  __shared__ float ys[8 * HHd];
  __shared__ float mrow[8], rrow[8];
  const int row0 = blockIdx.x * 8;
  const int tid = threadIdx.x;
  for (int i = tid; i < 8 * HHd; i += 256) ys[i] = b2f(Yb[(long)row0 * HHd + i]);
  __syncthreads();
  {
    int rr = tid >> 5, c = tid & 31;
    float s = 0.f;
    for (int k = c; k < HHd; k += 32) s += ys[rr * HHd + k];
#pragma unroll
    for (int o = 16; o; o >>= 1) s += __shfl_xor(s, o, 32);
    float mean = s * (1.f / HHd);
    float q = 0.f;
    for (int k = c; k < HHd; k += 32) { float d = ys[rr * HHd + k] - mean; q += d * d; }
#pragma unroll
    for (int o = 16; o; o >>= 1) q += __shfl_xor(q, o, 32);
    float rs = rsqrtf(q * (1.f / HHd) + 1e-5f);
    if (c == 0) { mrow[rr] = mean; rrow[rr] = rs; }
  }
  __syncthreads();
  for (int i = tid; i < 8 * HHd; i += 256) {
    int rw = i >> 9, col = i & 511;
    ys[i] = (ys[i] - mrow[rw]) * rrow[rw] * w[col] + b[col];
  }
  __syncthreads();
  const int n = tid & 31, r = tid >> 5;
  float acc = bias[n];
  const float* yr = &ys[r * HHd];
  for (int k = 0; k < HHd; ++k) acc = fmaf(yr[k], W[k * TTd + n], acc);
  feats[(long)(row0 + r) * TTd + n] = acc;
}

// ============================== Parallel Viterbi (hierarchical max-plus scan) ==============================
__global__ __launch_bounds__(256) void vit_p1(const float* __restrict__ feats,
                                              const float* __restrict__ trans,
                                              float* __restrict__ Mc) {
  __shared__ float trS[1024];
  __shared__ float fS[VW * 32];
  __shared__ float Ga[32 * 33], Gb[32 * 33];
  const int c = blockIdx.x, tid = threadIdx.x;
  for (int i = tid; i < 1024; i += 256) trS[i] = trans[i];
  for (int i = tid; i < VW * 32; i += 256) fS[i] = feats[c * VW * 32 + i];
  __syncthreads();
  for (int i = tid; i < 1024; i += 256) {
    int n = i >> 5, q = i & 31;
    Ga[n * 33 + q] = trS[i] + fS[n];
  }
  __syncthreads();
  float* G = Ga;
  float* Gn = Gb;
  const int q = tid & 31, nb = (tid >> 5) * 4;
  for (int s = 1; s < VW; ++s) {
    float m0 = -3.0e38f, m1 = -3.0e38f, m2 = -3.0e38f, m3 = -3.0e38f;
    for (int pp = 0; pp < 32; ++pp) {
      float g = G[pp * 33 + q];
      m0 = fmaxf(m0, trS[(nb + 0) * 32 + pp] + g);
      m1 = fmaxf(m1, trS[(nb + 1) * 32 + pp] + g);
      m2 = fmaxf(m2, trS[(nb + 2) * 32 + pp] + g);
      m3 = fmaxf(m3, trS[(nb + 3) * 32 + pp] + g);
    }
    Gn[(nb + 0) * 33 + q] = m0 + fS[s * 32 + nb + 0];
    Gn[(nb + 1) * 33 + q] = m1 + fS[s * 32 + nb + 1];
    Gn[(nb + 2) * 33 + q] = m2 + fS[s * 32 + nb + 2];
    Gn[(nb + 3) * 33 + q] = m3 + fS[s * 32 + nb + 3];
    __syncthreads();
    float* t = G; G = Gn; Gn = t;
  }
  for (int i = tid; i < 1024; i += 256) Mc[c * 1024 + i] = G[(i >> 5) * 33 + (i & 31)];
}

__global__ __launch_bounds__(256) void vit_p1b(const float* __restrict__ Mf, float* __restrict__ Mcrs) {
  __shared__ float Ga[32 * 33], Gb[32 * 33], Ms[1024];
  const int c = blockIdx.x, tid = threadIdx.x;
  for (int i = tid; i < 1024; i += 256) Ga[(i >> 5) * 33 + (i & 31)] = Mf[(4 * c) * 1024 + i];
  float* G = Ga;
  float* Gn = Gb;
  const int q = tid & 31, nb = (tid >> 5) * 4;
  for (int j = 1; j < 4; ++j) {
    for (int i = tid; i < 1024; i += 256) Ms[i] = Mf[(4 * c + j) * 1024 + i];
    __syncthreads();
    float m0 = -3.0e38f, m1 = -3.0e38f, m2 = -3.0e38f, m3 = -3.0e38f;
    for (int pp = 0; pp < 32; ++pp) {
      float g = G[pp * 33 + q];
      m0 = fmaxf(m0, Ms[(nb + 0) * 32 + pp] + g);
      m1 = fmaxf(m1, Ms[(nb + 1) * 32 + pp] + g);
      m2 = fmaxf(m2, Ms[(nb + 2) * 32 + pp] + g);
      m3 = fmaxf(m3, Ms[(nb + 3) * 32 + pp] + g);
    }
    Gn[(nb + 0) * 33 + q] = m0;
    Gn[(nb + 1) * 33 + q] = m1;
    Gn[(nb + 2) * 33 + q] = m2;
    Gn[(nb + 3) * 33 + q] = m3;
    __syncthreads();
    float* t = G; G = Gn; Gn = t;
  }
  for (int i = tid; i < 1024; i += 256) Mcrs[c * 1024 + i] = G[(i >> 5) * 33 + (i & 31)];
}

__device__ __forceinline__ float vstep(float fv, int p0, const f32x4& M0, const f32x4& M1,
                                       const f32x4& M2, const f32x4& M3) {
  float mv[16];
#pragma unroll
  for (int j = 0; j < 4; ++j) { mv[j] = M0[j]; mv[4 + j] = M1[j]; mv[8 + j] = M2[j]; mv[12 + j] = M3[j]; }
  float cnd[16];
#pragma unroll
  for (int j = 0; j < 16; ++j) cnd[j] = __shfl(fv, p0 + j) + mv[j];
  float t8[8], t4[4];
#pragma unroll
  for (int j = 0; j < 8; ++j) t8[j] = fmaxf(cnd[2 * j], cnd[2 * j + 1]);
#pragma unroll
  for (int j = 0; j < 4; ++j) t4[j] = fmaxf(t8[2 * j], t8[2 * j + 1]);
  float bv = fmaxf(fmaxf(t4[0], t4[1]), fmaxf(t4[2], t4[3]));
  return fmaxf(bv, __shfl_xor(bv, 32));
}

__global__ __launch_bounds__(64) void vit_p2(const float* __restrict__ Mcrs,
                                             const float* __restrict__ trans,
                                             float* __restrict__ bfvF,
                                             float* __restrict__ term,
                                             float* __restrict__ out) {
  const int lane = threadIdx.x, n = lane & 31, h = lane >> 5, p0 = h << 4;
  float fv = (n == 30) ? 0.f : -10000.f;
  if (lane < 32) bfvF[n] = fv;
  const float* base = Mcrs + n * 32 + p0;
  f32x4 A0, A1, A2, A3, B0, B1, B2, B3, C0, C1, C2, C3;
#define LDM(d0, d1, d2, d3, c) { const float* M = base + (c) * 1024; \
  d0 = *(const f32x4*)M; d1 = *(const f32x4*)(M + 4); d2 = *(const f32x4*)(M + 8); d3 = *(const f32x4*)(M + 12); }
  LDM(A0, A1, A2, A3, 0) LDM(B0, B1, B2, B3, 1) LDM(C0, C1, C2, C3, 2)
#pragma unroll 1
  for (int c = 0; c < 30; c += 3) {
    fv = vstep(fv, p0, A0, A1, A2, A3); if (lane < 32) bfvF[(4 * (c + 1)) * 32 + n] = fv;
    { int cl = (c + 3) & 31; LDM(A0, A1, A2, A3, cl) }
    fv = vstep(fv, p0, B0, B1, B2, B3); if (lane < 32) bfvF[(4 * (c + 2)) * 32 + n] = fv;
    { int cl = (c + 4) & 31; LDM(B0, B1, B2, B3, cl) }
    fv = vstep(fv, p0, C0, C1, C2, C3); if (lane < 32) bfvF[(4 * (c + 3)) * 32 + n] = fv;
    { int cl = (c + 5) & 31; LDM(C0, C1, C2, C3, cl) }
  }
  fv = vstep(fv, p0, A0, A1, A2, A3); if (lane < 32) bfvF[(4 * 31) * 32 + n] = fv;
  fv = vstep(fv, p0, B0, B1, B2, B3); if (lane < 32) bfvF[(4 * 32) * 32 + n] = fv;
#undef LDM
  float v = fv + trans[31 * 32 + n];
  int idx = n;
#pragma unroll
  for (int o = 16; o; o >>= 1) {
    float ov = __shfl_xor(v, o);
    int oi = __shfl_xor(idx, o);
    if (ov > v || (ov == v && oi < idx)) { v = ov; idx = oi; }
  }
  if (lane == 0) { out[0] = v; term[0] = (float)idx; }
}

__global__ __launch_bounds__(64) void vit_p2b(const float* __restrict__ Mf, float* __restrict__ bfvF) {
  const int c = blockIdx.x, lane = threadIdx.x, n = lane & 31, h = lane >> 5, p0 = h << 4;
  float fv = bfvF[(4 * c) * 32 + n];
  const float* base = Mf + (size_t)(4 * c) * 1024 + n * 32 + p0;
#pragma unroll
  for (int j = 0; j < 3; ++j) {
    const float* M = base + j * 1024;
    f32x4 A0 = *(const f32x4*)M, A1 = *(const f32x4*)(M + 4);
    f32x4 A2 = *(const f32x4*)(M + 8), A3 = *(const f32x4*)(M + 12);
    fv = vstep(fv, p0, A0, A1, A2, A3);
    if (lane < 32) bfvF[(4 * c + j + 1) * 32 + n] = fv;
  }
}

__global__ __launch_bounds__(64) void vit_p3(const float* __restrict__ feats,
                                             const float* __restrict__ trans,
                                             const float* __restrict__ bfvF,
                                             unsigned char* __restrict__ bp) {
  const int c = blockIdx.x, lane = threadIdx.x, n = lane & 31, h = lane >> 5, p0 = h << 4;
  float tr[16];
#pragma unroll
  for (int j = 0; j < 16; ++j) tr[j] = trans[n * 32 + p0 + j];
  float fv = bfvF[c * 32 + n];
  float ft[VW];
  for (int s = 0; s < VW; ++s) ft[s] = feats[(c * VW + s) * 32 + n];
  for (int s = 0; s < VW; ++s) {
    float cd[16];
#pragma unroll
    for (int j = 0; j < 16; ++j) cd[j] = __shfl(fv, p0 + j) + tr[j];
    float v8[8]; int i8a[8];
#pragma unroll
    for (int j = 0; j < 8; ++j) {
      bool g = cd[2 * j + 1] > cd[2 * j];
      v8[j] = g ? cd[2 * j + 1] : cd[2 * j];
      i8a[j] = g ? 2 * j + 1 : 2 * j;
    }
    float v4[4]; int i4a[4];
#pragma unroll
    for (int j = 0; j < 4; ++j) {
      bool g = v8[2 * j + 1] > v8[2 * j];
      v4[j] = g ? v8[2 * j + 1] : v8[2 * j];
      i4a[j] = g ? i8a[2 * j + 1] : i8a[2 * j];
    }
    float v2[2]; int i2a[2];
#pragma unroll
    for (int j = 0; j < 2; ++j) {
      bool g = v4[2 * j + 1] > v4[2 * j];
      v2[j] = g ? v4[2 * j + 1] : v4[2 * j];
      i2a[j] = g ? i4a[2 * j + 1] : i4a[2 * j];
    }
    bool g1 = v2[1] > v2[0];
    float bv = g1 ? v2[1] : v2[0];
    int bi = p0 + (g1 ? i2a[1] : i2a[0]);
    float ov = __shfl_xor(bv, 32);
    int oi = __shfl_xor(bi, 32);
    bool takeo = h ? (ov >= bv) : (ov > bv);
    float m = takeo ? ov : bv;
    int mi = takeo ? oi : bi;
    if (!h) bp[(c * VW + s) * 32 + n] = (unsigned char)mi;
    fv = m + ft[s];
  }
}

__global__ __launch_bounds__(VC) void vit_p4(const unsigned char* __restrict__ bp,
                                             const float* __restrict__ term,
                                             float* __restrict__ out) {
  __shared__ unsigned char GsL[VC * 32];
  __shared__ unsigned char bnd[VC];
  const int lane = threadIdx.x;
  unsigned char g[32];
#pragma unroll
  for (int j = 0; j < 32; ++j) g[j] = (unsigned char)j;
  for (int s = VW - 1; s >= 0; --s) {
    const unsigned char* rowp = bp + (lane * VW + s) * 32;
#pragma unroll
    for (int j = 0; j < 32; ++j) g[j] = rowp[g[j]];
  }
#pragma unroll
  for (int j = 0; j < 32; ++j) GsL[lane * 32 + j] = g[j];
  __syncthreads();
  if (lane == 0) {
    bnd[VC - 1] = (unsigned char)(int)term[0];
    for (int cc = VC - 1; cc >= 1; --cc) bnd[cc - 1] = GsL[cc * 32 + bnd[cc]];
  }
  __syncthreads();
  int x = bnd[lane];
  out[1 + lane * VW + VW - 1] = (float)x;
  for (int k = VW - 2; k >= 0; --k) {
    x = bp[(lane * VW + k + 1) * 32 + x];
    out[1 + lane * VW + k] = (float)x;
  }
}

// ------------------------------ host ------------------------------
extern "C" void kernel_launch(void* const* d_in, const int* in_sizes, int n_in,
                              void* d_out, int out_size, void* d_ws, size_t ws_size,
                              hipStream_t stream) {
  (void)in_sizes; (void)n_in; (void)out_size; (void)ws_size;
  const int H = HHd, F = FFd, S = SS, L = LLd;
  const long HH2 = (long)H * H;
  const long SH = (long)S * H;
  const long HF = (long)H * F;

  hipFuncSetAttribute(reinterpret_cast<const void*>(fsa_k),
                      hipFuncAttributeMaxDynamicSharedMemorySize, FSA_SMEM);

  const int*   sent = (const int*)d_in[0];
  const float* embd = (const float*)d_in[1];
  const float* eaw  = (const float*)d_in[2];
  const float* eab  = (const float*)d_in[3];
  const float* ew1  = (const float*)d_in[4];
  const float* eb1  = (const float*)d_in[5];
  const float* ew2  = (const float*)d_in[6];
  const float* eb2  = (const float*)d_in[7];
  const float* elnw = (const float*)d_in[8];
  const float* elnb = (const float*)d_in[9];
  const float* daw  = (const float*)d_in[10];
  const float* dab  = (const float*)d_in[11];
  const float* dw1  = (const float*)d_in[12];
  const float* db1  = (const float*)d_in[13];
  const float* dw2  = (const float*)d_in[14];
  const float* db2  = (const float*)d_in[15];
  const float* dlnw = (const float*)d_in[16];
  const float* dlnb = (const float*)d_in[17];
  const float* enw  = (const float*)d_in[18];
  const float* enb  = (const float*)d_in[19];
  const float* dnw  = (const float*)d_in[20];
  const float* dnb  = (const float*)d_in[21];
  const float* h2tw = (const float*)d_in[22];
  const float* h2tb = (const float*)d_in[23];
  const float* trns = (const float*)d_in[24];

  char* p = (char*)d_ws;
  auto alloc = [&](size_t bytes) -> char* {
    char* r = p;
    p += (bytes + 255) & ~(size_t)255;
    return r;
  };
  short* wEAT = (short*)alloc((size_t)L * 4 * HH2 * 2);
  short* wDAT = (short*)alloc((size_t)L * 8 * HH2 * 2);
  short* wE1T = (short*)alloc((size_t)L * HF * 2);
  short* wE2T = (short*)alloc((size_t)L * HF * 2);
  short* wD1T = (short*)alloc((size_t)L * HF * 2);
  short* wD2T = (short*)alloc((size_t)L * HF * 2);
  short* h_b  = (short*)alloc(SH * 2);
  short* y_b  = (short*)alloc(SH * 2);
  short* qkvb = (short*)alloc(4 * SH * 2);           // Q, K, V''-slot, crossQ
  float* scf  = (float*)alloc((size_t)8 * SH * 4);   // partial buffer (16x bf16 splits = 32MB; f32 alias prologue)
  float* Zp   = (float*)alloc((size_t)16 * S * 4);   // per-split Z row sums (self 8 + cross 8)
  short* ff1b = (short*)alloc((size_t)S * F * 2);
  short* memb = (short*)alloc(SH * 2);
  short* ckvA = (short*)alloc((size_t)2 * L * SH * 2);  // interleaved cross K (even slots; odd unused)
  short* cvT  = (short*)alloc((size_t)L * SH * 2);      // cross V''^T per layer (direct from GEMM)
  float* biasE = (float*)alloc((size_t)L * 4 * H * 4);  // eab with j=2 zeroed
  float* biasD = (float*)alloc((size_t)L * 8 * H * 4);  // dab with j=2,6 zeroed; j=3 <- dab j=4
  float* bvoAll = (float*)alloc((size_t)18 * H * 4);    // folded V/out biases
  float* bvoPart = (float*)alloc((size_t)18 * 16 * H * 4); // bvo partials
  float* ftsf = (float*)alloc((size_t)S * TTd * 4);
  float* McB  = (float*)alloc((size_t)VC * 1024 * 4);
  float* McrsB= (float*)alloc((size_t)(VC / 4) * 1024 * 4);
  float* bfvF = (float*)alloc((size_t)(VC + 1) * 32 * 4);
  float* termB= (float*)alloc(64);
  unsigned char* bpgB = (unsigned char*)alloc((size_t)2048 * 32);

  short* vtb = ff1b;                  // V''^T scratch aliases ff1b (disjoint lifetimes)
  short* sparts = (short*)scf;        // bf16 split partials (self: 8 x SH shorts)
  short* sparts2 = sparts + 8 * SH;   // bf16 split partials (cross: 8 x SH shorts)
  float* Zp2 = Zp + 8 * S;
  short* wvPe  = (short*)scf;         // plain bf16 Wv copies alias scf (prologue only)
  short* wvPds = wvPe + L * HH2;
  short* wvPdc = wvPds + L * HH2;

  const int ZBIG = 1 << 20;

  // ---- weight conversion (merged launches) ----
  tconv2_k<<<dim3(16, 16, L * 12), 256, 0, stream>>>(eaw, wEAT, daw, wDAT, H, H, L * 4);
  tconv2_k<<<dim3(64, 16, 2 * L), 256, 0, stream>>>(ew1, wE1T, dw1, wD1T, H, F, L);
  tconv2_k<<<dim3(16, 64, 2 * L), 256, 0, stream>>>(ew2, wE2T, dw2, wD2T, F, H, L);
  // plain bf16 copies of Wv (enc j2, dec-self j2, dec-cross j6) in one launch
  pconv3_k<<<dim3(256, 1, 3 * L), 256, 0, stream>>>(
      eaw + 2 * HH2, wvPe, 4 * HH2,
      daw + 2 * HH2, wvPds, 8 * HH2,
      daw + 6 * HH2, wvPdc, 8 * HH2, HH2);
  // compose Wvo^T = Wout^T @ Wv^T into the V-weight slots (in place)
  auto G_cmp = gemm3<128, 64, false, false, false, false, true, false>;
  G_cmp<<<dim3(8, 4, L), 256, 0, stream>>>(
      wEAT + 3 * HH2, wvPe, nullptr, nullptr, nullptr, wEAT + 2 * HH2,
      H, H, H, H, H, 0, 1.f, 1, 4 * HH2, HH2, 0, 0, 0, 4 * HH2,
      nullptr, 0, 1, -1);
  G_cmp<<<dim3(8, 4, L), 256, 0, stream>>>(
      wDAT + 3 * HH2, wvPds, nullptr, nullptr, nullptr, wDAT + 2 * HH2,
      H, H, H, H, H, 0, 1.f, 1, 8 * HH2, HH2, 0, 0, 0, 8 * HH2,
      nullptr, 0, 1, -1);
  G_cmp<<<dim3(8, 4, L), 256, 0, stream>>>(
      wDAT + 7 * HH2, wvPdc, nullptr, nullptr, nullptr, wDAT + 6 * HH2,
      H, H, H, H, H, 0, 1.f, 1, 8 * HH2, HH2, 0, 0, 0, 8 * HH2,
      nullptr, 0, 1, -1);
  // dec-self Wout^T slot (j=3) is free after compose: move crossQ W^T (j=4) into it
  scpy_k<<<dim3(256, 1, L), 256, 0, stream>>>(wDAT + 4 * HH2, wDAT + 3 * HH2, 8 * HH2, 8 * HH2);
  // bias tables with V slots zeroed; folded biases
  zbias_k<<<dim3((L * 4 * H + 255) / 256), 256, 0, stream>>>(eab, biasE, 4, 1u << 2, L * 4 * H);
  zbias_k<<<dim3((L * 8 * H + 255) / 256), 256, 0, stream>>>(dab, biasD, 8, (1u << 2) | (1u << 6), L * 8 * H);
  bcpy_k<<<dim3(L * H / 256), 256, 0, stream>>>(dab, biasD);
  bvoP_k<<<dim3(18, 16), 256, 0, stream>>>(eaw, eab, daw, dab, bvoPart);
  bvoR_k<<<dim3(18), 256, 0, stream>>>(bvoPart, eab, dab, bvoAll);

  gather_k<<<dim3((unsigned)(SH / 256)), 256, 0, stream>>>(sent, embd, h_b, y_b);

  // gemm variants
  auto G_qkv = gemm3<128, 64, true, false, false, false, true, true>;   // batched proj; z==2 -> V''^T direct
  auto G_spl = gemm3<128, 64, false, false, false, false, true, false>; // split-K partials -> bf16
  auto G_ff1 = gemm3<128, 64, true, true, false, false, true, false>;   // bias+relu -> bf16

  dim3 gQKVe(8, 16, 3), gQKVd(8, 16, 4), gSPL(8, 16, 4), gFF1(32, 16, 1);
  dim3 gFSA(8, 32, 1), gFSA2(8, 32, 2);

  // ---------------- encoder ----------------
  for (int i = 0; i < L; ++i) {
    G_qkv<<<gQKVe, 256, 0, stream>>>(
        h_b, wEAT + (size_t)i * 4 * HH2, biasE + (size_t)i * 4 * H, nullptr, nullptr, qkvb,
        S, H, H, H, H, 0, 1.f, ZBIG, 0, 0, HH2, 0, H, SH,
        vtb, 0, 3, 2);
    fsa_k<<<gFSA, 512, FSA_SMEM, stream>>>(qkvb, qkvb + SH, vtb, sparts, Zp,
                                           qkvb, qkvb + SH, vtb, sparts, Zp);
    r4zrln_k<<<dim3(S), 256, 0, stream>>>(sparts, Zp, bvoAll + (size_t)i * H, h_b,
        elnw + (size_t)(i * 2) * H, elnb + (size_t)(i * 2) * H, h_b);
    G_ff1<<<gFF1, 256, 0, stream>>>(
        h_b, wE1T + (size_t)i * HF, eb1 + (size_t)i * F, nullptr, nullptr, ff1b,
        S, F, H, H, H, 0, 1.f, 1, 0, 0, 0, 0, 0, 0,
        nullptr, 0, 1, -1);
    G_spl<<<gSPL, 256, 0, stream>>>(
        ff1b, wE2T + (size_t)i * HF, nullptr, nullptr, nullptr, sparts,
        S, H, F / 4, F, F, F / 4, 1.f, 1, 0, 0, 0, 0, 0, SH,
        nullptr, 0, 1, -1);
    r4rln_k<<<dim3(S), 256, 0, stream>>>(sparts, eb2 + (size_t)i * H, h_b,
        elnw + (size_t)(i * 2 + 1) * H, elnb + (size_t)(i * 2 + 1) * H, h_b);
  }
  lnb_k<<<dim3(S), 256, 0, stream>>>(h_b, enw, enb, nullptr, memb);

  // cross K (j=5, even z) and composed V''^T (j=6, odd z -> direct transposed to cvT)
  G_qkv<<<dim3(8, 16, 2 * L), 256, 0, stream>>>(
      memb, wDAT + 5 * HH2, biasD + 5 * H, nullptr, nullptr, ckvA,
      S, H, H, H, H, 0, 1.f, 2, 0, 8 * HH2, HH2, 8 * H, H, SH,
      cvT, SH, 2, 1);

  // ---------------- decoder ----------------
  for (int i = 0; i < L; ++i) {
    // z=4 batch: Q, K, V''(->vtb transposed), crossQ (slot 3 holds crossQ weights/bias)
    G_qkv<<<gQKVd, 256, 0, stream>>>(
        y_b, wDAT + (size_t)i * 8 * HH2, biasD + (size_t)i * 8 * H, nullptr, nullptr, qkvb,
        S, H, H, H, H, 0, 1.f, ZBIG, 0, 0, HH2, 0, H, SH,
        vtb, 0, 4, 2);
    // dual-issue: self attention (set 0) + cross attention (set 1) in one launch
    fsa_k<<<gFSA2, 512, FSA_SMEM, stream>>>(
        qkvb, qkvb + SH, vtb, sparts, Zp,
        qkvb + 3 * SH, ckvA + (size_t)(2 * i) * SH, cvT + (size_t)i * SH, sparts2, Zp2);
    // fused self + cross tails (y1 kept in registers)
    r4zrln2_k<<<dim3(S), 256, 0, stream>>>(
        sparts, Zp, bvoAll + (size_t)(6 + i) * H,
        sparts2, Zp2, bvoAll + (size_t)(12 + i) * H,
        dlnw + (size_t)(i * 3) * H, dlnb + (size_t)(i * 3) * H,
        dlnw + (size_t)(i * 3 + 1) * H, dlnb + (size_t)(i * 3 + 1) * H,
        y_b);
    // FFN
    G_ff1<<<gFF1, 256, 0, stream>>>(
        y_b, wD1T + (size_t)i * HF, db1 + (size_t)i * F, nullptr, nullptr, ff1b,
        S, F, H, H, H, 0, 1.f, 1, 0, 0, 0, 0, 0, 0,
        nullptr, 0, 1, -1);
    G_spl<<<gSPL, 256, 0, stream>>>(
        ff1b, wD2T + (size_t)i * HF, nullptr, nullptr, nullptr, sparts,
        S, H, F / 4, F, F, F / 4, 1.f, 1, 0, 0, 0, 0, 0, SH,
        nullptr, 0, 1, -1);
    r4rln_k<<<dim3(S), 256, 0, stream>>>(sparts, db2 + (size_t)i * H, y_b,
        dlnw + (size_t)(i * 3 + 2) * H, dlnb + (size_t)(i * 3 + 2) * H, y_b);
  }
  // fused final LN + feats + hierarchical parallel viterbi
  featsln_k<<<dim3(S / 8), 256, 0, stream>>>(y_b, dnw, dnb, h2tw, h2tb, ftsf);
  float* outF = (float*)d_out;
  vit_p1<<<dim3(VC), 256, 0, stream>>>(ftsf, trns, McB);
  vit_p1b<<<dim3(VC / 4), 256, 0, stream>>>(McB, McrsB);
  vit_p2<<<dim3(1), 64, 0, stream>>>(McrsB, trns, bfvF, termB, outF);
  vit_p2b<<<dim3(VC / 4), 64, 0, stream>>>(McB, bfvF);
  vit_p3<<<dim3(VC), 64, 0, stream>>>(ftsf, trns, bfvF, bpgB);
  vit_p4<<<dim3(1), VC, 0, stream>>>(bpgB, termB, outF);
}

// Round 29
// 1111.107 us; speedup vs baseline: 1.1858x; 1.0675x over previous
//
#include <hip/hip_runtime.h>
#include <cstdint>

#define SS 2048
#define HHd 512
#define FFd 2048
#define TTd 32
#define LLd 6
#define VW 16
#define VC 128

typedef float f32x4 __attribute__((ext_vector_type(4)));
typedef __bf16 bf16x8 __attribute__((ext_vector_type(8)));
typedef short short8v __attribute__((ext_vector_type(8)));
typedef short short4v __attribute__((ext_vector_type(4)));

__device__ __forceinline__ short f2b(float f) {
  unsigned u = __builtin_bit_cast(unsigned, f);
  u += 0x7fffu + ((u >> 16) & 1u);
  return (short)(u >> 16);
}
__device__ __forceinline__ float b2f(short s) {
  unsigned u = ((unsigned)(unsigned short)s) << 16;
  return __builtin_bit_cast(float, u);
}

typedef const __attribute__((address_space(1))) void gv_t;
typedef __attribute__((address_space(3))) void lv_t;
__device__ __forceinline__ void gload16(const void* g, void* l) {
  __builtin_amdgcn_global_load_lds((gv_t*)g, (lv_t*)l, 16, 0, 0);
}

// ------------------------------ GEMM (all-TB, BK=64, swizzled LDS, double-buffered 2-phase) ------------------------------
template<int BMt, int BNt, bool BIAS, bool RELU, bool RESID, bool OUTF, bool OUTB, bool TRBE>
__global__ __launch_bounds__(256) void gemm3(
    const short* __restrict__ A, const short* __restrict__ Bb,
    const float* __restrict__ biasb, const float* __restrict__ resid,
    float* __restrict__ Cfb, short* __restrict__ Cbb,
    int M, int N, int K, int lda, int ldb, int kzS, float scale,
    int zdiv, long as1, long bs1, long bs2, int bb1, int bb2, long cStr,
    short* __restrict__ CbT, long ctStr, int tmod, int tval)
{
  constexpr int MR = BMt / 32, NR = BNt / 32;
  constexpr int WMt = BMt / 2, WNt = BNt / 2;
  constexpr int ACALLS = BMt / 8;
  constexpr int TOT = (BMt + BNt) / 8;
  constexpr int CPW = TOT / 4;
  constexpr int HALF = BMt * 64 + BNt * 64;

  const int z = blockIdx.z;
  const short* Ap = A + (long)z * as1;
  const short* Bp = Bb + (long)(z / zdiv) * bs1 + (long)(z % zdiv) * bs2;
  const float* bias = BIAS ? (biasb + (z / zdiv) * bb1 + (z % zdiv) * bb2) : nullptr;
  const int kz = z * kzS;

  const int m0 = blockIdx.y * BMt;
  const int n0 = blockIdx.x * BNt;

  __shared__ __align__(16) short LDSbuf[2 * HALF];

  const int tid = threadIdx.x;
  const int lane = tid & 63;
  const int w = tid >> 6;

  const short* srcs[CPW];
  int loff[CPW];
  {
    const int rl8 = lane >> 3;
    const int c16 = (lane & 7) ^ rl8;
#pragma unroll
    for (int c = 0; c < CPW; ++c) {
      int q = w * CPW + c;
      if (q < ACALLS) {
        int row = q * 8 + rl8;
        srcs[c] = Ap + (long)(m0 + row) * lda + kz + c16 * 8;
        loff[c] = q * 512;
      } else {
        int row = (q - ACALLS) * 8 + rl8;
        srcs[c] = Bp + (long)(n0 + row) * ldb + kz + c16 * 8;
        loff[c] = BMt * 64 + (q - ACALLS) * 512;
      }
    }
  }

  const int lrow = lane & 15;
  const int slotb = lane >> 4;
  const int wm = (w >> 1) * WMt, wn = (w & 1) * WNt;

  f32x4 acc[MR][NR] = {};

  // prologue: stage tile 0 into buffer 0
#pragma unroll
  for (int c = 0; c < CPW; ++c) gload16(srcs[c], LDSbuf + loff[c]);
#pragma unroll
  for (int c = 0; c < CPW; ++c) srcs[c] += 64;
  __syncthreads();

  const int NIT = K >> 6;
  for (int it = 0; it < NIT; ++it) {
    const int cur = it & 1;
    if (it + 1 < NIT) {
      const int nxt = (cur ^ 1) * HALF;
#pragma unroll
      for (int c = 0; c < CPW; ++c) gload16(srcs[c], LDSbuf + nxt + loff[c]);
#pragma unroll
      for (int c = 0; c < CPW; ++c) srcs[c] += 64;
    }
    const short* As = LDSbuf + cur * HALF;
    const short* Bs = As + BMt * 64;
#pragma unroll
    for (int s = 0; s < 2; ++s) {
      bf16x8 af[MR], bfv[NR];
#pragma unroll
      for (int f = 0; f < MR; ++f) {
        int row = wm + f * 16 + lrow;
        int phys = (slotb + s * 4) ^ (row & 7);
        af[f] = *(const bf16x8*)&As[row * 64 + phys * 8];
      }
#pragma unroll
      for (int f = 0; f < NR; ++f) {
        int row = wn + f * 16 + lrow;
        int phys = (slotb + s * 4) ^ (row & 7);
        bfv[f] = *(const bf16x8*)&Bs[row * 64 + phys * 8];
      }
#pragma unroll
      for (int i = 0; i < MR; ++i)
#pragma unroll
        for (int j = 0; j < NR; ++j)
          acc[i][j] = __builtin_amdgcn_mfma_f32_16x16x32_bf16(af[i], bfv[j], acc[i][j], 0, 0, 0);
    }
    __syncthreads();   // drains L(it+1); frees buf[cur]
  }

  const int crow = (lane >> 4) * 4;
  const int ccol = lane & 15;
  const bool dotr = TRBE && ((z % tmod) == tval);

  if (OUTB) {
    if (dotr) {
      short* Cb = CbT + (long)(z / zdiv) * ctStr;
      constexpr int LDSW = BMt + 8;
      short* Os = LDSbuf;
#pragma unroll
      for (int i = 0; i < MR; ++i) {
#pragma unroll
        for (int j = 0; j < NR; ++j) {
          int lc = wn + j * 16 + ccol;
          float bv = BIAS ? bias[n0 + lc] : 0.f;
#pragma unroll
          for (int r = 0; r < 4; ++r) {
            int lr = wm + i * 16 + crow + r;
            Os[lc * LDSW + lr] = f2b(acc[i][j][r] * scale + bv);
          }
        }
      }
      __syncthreads();
      constexpr int CPR = BMt / 8;
      constexpr int CPT = (BMt * BNt / 8) / 256;
#pragma unroll
      for (int c = 0; c < CPT; ++c) {
        int idx = tid + c * 256;
        int col = idx / CPR;
        int rowc = (idx % CPR) * 8;
        int4 vv = *(const int4*)&Os[col * LDSW + rowc];
        *(int4*)&Cb[(long)(n0 + col) * M + m0 + rowc] = vv;
      }
    } else {
      short* Cb = Cbb + (long)z * cStr;
      constexpr int LDSW = BNt + 8;
      short* Os = LDSbuf;
#pragma unroll
      for (int i = 0; i < MR; ++i) {
#pragma unroll
        for (int j = 0; j < NR; ++j) {
          int lc = wn + j * 16 + ccol;
          float bv = BIAS ? bias[n0 + lc] : 0.f;
#pragma unroll
          for (int r = 0; r < 4; ++r) {
            int lr = wm + i * 16 + crow + r;
            float v = acc[i][j][r] * scale + bv;
            if (RELU) v = v > 0.f ? v : 0.f;
            Os[lr * LDSW + lc] = f2b(v);
          }
        }
      }
      __syncthreads();
      constexpr int CPR = BNt / 8;
      constexpr int CPT = (BMt * BNt / 8) / 256;
#pragma unroll
      for (int c = 0; c < CPT; ++c) {
        int idx = tid + c * 256;
        int row = idx / CPR;
        int col8 = (idx % CPR) * 8;
        int4 vv = *(const int4*)&Os[row * LDSW + col8];
        *(int4*)&Cb[(long)(m0 + row) * N + n0 + col8] = vv;
      }
    }
  } else {
    float* Cf = Cfb + (long)z * cStr;
#pragma unroll
    for (int i = 0; i < MR; ++i) {
#pragma unroll
      for (int j = 0; j < NR; ++j) {
        int gc = n0 + wn + j * 16 + ccol;
        float bv = BIAS ? bias[gc] : 0.f;
#pragma unroll
        for (int r = 0; r < 4; ++r) {
          int gr = m0 + wm + i * 16 + crow + r;
          long off = (long)gr * N + gc;
          float v = acc[i][j][r] * scale + bv;
          if (RESID) v += resid[off];
          if (RELU) v = v > 0.f ? v : 0.f;
          Cf[off] = v;
        }
      }
    }
  }
}

// ============================== Fused attention (q-tile 64, NSPLIT key splits, 8 waves, 2-phase) ==============================
// Each block covers SS/NSPLIT keys (multiple 64-key chunks, f32 accumulation across them).
// blockIdx.z selects pointer set 0/1 (dual-issue: decoder self + cross attention in one launch).
#define FSA_SMEM (64 * 512 * 2 + 512 * 64 * 2 + 64 * 64 * 2 + 128 * 4)
template<int NSPLIT>
__global__ __launch_bounds__(512) void fsa_k(
    const short* __restrict__ Q0, const short* __restrict__ K0,
    const short* __restrict__ V0, short* __restrict__ O0, float* __restrict__ Zp0,
    const short* __restrict__ Q1, const short* __restrict__ K1,
    const short* __restrict__ V1, short* __restrict__ O1, float* __restrict__ Zp1) {
  extern __shared__ __align__(16) char smem[];
  short* Ks  = (short*)smem;           // [64][512]  (Q stage / K chunk / O stage)
  short* Vts = Ks + 64 * 512;          // [512][64]
  short* Ps  = Vts + 512 * 64;         // [64][64]
  float* Zs  = (float*)(Ps + 64 * 64); // [2][64]
  const float RSQ = 0.04419417382415922f;
  constexpr int KSPAN = SS / NSPLIT;
  constexpr int NKC = KSPAN / 64;

  const int sel = blockIdx.z;
  const short* Q   = sel ? Q1 : Q0;
  const short* Kmat= sel ? K1 : K0;
  const short* VT  = sel ? V1 : V0;
  short* Op        = sel ? O1 : O0;
  float* Zp        = sel ? Zp1 : Zp0;

  const int z = blockIdx.x;            // key split (0..NSPLIT-1)
  const int q0 = blockIdx.y * 64;
  const int key0 = z * KSPAN;
  const int tid = threadIdx.x, lane = tid & 63, w = tid >> 6;
  const int qg = w >> 1;               // 0..3 q-group (16 rows each)
  const int kh = w & 1;
  const int wn = kh * 32, wn2 = kh * 256;
  const int lrow = lane & 15, lgrp = lane >> 4;

  // stage Q (64 rows)
  for (int c = 0; c < 8; ++c) {
    int row = w * 8 + c;
    const short* src = Q + (long)(q0 + row) * HHd + (lane ^ (row & 7)) * 8;
    gload16(src, &Ks[row * 512]);
  }
  __syncthreads();
  bf16x8 qf[16];
#pragma unroll
  for (int st = 0; st < 16; ++st) {
    int row = qg * 16 + lrow;
    int phys = (st * 4 + lgrp) ^ (row & 7);
    qf[st] = *(const bf16x8*)&Ks[row * 512 + phys * 8];
  }
  __syncthreads();

  // prologue: stage K(0)
  for (int c = 0; c < 8; ++c) {
    int row = w * 8 + c;
    const short* src = Kmat + (long)(key0 + row) * HHd + (lane ^ (row & 7)) * 8;
    gload16(src, &Ks[row * 512]);
  }
  __syncthreads();

  f32x4 accO[16] = {};
  float zacc[4] = {};

  for (int kc = 0; kc < NKC; ++kc) {
    // issue V(kc) — flies under QK compute
    for (int c = 0; c < 8; ++c) {
      int rb = (w * 8 + c) * 8;
      int vrow = rb + (lane >> 3);
      const short* src = VT + (long)vrow * SS + key0 + kc * 64 + ((lane & 7) ^ (vrow & 7)) * 8;
      gload16(src, &Vts[rb * 64]);
    }
    f32x4 accS0 = {}, accS1 = {};
#pragma unroll
    for (int st = 0; st < 16; ++st) {
      int row0 = wn + lrow;
      int phys0 = (st * 4 + lgrp) ^ (row0 & 7);
      bf16x8 b0 = *(const bf16x8*)&Ks[row0 * 512 + phys0 * 8];
      int row1 = wn + 16 + lrow;
      int phys1 = (st * 4 + lgrp) ^ (row1 & 7);
      bf16x8 b1 = *(const bf16x8*)&Ks[row1 * 512 + phys1 * 8];
      accS0 = __builtin_amdgcn_mfma_f32_16x16x32_bf16(qf[st], b0, accS0, 0, 0, 0);
      accS1 = __builtin_amdgcn_mfma_f32_16x16x32_bf16(qf[st], b1, accS1, 0, 0, 0);
    }
#pragma unroll
    for (int f = 0; f < 2; ++f) {
#pragma unroll
      for (int r = 0; r < 4; ++r) {
        int row = qg * 16 + lgrp * 4 + r;
        int col = wn + f * 16 + lrow;
        float sv = f ? accS1[r] : accS0[r];
        float e = __expf(sv * RSQ);
        zacc[r] += e;
        int slot = col >> 3;
        Ps[row * 64 + ((slot ^ (row & 7)) * 8) + (col & 7)] = f2b(e);
      }
    }
    __syncthreads();   // drains V(kc); P visible; Ks free (QK done)
    // issue K(kc+1) — flies under PV compute
    if (kc < NKC - 1) {
      for (int c = 0; c < 8; ++c) {
        int row = w * 8 + c;
        const short* src = Kmat + (long)(key0 + (kc + 1) * 64 + row) * HHd + (lane ^ (row & 7)) * 8;
        gload16(src, &Ks[row * 512]);
      }
    }
#pragma unroll
    for (int kk = 0; kk < 2; ++kk) {
      int prow = qg * 16 + lrow;
      int pphys = (kk * 4 + lgrp) ^ (prow & 7);
      bf16x8 pa = *(const bf16x8*)&Ps[prow * 64 + pphys * 8];
#pragma unroll
      for (int n = 0; n < 16; ++n) {
        int vrow = wn2 + n * 16 + lrow;
        int vphys = (kk * 4 + lgrp) ^ (vrow & 7);
        bf16x8 vb = *(const bf16x8*)&Vts[vrow * 64 + vphys * 8];
        accO[n] = __builtin_amdgcn_mfma_f32_16x16x32_bf16(pa, vb, accO[n], 0, 0, 0);
      }
    }
    __syncthreads();   // drains K(kc+1); Vts/Ps free for next iteration
  }

  // epilogue: stage O as bf16 into Ks (linear [64][512]) + Z shuffles
#pragma unroll
  for (int n = 0; n < 16; ++n) {
#pragma unroll
    for (int r = 0; r < 4; ++r) {
      int row = qg * 16 + lgrp * 4 + r;
      int col = wn2 + n * 16 + lrow;
      Ks[row * 512 + col] = f2b(accO[n][r]);
    }
  }
#pragma unroll
  for (int r = 0; r < 4; ++r) {
    float v = zacc[r];
    v += __shfl_xor(v, 1); v += __shfl_xor(v, 2);
    v += __shfl_xor(v, 4); v += __shfl_xor(v, 8);
    if (lrow == 0) Zs[kh * 64 + qg * 16 + lgrp * 4 + r] = v;
  }
  __syncthreads();
  short* OpZ = Op + (long)z * (long)SS * HHd + (long)q0 * HHd;
#pragma unroll
  for (int c = 0; c < 8; ++c) {
    int idx = tid + c * 512;
    *(int4*)&OpZ[idx * 8] = *(const int4*)&Ks[idx * 8];
  }
  if (tid < 64) Zp[(long)z * SS + q0 + tid] = Zs[tid] + Zs[64 + tid];
}

// ---------------- fused attention tail: (sum8 bf16-O)/Z + bvo + bf16 resid + LayerNorm -> bf16 (encoder) ----------------
__global__ __launch_bounds__(256) void r4zrln_k(const short* __restrict__ pb,
                                                const float* __restrict__ Zp,
                                                const float* __restrict__ bvo,
                                                const short* __restrict__ resid,
                                                const float* __restrict__ w, const float* __restrict__ b,
                                                short* __restrict__ Yb) {
  const long SH = (long)SS * HHd;
  const int row = blockIdx.x, tid = threadIdx.x;
  long base = (long)row * HHd;
  float zt = 0.f;
#pragma unroll
  for (int sk = 0; sk < 8; ++sk) zt += Zp[(long)sk * SS + row];
  float zi = 1.0f / zt;
  float a0 = 0.f, a1 = 0.f;
#pragma unroll
  for (int sk = 0; sk < 8; ++sk) {
    a0 += b2f(pb[sk * SH + base + tid]);
    a1 += b2f(pb[sk * SH + base + tid + 256]);
  }
  float x0 = a0 * zi + bvo[tid] + b2f(resid[base + tid]);
  float x1 = a1 * zi + bvo[tid + 256] + b2f(resid[base + tid + 256]);
  float s = x0 + x1;
#pragma unroll
  for (int o = 32; o; o >>= 1) s += __shfl_xor(s, o);
  __shared__ float r1[4], r2[4];
  if ((tid & 63) == 0) r1[tid >> 6] = s;
  __syncthreads();
  float mean = (r1[0] + r1[1] + r1[2] + r1[3]) * (1.f / HHd);
  float d0 = x0 - mean, d1 = x1 - mean;
  float q = d0 * d0 + d1 * d1;
#pragma unroll
  for (int o = 32; o; o >>= 1) q += __shfl_xor(q, o);
  if ((tid & 63) == 0) r2[tid >> 6] = q;
  __syncthreads();
  float var = (r2[0] + r2[1] + r2[2] + r2[3]) * (1.f / HHd);
  float rs = rsqrtf(var + 1e-5f);
  float o0 = d0 * rs * w[tid] + b[tid];
  float o1 = d1 * rs * w[tid + 256] + b[tid + 256];
  Yb[base + tid] = f2b(o0); Yb[base + tid + 256] = f2b(o1);
}

// ---------------- fused decoder double-tail (4 splits each): self tail then cross tail, y1 in registers ----------------
__global__ __launch_bounds__(256) void r4zrln2_k(
    const short* __restrict__ pbA, const float* __restrict__ ZpA, const float* __restrict__ bvoA,
    const short* __restrict__ pbB, const float* __restrict__ ZpB, const float* __restrict__ bvoB,
    const float* __restrict__ w1, const float* __restrict__ b1,
    const float* __restrict__ w2, const float* __restrict__ b2,
    short* __restrict__ Yb) {
  const long SH = (long)SS * HHd;
  const int row = blockIdx.x, tid = threadIdx.x;
  long base = (long)row * HHd;
  __shared__ float r1[4], r2[4], r3[4], r4[4];

  // ---- stage A: self-attention tail ----
  float zt = 0.f;
#pragma unroll
  for (int sk = 0; sk < 4; ++sk) zt += ZpA[(long)sk * SS + row];
  float zi = 1.0f / zt;
  float a0 = 0.f, a1 = 0.f;
#pragma unroll
  for (int sk = 0; sk < 4; ++sk) {
    a0 += b2f(pbA[sk * SH + base + tid]);
    a1 += b2f(pbA[sk * SH + base + tid + 256]);
  }
  float x0 = a0 * zi + bvoA[tid] + b2f(Yb[base + tid]);
  float x1 = a1 * zi + bvoA[tid + 256] + b2f(Yb[base + tid + 256]);
  float s = x0 + x1;
#pragma unroll
  for (int o = 32; o; o >>= 1) s += __shfl_xor(s, o);
  if ((tid & 63) == 0) r1[tid >> 6] = s;
  __syncthreads();
  float mean = (r1[0] + r1[1] + r1[2] + r1[3]) * (1.f / HHd);
  float d0 = x0 - mean, d1 = x1 - mean;
  float q = d0 * d0 + d1 * d1;
#pragma unroll
  for (int o = 32; o; o >>= 1) q += __shfl_xor(q, o);
  if ((tid & 63) == 0) r2[tid >> 6] = q;
  __syncthreads();
  float var = (r2[0] + r2[1] + r2[2] + r2[3]) * (1.f / HHd);
  float rs = rsqrtf(var + 1e-5f);
  // bf16-round y1 to match the previous store/reload numerics
  float y10 = b2f(f2b(d0 * rs * w1[tid] + b1[tid]));
  float y11 = b2f(f2b(d1 * rs * w1[tid + 256] + b1[tid + 256]));

  // ---- stage B: cross-attention tail (resid = y1 in registers) ----
  float zt2 = 0.f;
#pragma unroll
  for (int sk = 0; sk < 4; ++sk) zt2 += ZpB[(long)sk * SS + row];
  float zi2 = 1.0f / zt2;
  float c0 = 0.f, c1 = 0.f;
#pragma unroll
  for (int sk = 0; sk < 4; ++sk) {
    c0 += b2f(pbB[sk * SH + base + tid]);
    c1 += b2f(pbB[sk * SH + base + tid + 256]);
  }
  float u0 = c0 * zi2 + bvoB[tid] + y10;
  float u1 = c1 * zi2 + bvoB[tid + 256] + y11;
  float s2 = u0 + u1;
#pragma unroll
  for (int o = 32; o; o >>= 1) s2 += __shfl_xor(s2, o);
  if ((tid & 63) == 0) r3[tid >> 6] = s2;
  __syncthreads();
  float mean2 = (r3[0] + r3[1] + r3[2] + r3[3]) * (1.f / HHd);
  float e0 = u0 - mean2, e1 = u1 - mean2;
  float q2 = e0 * e0 + e1 * e1;
#pragma unroll
  for (int o = 32; o; o >>= 1) q2 += __shfl_xor(q2, o);
  if ((tid & 63) == 0) r4[tid >> 6] = q2;
  __syncthreads();
  float var2 = (r4[0] + r4[1] + r4[2] + r4[3]) * (1.f / HHd);
  float rs2 = rsqrtf(var2 + 1e-5f);
  float o0 = e0 * rs2 * w2[tid] + b2[tid];
  float o1 = e1 * rs2 * w2[tid + 256] + b2[tid + 256];
  Yb[base + tid] = f2b(o0); Yb[base + tid + 256] = f2b(o1);
}

// ---------------- split-K=4 bf16 reduce + bias + bf16 resid + LayerNorm -> bf16 (FFN2) ----------------
__global__ __launch_bounds__(256) void r4rln_k(const short* __restrict__ pb,
                                               const float* __restrict__ bias,
                                               const short* __restrict__ resid,
                                               const float* __restrict__ w, const float* __restrict__ b,
                                               short* __restrict__ Yb) {
  const long SH = (long)SS * HHd;
  const int row = blockIdx.x, tid = threadIdx.x;
  long base = (long)row * HHd;
  float x0 = bias[tid] + b2f(resid[base + tid]);
  float x1 = bias[tid + 256] + b2f(resid[base + tid + 256]);
#pragma unroll
  for (int sk = 0; sk < 4; ++sk) {
    x0 += b2f(pb[sk * SH + base + tid]);
    x1 += b2f(pb[sk * SH + base + tid + 256]);
  }
  float s = x0 + x1;
#pragma unroll
  for (int o = 32; o; o >>= 1) s += __shfl_xor(s, o);
  __shared__ float r1[4], r2[4];
  if ((tid & 63) == 0) r1[tid >> 6] = s;
  __syncthreads();
  float mean = (r1[0] + r1[1] + r1[2] + r1[3]) * (1.f / HHd);
  float d0 = x0 - mean, d1 = x1 - mean;
  float q = d0 * d0 + d1 * d1;
#pragma unroll
  for (int o = 32; o; o >>= 1) q += __shfl_xor(q, o);
  if ((tid & 63) == 0) r2[tid >> 6] = q;
  __syncthreads();
  float var = (r2[0] + r2[1] + r2[2] + r2[3]) * (1.f / HHd);
  float rs = rsqrtf(var + 1e-5f);
  float o0 = d0 * rs * w[tid] + b[tid];
  float o1 = d1 * rs * w[tid + 256] + b[tid + 256];
  Yb[base + tid] = f2b(o0); Yb[base + tid + 256] = f2b(o1);
}

// ---------------- LayerNorm over bf16 rows; optional f32 out + bf16 out ----------------
__global__ __launch_bounds__(256) void lnb_k(const short* __restrict__ Xb, const float* __restrict__ w,
                                             const float* __restrict__ b, float* __restrict__ Yf,
                                             short* __restrict__ Yb) {
  const int row = blockIdx.x;
  const int tid = threadIdx.x;
  long base = (long)row * HHd;
  float x0 = b2f(Xb[base + tid]), x1 = b2f(Xb[base + tid + 256]);
  float s = x0 + x1;
#pragma unroll
  for (int o = 32; o; o >>= 1) s += __shfl_xor(s, o);
  __shared__ float r1[4], r2[4];
  if ((tid & 63) == 0) r1[tid >> 6] = s;
  __syncthreads();
  float mean = (r1[0] + r1[1] + r1[2] + r1[3]) * (1.f / HHd);
  float d0 = x0 - mean, d1 = x1 - mean;
  float q = d0 * d0 + d1 * d1;
#pragma unroll
  for (int o = 32; o; o >>= 1) q += __shfl_xor(q, o);
  if ((tid & 63) == 0) r2[tid >> 6] = q;
  __syncthreads();
  float var = (r2[0] + r2[1] + r2[2] + r2[3]) * (1.f / HHd);
  float rs = rsqrtf(var + 1e-5f);
  float o0 = d0 * rs * w[tid] + b[tid];
  float o1 = d1 * rs * w[tid + 256] + b[tid + 256];
  if (Yf) { Yf[base + tid] = o0; Yf[base + tid + 256] = o1; }
  Yb[base + tid] = f2b(o0); Yb[base + tid + 256] = f2b(o1);
}

// ---------------- dual f32 [K,N] -> bf16 [N,K] transpose-convert (z-range select) ----------------
__global__ __launch_bounds__(256) void tconv2_k(const float* __restrict__ in0, short* __restrict__ out0,
                                                const float* __restrict__ in1, short* __restrict__ out1,
                                                int K, int N, int split) {
  __shared__ float t[32][33];
  int zz = blockIdx.z;
  const float* in = (zz < split) ? in0 : in1;
  short* out = (zz < split) ? out0 : out1;
  int zi = (zz < split) ? zz : zz - split;
  long zo = (long)zi * K * N;
  int n0 = blockIdx.x * 32, k0 = blockIdx.y * 32;
  int tx = threadIdx.x & 31, ty = threadIdx.x >> 5;
#pragma unroll
  for (int i = 0; i < 4; ++i)
    t[ty + i * 8][tx] = in[zo + (long)(k0 + ty + i * 8) * N + n0 + tx];
  __syncthreads();
#pragma unroll
  for (int i = 0; i < 4; ++i)
    out[zo + (long)(n0 + ty + i * 8) * K + k0 + tx] = f2b(t[tx][ty + i * 8]);
}

// ---------------- triple strided f32 -> bf16 convert (z/L selects pair) ----------------
__global__ __launch_bounds__(256) void pconv3_k(const float* __restrict__ inA, short* __restrict__ outA,
                                                long strideA,
                                                const float* __restrict__ inB, short* __restrict__ outB,
                                                long strideB,
                                                const float* __restrict__ inC, short* __restrict__ outC,
                                                long strideC, long outStride) {
  int zz = blockIdx.z;
  int grp = zz / LLd, zi = zz % LLd;
  const float* in = grp == 0 ? inA : (grp == 1 ? inB : inC);
  short* out = grp == 0 ? outA : (grp == 1 ? outB : outC);
  long inStride = grp == 0 ? strideA : (grp == 1 ? strideB : strideC);
  long i = ((long)blockIdx.x * 256 + threadIdx.x) * 4;
  const float* ip = in + (long)zi * inStride + i;
  short* op = out + (long)zi * outStride + i;
  float4 v = *(const float4*)ip;
  short4v o;
  o[0] = f2b(v.x); o[1] = f2b(v.y); o[2] = f2b(v.z); o[3] = f2b(v.w);
  *(short4v*)op = o;
}

// ---------------- bf16 strided copy (batched z) ----------------
__global__ __launch_bounds__(256) void scpy_k(const short* __restrict__ src, short* __restrict__ dst,
                                              long srcStride, long dstStride) {
  long i = ((long)blockIdx.x * 256 + threadIdx.x) * 4;
  *(short4v*)(dst + (long)blockIdx.z * dstStride + i) =
      *(const short4v*)(src + (long)blockIdx.z * srcStride + i);
}

// ---------------- bias slot copy: biasD[l*8+3] <- dab[l*8+4] ----------------
__global__ __launch_bounds__(256) void bcpy_k(const float* __restrict__ src, float* __restrict__ dst) {
  int i = blockIdx.x * 256 + threadIdx.x;  // over L*H
  int l = i >> 9, c = i & 511;
  dst[(l * 8 + 3) * HHd + c] = src[(l * 8 + 4) * HHd + c];
}

// ---------------- bias table copy with zeroed j-slots ----------------
__global__ __launch_bounds__(256) void zbias_k(const float* __restrict__ src, float* __restrict__ dst,
                                               int nj, unsigned jmask, int total) {
  int i = blockIdx.x * 256 + threadIdx.x;
  if (i >= total) return;
  int j = (i >> 9) % nj;
  dst[i] = ((jmask >> j) & 1u) ? 0.f : src[i];
}

// ---------------- bvo partials: row-major streaming (18 combos x 16 m-groups) ----------------
__global__ __launch_bounds__(256) void bvoP_k(const float* __restrict__ eaw, const float* __restrict__ eab,
                                              const float* __restrict__ daw, const float* __restrict__ dab,
                                              float* __restrict__ part) {
  const long HH2 = (long)HHd * HHd;
  const int b = blockIdx.x, mg = blockIdx.y, tid = threadIdx.x;
  const float* Wout; const float* bv;
  if (b < 6) {
    int i = b;
    Wout = eaw + (i * 4 + 3) * HH2; bv = eab + (i * 4 + 2) * HHd;
  } else if (b < 12) {
    int i = b - 6;
    Wout = daw + (i * 8 + 3) * HH2; bv = dab + (i * 8 + 2) * HHd;
  } else {
    int i = b - 12;
    Wout = daw + (i * 8 + 7) * HH2; bv = dab + (i * 8 + 6) * HHd;
  }
  float a0 = 0.f, a1 = 0.f;
#pragma unroll 4
  for (int m = mg * 32; m < mg * 32 + 32; ++m) {
    float bvm = bv[m];
    a0 = fmaf(bvm, Wout[(long)m * HHd + tid], a0);
    a1 = fmaf(bvm, Wout[(long)m * HHd + tid + 256], a1);
  }
  long o = ((long)b * 16 + mg) * HHd;
  part[o + tid] = a0;
  part[o + tid + 256] = a1;
}

// ---------------- bvo reduce: sum 16 partials + bout ----------------
__global__ __launch_bounds__(256) void bvoR_k(const float* __restrict__ part,
                                              const float* __restrict__ eab, const float* __restrict__ dab,
                                              float* __restrict__ bvoAll) {
  const int b = blockIdx.x, tid = threadIdx.x;
  const float* bout;
  if (b < 6) bout = eab + (b * 4 + 3) * HHd;
  else if (b < 12) bout = dab + ((b - 6) * 8 + 3) * HHd;
  else bout = dab + ((b - 12) * 8 + 7) * HHd;
  float s0 = bout[tid], s1 = bout[tid + 256];
#pragma unroll
  for (int mg = 0; mg < 16; ++mg) {
    long o = ((long)b * 16 + mg) * HHd;
    s0 += part[o + tid];
    s1 += part[o + tid + 256];
  }
  bvoAll[(long)b * HHd + tid] = s0;
  bvoAll[(long)b * HHd + tid + 256] = s1;
}

// ------------------------------ embedding gather (bf16 only) ------------------------------
__global__ __launch_bounds__(256) void gather_k(const int* __restrict__ sent, const float* __restrict__ emb,
                                                short* __restrict__ hb, short* __restrict__ yb) {
  long i = (long)blockIdx.x * 256 + threadIdx.x;
  int s = (int)(i >> 9);
  int hcol = (int)(i & 511);
  float v = emb[(long)sent[s] * HHd + hcol];
  short bb = f2b(v);
  hb[i] = bb; yb[i] = bb;
}

// ------------------------------ fused final LN + feats: LN(y_b) @ [HHd,TTd] + b (f32) ------------------------------
__global__ __launch_bounds__(256) void featsln_k(const short* __restrict__ Yb,
                                                 const float* __restrict__ w, const float* __restrict__ b,
                                                 const float* __restrict__ W, const float* __restrict__ bias,
                                                 float* __restrict__ feats) {
  __shared__ float ys[8 * HHd];
  __shared__ float mrow[8], rrow[8];
  const int row0 = blockIdx.x * 8;
  const int tid = threadIdx.x;
  for (int i = tid; i < 8 * HHd; i += 256) ys[i] = b2f(Yb[(long)row0 * HHd + i]);
  __syncthreads();
  {
    int rr = tid >> 5, c = tid & 31;
    float s = 0.f;
    for (int k = c; k < HHd; k += 32) s += ys[rr * HHd + k];
#pragma unroll
    for (int o = 16; o; o >>= 1) s += __shfl_xor(s, o, 32);
    float mean = s * (1.f / HHd);
    float q = 0.f;
    for (int k = c; k < HHd; k += 32) { float d = ys[rr * HHd + k] - mean; q += d * d; }
#pragma unroll
    for (int o = 16; o; o >>= 1) q += __shfl_xor(q, o, 32);
    float rs = rsqrtf(q * (1.f / HHd) + 1e-5f);
    if (c == 0) { mrow[rr] = mean; rrow[rr] = rs; }
  }
  __syncthreads();
  for (int i = tid; i < 8 * HHd; i += 256) {
    int rw = i >> 9, col = i & 511;
    ys[i] = (ys[i] - mrow[rw]) * rrow[rw] * w[col] + b[col];
  }
  __syncthreads();
  const int n = tid & 31, r = tid >> 5;
  float acc = bias[n];
  const float* yr = &ys[r * HHd];
  for (int k = 0; k < HHd; ++k) acc = fmaf(yr[k], W[k * TTd + n], acc);
  feats[(long)(row0 + r) * TTd + n] = acc;
}

// ============================== Parallel Viterbi (hierarchical max-plus scan) ==============================
__global__ __launch_bounds__(256) void vit_p1(const float* __restrict__ feats,
                                              const float* __restrict__ trans,
                                              float* __restrict__ Mc) {
  __shared__ float trS[1024];
  __shared__ float fS[VW * 32];
  __shared__ float Ga[32 * 33], Gb[32 * 33];
  const int c = blockIdx.x, tid = threadIdx.x;
  for (int i = tid; i < 1024; i += 256) trS[i] = trans[i];
  for (int i = tid; i < VW * 32; i += 256) fS[i] = feats[c * VW * 32 + i];
  __syncthreads();
  for (int i = tid; i < 1024; i += 256) {
    int n = i >> 5, q = i & 31;
    Ga[n * 33 + q] = trS[i] + fS[n];
  }
  __syncthreads();
  float* G = Ga;
  float* Gn = Gb;
  const int q = tid & 31, nb = (tid >> 5) * 4;
  for (int s = 1; s < VW; ++s) {
    float m0 = -3.0e38f, m1 = -3.0e38f, m2 = -3.0e38f, m3 = -3.0e38f;
    for (int pp = 0; pp < 32; ++pp) {
      float g = G[pp * 33 + q];
      m0 = fmaxf(m0, trS[(nb + 0) * 32 + pp] + g);
      m1 = fmaxf(m1, trS[(nb + 1) * 32 + pp] + g);
      m2 = fmaxf(m2, trS[(nb + 2) * 32 + pp] + g);
      m3 = fmaxf(m3, trS[(nb + 3) * 32 + pp] + g);
    }
    Gn[(nb + 0) * 33 + q] = m0 + fS[s * 32 + nb + 0];
    Gn[(nb + 1) * 33 + q] = m1 + fS[s * 32 + nb + 1];
    Gn[(nb + 2) * 33 + q] = m2 + fS[s * 32 + nb + 2];
    Gn[(nb + 3) * 33 + q] = m3 + fS[s * 32 + nb + 3];
    __syncthreads();
    float* t = G; G = Gn; Gn = t;
  }
  for (int i = tid; i < 1024; i += 256) Mc[c * 1024 + i] = G[(i >> 5) * 33 + (i & 31)];
}

__global__ __launch_bounds__(256) void vit_p1b(const float* __restrict__ Mf, float* __restrict__ Mcrs) {
  __shared__ float Ga[32 * 33], Gb[32 * 33], Ms[1024];
  const int c = blockIdx.x, tid = threadIdx.x;
  for (int i = tid; i < 1024; i += 256) Ga[(i >> 5) * 33 + (i & 31)] = Mf[(4 * c) * 1024 + i];
  float* G = Ga;
  float* Gn = Gb;
  const int q = tid & 31, nb = (tid >> 5) * 4;
  for (int j = 1; j < 4; ++j) {
    for (int i = tid; i < 1024; i += 256) Ms[i] = Mf[(4 * c + j) * 1024 + i];
    __syncthreads();
    float m0 = -3.0e38f, m1 = -3.0e38f, m2 = -3.0e38f, m3 = -3.0e38f;
    for (int pp = 0; pp < 32; ++pp) {
      float g = G[pp * 33 + q];
      m0 = fmaxf(m0, Ms[(nb + 0) * 32 + pp] + g);
      m1 = fmaxf(m1, Ms[(nb + 1) * 32 + pp] + g);
      m2 = fmaxf(m2, Ms[(nb + 2) * 32 + pp] + g);
      m3 = fmaxf(m3, Ms[(nb + 3) * 32 + pp] + g);
    }
    Gn[(nb + 0) * 33 + q] = m0;
    Gn[(nb + 1) * 33 + q] = m1;
    Gn[(nb + 2) * 33 + q] = m2;
    Gn[(nb + 3) * 33 + q] = m3;
    __syncthreads();
    float* t = G; G = Gn; Gn = t;
  }
  for (int i = tid; i < 1024; i += 256) Mcrs[c * 1024 + i] = G[(i >> 5) * 33 + (i & 31)];
}

__device__ __forceinline__ float vstep(float fv, int p0, const f32x4& M0, const f32x4& M1,
                                       const f32x4& M2, const f32x4& M3) {
  float mv[16];
#pragma unroll
  for (int j = 0; j < 4; ++j) { mv[j] = M0[j]; mv[4 + j] = M1[j]; mv[8 + j] = M2[j]; mv[12 + j] = M3[j]; }
  float cnd[16];
#pragma unroll
  for (int j = 0; j < 16; ++j) cnd[j] = __shfl(fv, p0 + j) + mv[j];
  float t8[8], t4[4];
#pragma unroll
  for (int j = 0; j < 8; ++j) t8[j] = fmaxf(cnd[2 * j], cnd[2 * j + 1]);
#pragma unroll
  for (int j = 0; j < 4; ++j) t4[j] = fmaxf(t8[2 * j], t8[2 * j + 1]);
  float bv = fmaxf(fmaxf(t4[0], t4[1]), fmaxf(t4[2], t4[3]));
  return fmaxf(bv, __shfl_xor(bv, 32));
}

__global__ __launch_bounds__(64) void vit_p2(const float* __restrict__ Mcrs,
                                             const float* __restrict__ trans,
                                             float* __restrict__ bfvF,
                                             float* __restrict__ term,
                                             float* __restrict__ out) {
  const int lane = threadIdx.x, n = lane & 31, h = lane >> 5, p0 = h << 4;
  float fv = (n == 30) ? 0.f : -10000.f;
  if (lane < 32) bfvF[n] = fv;
  const float* base = Mcrs + n * 32 + p0;
  f32x4 A0, A1, A2, A3, B0, B1, B2, B3, C0, C1, C2, C3;
#define LDM(d0, d1, d2, d3, c) { const float* M = base + (c) * 1024; \
  d0 = *(const f32x4*)M; d1 = *(const f32x4*)(M + 4); d2 = *(const f32x4*)(M + 8); d3 = *(const f32x4*)(M + 12); }
  LDM(A0, A1, A2, A3, 0) LDM(B0, B1, B2, B3, 1) LDM(C0, C1, C2, C3, 2)
#pragma unroll 1
  for (int c = 0; c < 30; c += 3) {
    fv = vstep(fv, p0, A0, A1, A2, A3); if (lane < 32) bfvF[(4 * (c + 1)) * 32 + n] = fv;
    { int cl = (c + 3) & 31; LDM(A0, A1, A2, A3, cl) }
    fv = vstep(fv, p0, B0, B1, B2, B3); if (lane < 32) bfvF[(4 * (c + 2)) * 32 + n] = fv;
    { int cl = (c + 4) & 31; LDM(B0, B1, B2, B3, cl) }
    fv = vstep(fv, p0, C0, C1, C2, C3); if (lane < 32) bfvF[(4 * (c + 3)) * 32 + n] = fv;
    { int cl = (c + 5) & 31; LDM(C0, C1, C2, C3, cl) }
  }
  fv = vstep(fv, p0, A0, A1, A2, A3); if (lane < 32) bfvF[(4 * 31) * 32 + n] = fv;
  fv = vstep(fv, p0, B0, B1, B2, B3); if (lane < 32) bfvF[(4 * 32) * 32 + n] = fv;
#undef LDM
  float v = fv + trans[31 * 32 + n];
  int idx = n;
#pragma unroll
  for (int o = 16; o; o >>= 1) {
    float ov = __shfl_xor(v, o);
    int oi = __shfl_xor(idx, o);
    if (ov > v || (ov == v && oi < idx)) { v = ov; idx = oi; }
  }
  if (lane == 0) { out[0] = v; term[0] = (float)idx; }
}

__global__ __launch_bounds__(64) void vit_p2b(const float* __restrict__ Mf, float* __restrict__ bfvF) {
  const int c = blockIdx.x, lane = threadIdx.x, n = lane & 31, h = lane >> 5, p0 = h << 4;
  float fv = bfvF[(4 * c) * 32 + n];
  const float* base = Mf + (size_t)(4 * c) * 1024 + n * 32 + p0;
#pragma unroll
  for (int j = 0; j < 3; ++j) {
    const float* M = base + j * 1024;
    f32x4 A0 = *(const f32x4*)M, A1 = *(const f32x4*)(M + 4);
    f32x4 A2 = *(const f32x4*)(M + 8), A3 = *(const f32x4*)(M + 12);
    fv = vstep(fv, p0, A0, A1, A2, A3);
    if (lane < 32) bfvF[(4 * c + j + 1) * 32 + n] = fv;
  }
}

__global__ __launch_bounds__(64) void vit_p3(const float* __restrict__ feats,
                                             const float* __restrict__ trans,
                                             const float* __restrict__ bfvF,
                                             unsigned char* __restrict__ bp) {
  const int c = blockIdx.x, lane = threadIdx.x, n = lane & 31, h = lane >> 5, p0 = h << 4;
  float tr[16];
#pragma unroll
  for (int j = 0; j < 16; ++j) tr[j] = trans[n * 32 + p0 + j];
  float fv = bfvF[c * 32 + n];
  float ft[VW];
  for (int s = 0; s < VW; ++s) ft[s] = feats[(c * VW + s) * 32 + n];
  for (int s = 0; s < VW; ++s) {
    float cd[16];
#pragma unroll
    for (int j = 0; j < 16; ++j) cd[j] = __shfl(fv, p0 + j) + tr[j];
    float v8[8]; int i8a[8];
#pragma unroll
    for (int j = 0; j < 8; ++j) {
      bool g = cd[2 * j + 1] > cd[2 * j];
      v8[j] = g ? cd[2 * j + 1] : cd[2 * j];
      i8a[j] = g ? 2 * j + 1 : 2 * j;
    }
    float v4[4]; int i4a[4];
#pragma unroll
    for (int j = 0; j < 4; ++j) {
      bool g = v8[2 * j + 1] > v8[2 * j];
      v4[j] = g ? v8[2 * j + 1] : v8[2 * j];
      i4a[j] = g ? i8a[2 * j + 1] : i8a[2 * j];
    }
    float v2[2]; int i2a[2];
#pragma unroll
    for (int j = 0; j < 2; ++j) {
      bool g = v4[2 * j + 1] > v4[2 * j];
      v2[j] = g ? v4[2 * j + 1] : v4[2 * j];
      i2a[j] = g ? i4a[2 * j + 1] : i4a[2 * j];
    }
    bool g1 = v2[1] > v2[0];
    float bv = g1 ? v2[1] : v2[0];
    int bi = p0 + (g1 ? i2a[1] : i2a[0]);
    float ov = __shfl_xor(bv, 32);
    int oi = __shfl_xor(bi, 32);
    bool takeo = h ? (ov >= bv) : (ov > bv);
    float m = takeo ? ov : bv;
    int mi = takeo ? oi : bi;
    if (!h) bp[(c * VW + s) * 32 + n] = (unsigned char)mi;
    fv = m + ft[s];
  }
}

__global__ __launch_bounds__(VC) void vit_p4(const unsigned char* __restrict__ bp,
                                             const float* __restrict__ term,
                                             float* __restrict__ out) {
  __shared__ unsigned char GsL[VC * 32];
  __shared__ unsigned char bnd[VC];
  const int lane = threadIdx.x;
  unsigned char g[32];
#pragma unroll
  for (int j = 0; j < 32; ++j) g[j] = (unsigned char)j;
  for (int s = VW - 1; s >= 0; --s) {
    const unsigned char* rowp = bp + (lane * VW + s) * 32;
#pragma unroll
    for (int j = 0; j < 32; ++j) g[j] = rowp[g[j]];
  }
#pragma unroll
  for (int j = 0; j < 32; ++j) GsL[lane * 32 + j] = g[j];
  __syncthreads();
  if (lane == 0) {
    bnd[VC - 1] = (unsigned char)(int)term[0];
    for (int cc = VC - 1; cc >= 1; --cc) bnd[cc - 1] = GsL[cc * 32 + bnd[cc]];
  }
  __syncthreads();
  int x = bnd[lane];
  out[1 + lane * VW + VW - 1] = (float)x;
  for (int k = VW - 2; k >= 0; --k) {
    x = bp[(lane * VW + k + 1) * 32 + x];
    out[1 + lane * VW + k] = (float)x;
  }
}

// ------------------------------ host ------------------------------
extern "C" void kernel_launch(void* const* d_in, const int* in_sizes, int n_in,
                              void* d_out, int out_size, void* d_ws, size_t ws_size,
                              hipStream_t stream) {
  (void)in_sizes; (void)n_in; (void)out_size; (void)ws_size;
  const int H = HHd, F = FFd, S = SS, L = LLd;
  const long HH2 = (long)H * H;
  const long SH = (long)S * H;
  const long HF = (long)H * F;

  hipFuncSetAttribute(reinterpret_cast<const void*>(fsa_k<8>),
                      hipFuncAttributeMaxDynamicSharedMemorySize, FSA_SMEM);
  hipFuncSetAttribute(reinterpret_cast<const void*>(fsa_k<4>),
                      hipFuncAttributeMaxDynamicSharedMemorySize, FSA_SMEM);

  const int*   sent = (const int*)d_in[0];
  const float* embd = (const float*)d_in[1];
  const float* eaw  = (const float*)d_in[2];
  const float* eab  = (const float*)d_in[3];
  const float* ew1  = (const float*)d_in[4];
  const float* eb1  = (const float*)d_in[5];
  const float* ew2  = (const float*)d_in[6];
  const float* eb2  = (const float*)d_in[7];
  const float* elnw = (const float*)d_in[8];
  const float* elnb = (const float*)d_in[9];
  const float* daw  = (const float*)d_in[10];
  const float* dab  = (const float*)d_in[11];
  const float* dw1  = (const float*)d_in[12];
  const float* db1  = (const float*)d_in[13];
  const float* dw2  = (const float*)d_in[14];
  const float* db2  = (const float*)d_in[15];
  const float* dlnw = (const float*)d_in[16];
  const float* dlnb = (const float*)d_in[17];
  const float* enw  = (const float*)d_in[18];
  const float* enb  = (const float*)d_in[19];
  const float* dnw  = (const float*)d_in[20];
  const float* dnb  = (const float*)d_in[21];
  const float* h2tw = (const float*)d_in[22];
  const float* h2tb = (const float*)d_in[23];
  const float* trns = (const float*)d_in[24];

  char* p = (char*)d_ws;
  auto alloc = [&](size_t bytes) -> char* {
    char* r = p;
    p += (bytes + 255) & ~(size_t)255;
    return r;
  };
  short* wEAT = (short*)alloc((size_t)L * 4 * HH2 * 2);
  short* wDAT = (short*)alloc((size_t)L * 8 * HH2 * 2);
  short* wE1T = (short*)alloc((size_t)L * HF * 2);
  short* wE2T = (short*)alloc((size_t)L * HF * 2);
  short* wD1T = (short*)alloc((size_t)L * HF * 2);
  short* wD2T = (short*)alloc((size_t)L * HF * 2);
  short* h_b  = (short*)alloc(SH * 2);
  short* y_b  = (short*)alloc(SH * 2);
  short* qkvb = (short*)alloc(4 * SH * 2);           // Q, K, V''-slot, crossQ
  float* scf  = (float*)alloc((size_t)8 * SH * 4);   // partial buffer (bf16 splits; f32 alias prologue)
  float* Zp   = (float*)alloc((size_t)16 * S * 4);   // per-split Z row sums
  short* ff1b = (short*)alloc((size_t)S * F * 2);
  short* memb = (short*)alloc(SH * 2);
  short* ckvA = (short*)alloc((size_t)2 * L * SH * 2);  // interleaved cross K (even slots; odd unused)
  short* cvT  = (short*)alloc((size_t)L * SH * 2);      // cross V''^T per layer (direct from GEMM)
  float* biasE = (float*)alloc((size_t)L * 4 * H * 4);  // eab with j=2 zeroed
  float* biasD = (float*)alloc((size_t)L * 8 * H * 4);  // dab with j=2,6 zeroed; j=3 <- dab j=4
  float* bvoAll = (float*)alloc((size_t)18 * H * 4);    // folded V/out biases
  float* bvoPart = (float*)alloc((size_t)18 * 16 * H * 4); // bvo partials
  float* ftsf = (float*)alloc((size_t)S * TTd * 4);
  float* McB  = (float*)alloc((size_t)VC * 1024 * 4);
  float* McrsB= (float*)alloc((size_t)(VC / 4) * 1024 * 4);
  float* bfvF = (float*)alloc((size_t)(VC + 1) * 32 * 4);
  float* termB= (float*)alloc(64);
  unsigned char* bpgB = (unsigned char*)alloc((size_t)2048 * 32);

  short* vtb = ff1b;                  // V''^T scratch aliases ff1b (disjoint lifetimes)
  short* sparts = (short*)scf;        // bf16 split partials (enc: 8 slices; dec self: 4 slices)
  short* sparts2 = sparts + 4 * SH;   // bf16 split partials (dec cross: 4 slices)
  float* Zp2 = Zp + 4 * S;
  short* wvPe  = (short*)scf;         // plain bf16 Wv copies alias scf (prologue only)
  short* wvPds = wvPe + L * HH2;
  short* wvPdc = wvPds + L * HH2;

  const int ZBIG = 1 << 20;

  // ---- weight conversion (merged launches) ----
  tconv2_k<<<dim3(16, 16, L * 12), 256, 0, stream>>>(eaw, wEAT, daw, wDAT, H, H, L * 4);
  tconv2_k<<<dim3(64, 16, 2 * L), 256, 0, stream>>>(ew1, wE1T, dw1, wD1T, H, F, L);
  tconv2_k<<<dim3(16, 64, 2 * L), 256, 0, stream>>>(ew2, wE2T, dw2, wD2T, F, H, L);
  // plain bf16 copies of Wv (enc j2, dec-self j2, dec-cross j6) in one launch
  pconv3_k<<<dim3(256, 1, 3 * L), 256, 0, stream>>>(
      eaw + 2 * HH2, wvPe, 4 * HH2,
      daw + 2 * HH2, wvPds, 8 * HH2,
      daw + 6 * HH2, wvPdc, 8 * HH2, HH2);
  // compose Wvo^T = Wout^T @ Wv^T into the V-weight slots (in place)
  auto G_cmp = gemm3<128, 64, false, false, false, false, true, false>;
  G_cmp<<<dim3(8, 4, L), 256, 0, stream>>>(
      wEAT + 3 * HH2, wvPe, nullptr, nullptr, nullptr, wEAT + 2 * HH2,
      H, H, H, H, H, 0, 1.f, 1, 4 * HH2, HH2, 0, 0, 0, 4 * HH2,
      nullptr, 0, 1, -1);
  G_cmp<<<dim3(8, 4, L), 256, 0, stream>>>(
      wDAT + 3 * HH2, wvPds, nullptr, nullptr, nullptr, wDAT + 2 * HH2,
      H, H, H, H, H, 0, 1.f, 1, 8 * HH2, HH2, 0, 0, 0, 8 * HH2,
      nullptr, 0, 1, -1);
  G_cmp<<<dim3(8, 4, L), 256, 0, stream>>>(
      wDAT + 7 * HH2, wvPdc, nullptr, nullptr, nullptr, wDAT + 6 * HH2,
      H, H, H, H, H, 0, 1.f, 1, 8 * HH2, HH2, 0, 0, 0, 8 * HH2,
      nullptr, 0, 1, -1);
  // dec-self Wout^T slot (j=3) is free after compose: move crossQ W^T (j=4) into it
  scpy_k<<<dim3(256, 1, L), 256, 0, stream>>>(wDAT + 4 * HH2, wDAT + 3 * HH2, 8 * HH2, 8 * HH2);
  // bias tables with V slots zeroed; folded biases
  zbias_k<<<dim3((L * 4 * H + 255) / 256), 256, 0, stream>>>(eab, biasE, 4, 1u << 2, L * 4 * H);
  zbias_k<<<dim3((L * 8 * H + 255) / 256), 256, 0, stream>>>(dab, biasD, 8, (1u << 2) | (1u << 6), L * 8 * H);
  bcpy_k<<<dim3(L * H / 256), 256, 0, stream>>>(dab, biasD);
  bvoP_k<<<dim3(18, 16), 256, 0, stream>>>(eaw, eab, daw, dab, bvoPart);
  bvoR_k<<<dim3(18), 256, 0, stream>>>(bvoPart, eab, dab, bvoAll);

  gather_k<<<dim3((unsigned)(SH / 256)), 256, 0, stream>>>(sent, embd, h_b, y_b);

  // gemm variants
  auto G_qkv = gemm3<128, 64, true, false, false, false, true, true>;   // batched proj; z==2 -> V''^T direct
  auto G_spl = gemm3<128, 64, false, false, false, false, true, false>; // split-K partials -> bf16
  auto G_ff1 = gemm3<128, 64, true, true, false, false, true, false>;   // bias+relu -> bf16

  dim3 gQKVe(8, 16, 3), gQKVd(8, 16, 4), gSPL(8, 16, 4), gFF1(32, 16, 1);
  dim3 gFSAe(8, 32, 1), gFSAd(4, 32, 2);

  // ---------------- encoder ----------------
  for (int i = 0; i < L; ++i) {
    G_qkv<<<gQKVe, 256, 0, stream>>>(
        h_b, wEAT + (size_t)i * 4 * HH2, biasE + (size_t)i * 4 * H, nullptr, nullptr, qkvb,
        S, H, H, H, H, 0, 1.f, ZBIG, 0, 0, HH2, 0, H, SH,
        vtb, 0, 3, 2);
    fsa_k<8><<<gFSAe, 512, FSA_SMEM, stream>>>(qkvb, qkvb + SH, vtb, sparts, Zp,
                                               qkvb, qkvb + SH, vtb, sparts, Zp);
    r4zrln_k<<<dim3(S), 256, 0, stream>>>(sparts, Zp, bvoAll + (size_t)i * H, h_b,
        elnw + (size_t)(i * 2) * H, elnb + (size_t)(i * 2) * H, h_b);
    G_ff1<<<gFF1, 256, 0, stream>>>(
        h_b, wE1T + (size_t)i * HF, eb1 + (size_t)i * F, nullptr, nullptr, ff1b,
        S, F, H, H, H, 0, 1.f, 1, 0, 0, 0, 0, 0, 0,
        nullptr, 0, 1, -1);
    G_spl<<<gSPL, 256, 0, stream>>>(
        ff1b, wE2T + (size_t)i * HF, nullptr, nullptr, nullptr, sparts,
        S, H, F / 4, F, F, F / 4, 1.f, 1, 0, 0, 0, 0, 0, SH,
        nullptr, 0, 1, -1);
    r4rln_k<<<dim3(S), 256, 0, stream>>>(sparts, eb2 + (size_t)i * H, h_b,
        elnw + (size_t)(i * 2 + 1) * H, elnb + (size_t)(i * 2 + 1) * H, h_b);
  }
  lnb_k<<<dim3(S), 256, 0, stream>>>(h_b, enw, enb, nullptr, memb);

  // cross K (j=5, even z) and composed V''^T (j=6, odd z -> direct transposed to cvT)
  G_qkv<<<dim3(8, 16, 2 * L), 256, 0, stream>>>(
      memb, wDAT + 5 * HH2, biasD + 5 * H, nullptr, nullptr, ckvA,
      S, H, H, H, H, 0, 1.f, 2, 0, 8 * HH2, HH2, 8 * H, H, SH,
      cvT, SH, 2, 1);

  // ---------------- decoder ----------------
  for (int i = 0; i < L; ++i) {
    // z=4 batch: Q, K, V''(->vtb transposed), crossQ (slot 3 holds crossQ weights/bias)
    G_qkv<<<gQKVd, 256, 0, stream>>>(
        y_b, wDAT + (size_t)i * 8 * HH2, biasD + (size_t)i * 8 * H, nullptr, nullptr, qkvb,
        S, H, H, H, H, 0, 1.f, ZBIG, 0, 0, HH2, 0, H, SH,
        vtb, 0, 4, 2);
    // dual-issue (4 key-splits each, 2x key chunks per block): self (set 0) + cross (set 1)
    fsa_k<4><<<gFSAd, 512, FSA_SMEM, stream>>>(
        qkvb, qkvb + SH, vtb, sparts, Zp,
        qkvb + 3 * SH, ckvA + (size_t)(2 * i) * SH, cvT + (size_t)i * SH, sparts2, Zp2);
    // fused self + cross tails (y1 kept in registers)
    r4zrln2_k<<<dim3(S), 256, 0, stream>>>(
        sparts, Zp, bvoAll + (size_t)(6 + i) * H,
        sparts2, Zp2, bvoAll + (size_t)(12 + i) * H,
        dlnw + (size_t)(i * 3) * H, dlnb + (size_t)(i * 3) * H,
        dlnw + (size_t)(i * 3 + 1) * H, dlnb + (size_t)(i * 3 + 1) * H,
        y_b);
    // FFN
    G_ff1<<<gFF1, 256, 0, stream>>>(
        y_b, wD1T + (size_t)i * HF, db1 + (size_t)i * F, nullptr, nullptr, ff1b,
        S, F, H, H, H, 0, 1.f, 1, 0, 0, 0, 0, 0, 0,
        nullptr, 0, 1, -1);
    G_spl<<<gSPL, 256, 0, stream>>>(
        ff1b, wD2T + (size_t)i * HF, nullptr, nullptr, nullptr, sparts,
        S, H, F / 4, F, F, F / 4, 1.f, 1, 0, 0, 0, 0, 0, SH,
        nullptr, 0, 1, -1);
    r4rln_k<<<dim3(S), 256, 0, stream>>>(sparts, db2 + (size_t)i * H, y_b,
        dlnw + (size_t)(i * 3 + 2) * H, dlnb + (size_t)(i * 3 + 2) * H, y_b);
  }
  // fused final LN + feats + hierarchical parallel viterbi
  featsln_k<<<dim3(S / 8), 256, 0, stream>>>(y_b, dnw, dnb, h2tw, h2tb, ftsf);
  float* outF = (float*)d_out;
  vit_p1<<<dim3(VC), 256, 0, stream>>>(ftsf, trns, McB);
  vit_p1b<<<dim3(VC / 4), 256, 0, stream>>>(McB, McrsB);
  vit_p2<<<dim3(1), 64, 0, stream>>>(McrsB, trns, bfvF, termB, outF);
  vit_p2b<<<dim3(VC / 4), 64, 0, stream>>>(McB, bfvF);
  vit_p3<<<dim3(VC), 64, 0, stream>>>(ftsf, trns, bfvF, bpgB);
  vit_p4<<<dim3(1), VC, 0, stream>>>(bpgB, termB, outF);
}